// Round 9
// baseline (4501.053 us; speedup 1.0000x reference)
//
#include <hip/hip_runtime.h>
#include <hip/hip_fp16.h>
#include <math.h>

#define D 128
#define G4 256
#define LSEQ 21
#define EPSF 1e-5f

typedef unsigned short u16;
typedef __attribute__((ext_vector_type(8))) short bf16x8;
typedef __attribute__((ext_vector_type(4))) float f32x4;
typedef __attribute__((ext_vector_type(2))) unsigned u32x2;
typedef __attribute__((ext_vector_type(4))) unsigned u32x4;

#define MFMA16(a,b,c) __builtin_amdgcn_mfma_f32_16x16x32_bf16(a,b,c,0,0,0)

// ---------------------------------------------------------------- helpers
__device__ __forceinline__ float sigf(float x){ return 1.0f/(1.0f+__expf(-x)); }
__device__ __forceinline__ u16 f2bf(float x){
  unsigned u = __float_as_uint(x);
  return (u16)((u + 0x7FFFu + ((u>>16)&1u)) >> 16);
}
__device__ __forceinline__ float bf2f(u16 h){ return __uint_as_float(((unsigned)h)<<16); }
__device__ __forceinline__ unsigned pack_h2(float a, float b){
  __half2 h = __floats2half2_rn(a, b);
  return *(unsigned*)&h;
}
__device__ __forceinline__ float2 unpack_h2(unsigned u){
  __half2 h = *(__half2*)&u;
  return __half22float2(h);
}
__device__ __forceinline__ u16 f2h(float v){ __half h = __float2half(v); return *(u16*)&h; }

__device__ __forceinline__ void edge_acc(u32x4 a, uint2 g, bool valid,
                                         float2 po2, float2 w0, float2 w1, float2 w2,
                                         float& ax, float& ay){
  float e0=__uint_as_float(a.y), e1=__uint_as_float(a.z), e2=__uint_as_float(a.w);
  float2 ps0 = unpack_h2(g.x);   // {P(ch0), S(ch0)}
  float2 ps1 = unpack_h2(g.y);   // {P(ch1), S(ch1)}
  float gx = po2.x + ps0.x + e0*w0.x + e1*w1.x + e2*w2.x;
  float gy = po2.y + ps1.x + e0*w0.y + e1*w1.y + e2*w2.y;
  float mm = valid ? 1.f : 0.f;
  ax = fmaf(ps0.y*mm, sigf(gx), ax);
  ay = fmaf(ps1.y*mm, sigf(gy), ay);
}

// ---------------------------------------------------------------- prologue kernels
__global__ void k_misc(int* __restrict__ starts, const int* __restrict__ batch, int N, int Bb,
                       float* __restrict__ WEin, float* __restrict__ WEout,
                       const float* __restrict__ W_in, const float* __restrict__ W_out,
                       float* __restrict__ bsum_f, float* __restrict__ bsum_b,
                       const float* __restrict__ bih_f, const float* __restrict__ bhh_f,
                       const float* __restrict__ bih_b, const float* __restrict__ bhh_b){
  int tid = threadIdx.x;
  if (tid < Bb){
    int lo = 0, hi = N;
    while (lo < hi){ int m = (lo+hi)>>1; if (batch[m] < tid) lo = m+1; else hi = m; }
    starts[tid] = lo;
  }
  for (int i = tid; i < 384; i += 256){
    int t = i >> 7, j = i & 127;
    WEin [i] = W_in [(size_t)j*259 + 256 + t];
    WEout[i] = W_out[(size_t)j*259 + 256 + t];
  }
  if (tid < 256){
    bsum_f[tid] = bih_f[tid] + bhh_f[tid];
    bsum_b[tid] = bih_b[tid] + bhh_b[tid];
  }
}

// pre-pack MFMA B-fragments (hi/lo bf16), layout [nt][ks][lane][8] contiguous
__global__ void k_packB(u16* __restrict__ PB4h, u16* __restrict__ PB4l,
                        u16* __restrict__ PBnh, u16* __restrict__ PBnl,
                        u16* __restrict__ PBEh, u16* __restrict__ PBEl,
                        const float* __restrict__ W_in, const float* __restrict__ W_out,
                        const float* __restrict__ W_node, const float* __restrict__ W_esm){
  int idx = blockIdx.x*256 + threadIdx.x;
  if (idx < 65536){
    int j = idx&7, l=(idx>>3)&63, q=idx>>9;
    int ks = q&3, nt = q>>2;
    int c = nt*16 + (l&15);
    int k = ks*32 + ((l>>4)<<3) + j;
    float v;
    if (c < 128)      v = W_in [(size_t)c*259 + k];
    else if (c < 256) v = W_in [(size_t)(c-128)*259 + 128 + k];
    else if (c < 384) v = W_out[(size_t)(c-256)*259 + k];
    else              v = W_out[(size_t)(c-384)*259 + 128 + k];
    u16 h = f2bf(v);
    PB4h[idx] = h; PB4l[idx] = f2bf(v - bf2f(h));
  } else if (idx < 65536 + 16384){
    int p = idx - 65536;
    int j = p&7, l=(p>>3)&63, q=p>>9;
    int ks = q&3, nt = q>>2;
    int c = nt*16 + (l&15);
    int k = ks*32 + ((l>>4)<<3) + j;
    float v = W_node[(size_t)c*129 + k];
    u16 h = f2bf(v);
    PBnh[p] = h; PBnl[p] = f2bf(v - bf2f(h));
  } else if (idx < 65536 + 16384 + 327680){
    int p = idx - 81920;
    int j = p&7, l=(p>>3)&63, q=p>>9;
    int ks = q%80, nt = q/80;
    int c = nt*16 + (l&15);
    int k = ks*32 + ((l>>4)<<3) + j;
    float v = W_esm[(size_t)c*2560 + k];
    u16 h = f2bf(v);
    PBEh[p] = h; PBEl[p] = f2bf(v - bf2f(h));
  }
}

__global__ void k_seq0(float* __restrict__ seq0, const float* __restrict__ hot,
                       const float* __restrict__ W_seq, const float* __restrict__ b_seq){
  int row = blockIdx.x, j = threadIdx.x;           // 128 threads
  const float* h = hot + (size_t)row*28;
  const float* w = W_seq + (size_t)j*28;
  float acc = b_seq[j];
  #pragma unroll
  for (int k = 0; k < 28; k++) acc += h[k]*w[k];
  seq0[(size_t)row*D + j] = acc;
}

// fused: esm = x[:,1:] @ W_esm.T + b_esm ; struct0 = [esm, x[:,:1]] @ W_node.T + b_node
__global__ __launch_bounds__(256) void k_esm2(float* __restrict__ struct0, const float* __restrict__ x,
    const u16* __restrict__ PBEh, const u16* __restrict__ PBEl,
    const u16* __restrict__ PBnh, const u16* __restrict__ PBnl,
    const float* __restrict__ b_esm, const float* __restrict__ W_node,
    const float* __restrict__ b_node){
  __shared__ union {
    struct { u16 xh[32*72], xl[32*72]; } p1;
    struct { u16 Ah[32*136], Al[32*136]; } p2;
  } uu;
  __shared__ float esmF[32*132];
  int tid = threadIdx.x;
  int r0 = blockIdx.x*32;
  int w = tid>>6, l = tid&63;
  f32x4 acc[2][2];
  #pragma unroll
  for (int a=0;a<2;a++)
    #pragma unroll
    for (int b=0;b<2;b++) acc[a][b] = (f32x4){0.f,0.f,0.f,0.f};

  // x staging: row rr (0..31), 8 cols at c8; vectorized float4 loads
  int rr = tid >> 3, c8 = (tid & 7)*8;
  const float* xrow = x + (size_t)(r0+rr)*2561 + 1 + c8;
  float4 xva = *(const float4*)(xrow);
  float4 xvb = *(const float4*)(xrow + 4);
  for (int kc = 0; kc < 2560; kc += 64){
    __syncthreads();
    unsigned* xh32 = (unsigned*)uu.p1.xh;
    unsigned* xl32 = (unsigned*)uu.p1.xl;
    {
      float vv[8] = {xva.x,xva.y,xva.z,xva.w, xvb.x,xvb.y,xvb.z,xvb.w};
      #pragma unroll
      for (int j = 0; j < 4; j++){
        float v0 = vv[2*j], v1 = vv[2*j+1];
        u16 h0 = f2bf(v0), h1 = f2bf(v1);
        u16 l0 = f2bf(v0 - bf2f(h0)), l1 = f2bf(v1 - bf2f(h1));
        xh32[rr*36 + (c8>>1) + j] = (unsigned)h0 | ((unsigned)h1 << 16);
        xl32[rr*36 + (c8>>1) + j] = (unsigned)l0 | ((unsigned)l1 << 16);
      }
    }
    __syncthreads();
    if (kc + 64 < 2560){
      xva = *(const float4*)(xrow + kc + 64);
      xvb = *(const float4*)(xrow + kc + 68);
    }
    #pragma unroll
    for (int ks = 0; ks < 2; ks++){
      bf16x8 ah[2], al[2];
      #pragma unroll
      for (int rt = 0; rt < 2; rt++){
        int row = rt*16 + (l&15);
        int k = ks*32 + ((l>>4)<<3);
        ah[rt] = *(const bf16x8*)&uu.p1.xh[row*72 + k];
        al[rt] = *(const bf16x8*)&uu.p1.xl[row*72 + k];
      }
      int ksg = (kc>>5) + ks;
      #pragma unroll
      for (int ctl = 0; ctl < 2; ctl++){
        int nt = w*2 + ctl;
        bf16x8 bh = *(const bf16x8*)&PBEh[((size_t)(nt*80 + ksg)*64 + l)*8];
        bf16x8 bl = *(const bf16x8*)&PBEl[((size_t)(nt*80 + ksg)*64 + l)*8];
        #pragma unroll
        for (int rt = 0; rt < 2; rt++){
          acc[rt][ctl] = MFMA16(ah[rt], bh, acc[rt][ctl]);
          acc[rt][ctl] = MFMA16(al[rt], bh, acc[rt][ctl]);
          acc[rt][ctl] = MFMA16(ah[rt], bl, acc[rt][ctl]);
        }
      }
    }
  }
  __syncthreads();
  int cq = l & 15, rqb = (l>>4)*4;
  #pragma unroll
  for (int ctl = 0; ctl < 2; ctl++){
    int coln = (w*2+ctl)*16 + cq;
    float be = b_esm[coln];
    #pragma unroll
    for (int rt = 0; rt < 2; rt++)
      #pragma unroll
      for (int r = 0; r < 4; r++)
        esmF[(rt*16+rqb+r)*132 + coln] = acc[rt][ctl][r] + be;
  }
  __syncthreads();
  {
    unsigned* Ah32 = (unsigned*)uu.p2.Ah;
    unsigned* Al32 = (unsigned*)uu.p2.Al;
    int rr2 = tid >> 6, k2 = tid & 63;   // 4 rows/iter, 64 col-pairs
    #pragma unroll
    for (int q = 0; q < 8; q++){
      int r = rr2 + 4*q;
      float v0 = esmF[r*132 + k2*2];
      float v1 = esmF[r*132 + k2*2 + 1];
      u16 h0 = f2bf(v0), h1 = f2bf(v1);
      u16 l0 = f2bf(v0 - bf2f(h0)), l1 = f2bf(v1 - bf2f(h1));
      Ah32[r*68 + k2] = (unsigned)h0 | ((unsigned)h1 << 16);
      Al32[r*68 + k2] = (unsigned)l0 | ((unsigned)l1 << 16);
    }
  }
  __syncthreads();
  f32x4 acc2[2][2];
  #pragma unroll
  for (int a=0;a<2;a++)
    #pragma unroll
    for (int b=0;b<2;b++) acc2[a][b] = (f32x4){0.f,0.f,0.f,0.f};
  #pragma unroll
  for (int ks = 0; ks < 4; ks++){
    bf16x8 ah[2], al[2];
    #pragma unroll
    for (int rt = 0; rt < 2; rt++){
      int row = rt*16 + (l&15);
      int k = ks*32 + ((l>>4)<<3);
      ah[rt] = *(const bf16x8*)&uu.p2.Ah[row*136 + k];
      al[rt] = *(const bf16x8*)&uu.p2.Al[row*136 + k];
    }
    #pragma unroll
    for (int ctl = 0; ctl < 2; ctl++){
      int nt = w*2 + ctl;
      bf16x8 bh = *(const bf16x8*)&PBnh[((size_t)(nt*4 + ks)*64 + l)*8];
      bf16x8 bl = *(const bf16x8*)&PBnl[((size_t)(nt*4 + ks)*64 + l)*8];
      #pragma unroll
      for (int rt = 0; rt < 2; rt++){
        acc2[rt][ctl] = MFMA16(ah[rt], bh, acc2[rt][ctl]);
        acc2[rt][ctl] = MFMA16(al[rt], bh, acc2[rt][ctl]);
        acc2[rt][ctl] = MFMA16(ah[rt], bl, acc2[rt][ctl]);
      }
    }
  }
  #pragma unroll
  for (int ctl = 0; ctl < 2; ctl++){
    int col = (w*2+ctl)*16 + cq;
    float wl = W_node[(size_t)col*129 + 128];
    float bn = b_node[col];
    #pragma unroll
    for (int rt = 0; rt < 2; rt++)
      #pragma unroll
      for (int r = 0; r < 4; r++){
        int row = r0 + rt*16 + rqb + r;
        float x0 = x[(size_t)row*2561];
        struct0[(size_t)row*D + col] = acc2[rt][ctl][r] + x0*wl + bn;
      }
  }
}

// ---------------------------------------------------------------- CSR build
__global__ void k_zero2(int* a, int* b, int n){
  int i = blockIdx.x*blockDim.x + threadIdx.x;
  if (i < n){ a[i] = 0; b[i] = 0; }
}
__global__ void k_count(int* cnt_s, int* cnt_d, const int* __restrict__ ei, int E2){
  int e = blockIdx.x*blockDim.x + threadIdx.x;
  if (e < E2){
    atomicAdd(&cnt_s[ei[2*e]], 1);
    atomicAdd(&cnt_d[ei[2*E2 + 2*e]], 1);
  }
}
__global__ __launch_bounds__(1024) void k_scan(const int* __restrict__ cnt, int* __restrict__ offs, int n){
  __shared__ int sh[1024];
  __shared__ int sbase;
  int tid = threadIdx.x;
  if (tid == 0) sbase = 0;
  __syncthreads();
  for (int chunk = 0; chunk < n; chunk += 1024){
    int v = (chunk+tid < n) ? cnt[chunk+tid] : 0;
    sh[tid] = v;
    __syncthreads();
    for (int off = 1; off < 1024; off <<= 1){
      int t = (tid >= off) ? sh[tid-off] : 0;
      __syncthreads();
      sh[tid] += t;
      __syncthreads();
    }
    if (chunk+tid < n) offs[chunk+tid] = sbase + sh[tid] - v;
    __syncthreads();
    if (tid == 0) sbase += sh[1023];
    __syncthreads();
  }
  if (tid == 0) offs[n] = sbase;
}
__global__ void k_copy2(int* cur_s, const int* offs_s, int* cur_d, const int* offs_d, int n){
  int i = blockIdx.x*blockDim.x + threadIdx.x;
  if (i < n){ cur_s[i] = offs_s[i]; cur_d[i] = offs_d[i]; }
}
__global__ void k_fill(const int* __restrict__ ei, const float* __restrict__ eattr, int E2,
                       int* cur_s, int4* __restrict__ adj_s,
                       int* cur_d, int4* __restrict__ adj_d){
  int e = blockIdx.x*blockDim.x + threadIdx.x;
  if (e >= E2) return;
  int s = ei[2*e];
  int d = ei[2*E2 + 2*e];
  const float* ein  = eattr + (size_t)(2*e+1)*3;
  const float* eout = eattr + (size_t)(2*e)*3;
  int ps = atomicAdd(&cur_s[s], 1);
  adj_s[ps] = make_int4(d, __float_as_int(ein[0]),  __float_as_int(ein[1]),  __float_as_int(ein[2]));
  int pd = atomicAdd(&cur_d[d], 1);
  adj_d[pd] = make_int4(s, __float_as_int(eout[0]), __float_as_int(eout[1]), __float_as_int(eout[2]));
}
__global__ void k_pad(int4* __restrict__ adj_s, int4* __restrict__ adj_d, int E2){
  int t = threadIdx.x;
  if (t < 8){
    adj_s[E2+t] = make_int4(0,0,0,0);
    adj_d[E2+t] = make_int4(0,0,0,0);
  }
}

// ---------------------------------------------------------------- per-step kernel A
// blocks [0,Bb): seq pre-GEMM ; blocks [Bb,..): struct GEMM + parallel table epilogue
__global__ __launch_bounds__(256) void k_A(
  const float* __restrict__ s0t, const float* __restrict__ ty, const float* __restrict__ tz,
  float* __restrict__ struct_in,
  const u16* __restrict__ PB4h, const u16* __restrict__ PB4l,
  unsigned* __restrict__ G_in, unsigned* __restrict__ G_out,
  unsigned* __restrict__ PownPk,
  const float* __restrict__ b_in, const float* __restrict__ b_out,
  const float* __restrict__ s0s, const float* __restrict__ sy, const float* __restrict__ sz,
  float* __restrict__ seq_in, float* __restrict__ pre_f, float* __restrict__ pre_b,
  const float* __restrict__ Wih_f, const float* __restrict__ Wih_b,
  const float* __restrict__ bsum_f, const float* __restrict__ bsum_b,
  int N, int Bb)
{
  __shared__ union {
    struct { u16 Ah[32*136], Al[32*136]; float Sf[32*132];
             unsigned stgIn[32*128], stgOut[32*128]; } m;
    float sh[LSEQ*128];
  } u;
  int tid = threadIdx.x;
  if ((int)blockIdx.x >= Bb){
    int r0 = (blockIdx.x - Bb)*32;
    const float4* ty4 = (const float4*)(ty + (size_t)r0*D);
    const float4* tz4 = (const float4*)(tz + (size_t)r0*D);
    const float4* s04 = s0t ? (const float4*)(s0t + (size_t)r0*D) : nullptr;
    float4* si4 = (float4*)(struct_in + (size_t)r0*D);
    #pragma unroll
    for (int q = 0; q < 4; q++){
      int i = tid + 256*q;          // float4 index, 0..1023
      int r = i >> 5, k4 = i & 31;
      float4 v = ty4[i];
      float4 z = tz4[i];
      v.x += z.x; v.y += z.y; v.z += z.z; v.w += z.w;
      if (s04){ float4 s = s04[i]; v.x += s.x; v.y += s.y; v.z += s.z; v.w += s.w; }
      si4[i] = v;
      u16 h0 = f2bf(v.x), h1 = f2bf(v.y), h2 = f2bf(v.z), h3 = f2bf(v.w);
      *(ushort4*)&u.m.Ah[r*136 + k4*4] = make_ushort4(h0,h1,h2,h3);
      *(ushort4*)&u.m.Al[r*136 + k4*4] = make_ushort4(
          f2bf(v.x - bf2f(h0)), f2bf(v.y - bf2f(h1)),
          f2bf(v.z - bf2f(h2)), f2bf(v.w - bf2f(h3)));
      *(float4*)&u.m.Sf[r*132 + k4*4] = v;
    }
    __syncthreads();
    int w = tid >> 6, l = tid & 63;
    f32x4 acc[2][8];
    #pragma unroll
    for (int a=0;a<2;a++)
      #pragma unroll
      for (int b=0;b<8;b++) acc[a][b] = (f32x4){0.f,0.f,0.f,0.f};
    #pragma unroll
    for (int ks = 0; ks < 4; ks++){
      bf16x8 ah[2], al[2];
      #pragma unroll
      for (int rt = 0; rt < 2; rt++){
        int row = rt*16 + (l&15);
        int k = ks*32 + ((l>>4)<<3);
        ah[rt] = *(const bf16x8*)&u.m.Ah[row*136 + k];
        al[rt] = *(const bf16x8*)&u.m.Al[row*136 + k];
      }
      #pragma unroll
      for (int ct = 0; ct < 8; ct++){
        int nt = w*8 + ct;
        bf16x8 bh = *(const bf16x8*)&PB4h[((size_t)(nt*4 + ks)*64 + l)*8];
        bf16x8 bl = *(const bf16x8*)&PB4l[((size_t)(nt*4 + ks)*64 + l)*8];
        #pragma unroll
        for (int rt = 0; rt < 2; rt++){
          acc[rt][ct] = MFMA16(ah[rt], bh, acc[rt][ct]);
          acc[rt][ct] = MFMA16(al[rt], bh, acc[rt][ct]);
          acc[rt][ct] = MFMA16(ah[rt], bl, acc[rt][ct]);
        }
      }
    }
    // ---- parallel table epilogue: one fill pass (all waves), one sync, one copy ----
    __syncthreads();                       // MFMA done reading Ah/Al
    u16* stgPk16 = (u16*)u.m.Ah;           // PownPk staging reuses Ah/Al region (16KB)
    int cq = l & 15, rqb = (l>>4)*4;
    if (w == 1){
      #pragma unroll
      for (int ct = 0; ct < 8; ct++){
        int coln = ct*16 + cq;
        #pragma unroll
        for (int rt = 0; rt < 2; rt++)
          #pragma unroll
          for (int r = 0; r < 4; r++){
            int lr = rt*16 + rqb + r;
            u.m.stgIn[lr*128 + coln] = pack_h2(acc[rt][ct][r], u.m.Sf[lr*132 + coln]);
          }
      }
    } else if (w == 2){
      #pragma unroll
      for (int ct = 0; ct < 8; ct++){
        int coln = ct*16 + cq;
        #pragma unroll
        for (int rt = 0; rt < 2; rt++)
          #pragma unroll
          for (int r = 0; r < 4; r++){
            int lr = rt*16 + rqb + r;
            u.m.stgOut[lr*128 + coln] = pack_h2(acc[rt][ct][r], u.m.Sf[lr*132 + coln]);
          }
      }
    } else {
      const float* bb = (w == 0) ? b_in : b_out;
      int half = (w == 0) ? 0 : 1;
      #pragma unroll
      for (int ct = 0; ct < 8; ct++){
        int coln = ct*16 + cq;
        float bc = bb[coln];
        #pragma unroll
        for (int rt = 0; rt < 2; rt++)
          #pragma unroll
          for (int r = 0; r < 4; r++){
            int lr = rt*16 + rqb + r;
            stgPk16[(lr*128 + coln)*2 + half] = f2h(acc[rt][ct][r] + bc);
          }
      }
    }
    __syncthreads();
    {
      uint4* dIn  = (uint4*)(G_in  + (size_t)r0*D);
      uint4* dOut = (uint4*)(G_out + (size_t)r0*D);
      uint4* dPk  = (uint4*)(PownPk + (size_t)r0*D);
      const uint4* sIn  = (const uint4*)u.m.stgIn;
      const uint4* sOut = (const uint4*)u.m.stgOut;
      const uint4* sPk  = (const uint4*)stgPk16;
      #pragma unroll
      for (int q = 0; q < 4; q++){
        int i = tid + 256*q;
        dIn[i]  = sIn[i];
        dOut[i] = sOut[i];
        dPk[i]  = sPk[i];
      }
    }
  } else {
    int b = blockIdx.x;
    for (int idx = tid; idx < LSEQ*128; idx += 256){
      size_t off = (size_t)b*LSEQ*128 + idx;
      float v = sy[off] + sz[off];
      if (s0s) v += s0s[off];
      u.sh[idx] = v;
      seq_in[off] = v;
    }
    __syncthreads();
    int g = tid;  // 0..255
    float accf[LSEQ], accb[LSEQ];
    float bf = bsum_f[g], bb = bsum_b[g];
    #pragma unroll
    for (int l = 0; l < LSEQ; l++){ accf[l] = bf; accb[l] = bb; }
    const float* wfp = Wih_f + (size_t)g*128;
    const float* wbp = Wih_b + (size_t)g*128;
    for (int kc = 0; kc < 128; kc += 16){
      float4 wf[4], wb[4];
      #pragma unroll
      for (int q = 0; q < 4; q++){
        wf[q] = *(const float4*)(wfp + kc + 4*q);
        wb[q] = *(const float4*)(wbp + kc + 4*q);
      }
      #pragma unroll
      for (int l = 0; l < LSEQ; l++){
        #pragma unroll
        for (int q = 0; q < 4; q++){
          float4 s4 = *(const float4*)&u.sh[l*128 + kc + 4*q];
          accf[l] += s4.x*wf[q].x + s4.y*wf[q].y + s4.z*wf[q].z + s4.w*wf[q].w;
          accb[l] += s4.x*wb[q].x + s4.y*wb[q].y + s4.z*wb[q].z + s4.w*wb[q].w;
        }
      }
    }
    for (int l = 0; l < LSEQ; l++){
      pre_f[((size_t)b*LSEQ + l)*G4 + g] = accf[l];
      pre_b[((size_t)b*LSEQ + l)*G4 + g] = accb[l];
    }
  }
}

// ---------------------------------------------------------------- per-step kernel B
// blocks [0,Bb): LSTM recurrence + seq LN
// blocks [Bb, Bb+N/32): edge gather — wave owns 4 consecutive nodes; both directions
//   interleaved per iteration (8 gathers in flight), no barriers in gather path.
__global__ __launch_bounds__(512) void k_B(
  const unsigned* __restrict__ G_in, const unsigned* __restrict__ G_out,
  const unsigned* __restrict__ PownPk,
  const float* __restrict__ struct_in, float* __restrict__ struct_out,
  const int* __restrict__ offs_s, const int4* __restrict__ adj_s,
  const int* __restrict__ offs_d, const int4* __restrict__ adj_d,
  const float* __restrict__ WEin, const float* __restrict__ WEout,
  const float* __restrict__ ln_st_g, const float* __restrict__ ln_st_b,
  const float* __restrict__ pre_f, const float* __restrict__ pre_b,
  const float* __restrict__ Whh_f, const float* __restrict__ Whh_b,
  const float* __restrict__ seq_in, float* __restrict__ seq_out,
  const float* __restrict__ ln_seq_g, const float* __restrict__ ln_seq_b,
  int N, int Bb, int E2)
{
  __shared__ float h_hist[2][LSEQ][64];
  __shared__ float hcur[2][64];
  __shared__ float gsh[2][G4];
  if ((int)blockIdx.x >= Bb){
    int wv = threadIdx.x >> 6, lane = threadIdx.x & 63;
    int n0 = ((blockIdx.x - Bb)*8 + wv)*4;           // 4 consecutive nodes per wave
    const float2* WEi2 = (const float2*)WEin;
    const float2* WEo2 = (const float2*)WEout;
    float2 wi0 = WEi2[lane], wi1 = WEi2[64+lane], wi2 = WEi2[128+lane];
    float2 wo0 = WEo2[lane], wo1 = WEo2[64+lane], wo2 = WEo2[128+lane];
    float2 g2v = ((const float2*)ln_st_g)[lane], be2 = ((const float2*)ln_st_b)[lane];
    const uint2* Gi = (const uint2*)G_in;
    const uint2* Go = (const uint2*)G_out;
    const u32x4* As = (const u32x4*)adj_s;
    const u32x4* Ad = (const u32x4*)adj_d;
    #pragma unroll 1
    for (int n = n0; n < n0+4; ++n){
      u32x2 pw = *((const u32x2*)PownPk + (size_t)n*64 + lane);
      float2 pp0 = unpack_h2(pw.x), pp1 = unpack_h2(pw.y);
      float2 poI = make_float2(pp0.x, pp1.x);
      float2 poO = make_float2(pp0.y, pp1.y);
      float ax = 0.f, ay = 0.f;
      int js0 = __builtin_amdgcn_readfirstlane(offs_s[n]);
      int js1 = __builtin_amdgcn_readfirstlane(offs_s[n+1]);
      int jd0 = __builtin_amdgcn_readfirstlane(offs_d[n]);
      int jd1 = __builtin_amdgcn_readfirstlane(offs_d[n+1]);
      int jbs = js0, jbd = jd0;
      while (jbs < js1 || jbd < jd1){
        int bs = (jbs < js1) ? jbs : E2;     // exhausted side reads zero padding
        int bd = (jbd < jd1) ? jbd : E2;
        u32x4 as0 = As[bs], as1 = As[bs+1], as2 = As[bs+2], as3 = As[bs+3];
        u32x4 ad0 = Ad[bd], ad1 = Ad[bd+1], ad2 = Ad[bd+2], ad3 = Ad[bd+3];
        uint2 gs0 = Gi[(size_t)as0.x*64 + lane];
        uint2 gs1 = Gi[(size_t)as1.x*64 + lane];
        uint2 gs2 = Gi[(size_t)as2.x*64 + lane];
        uint2 gs3 = Gi[(size_t)as3.x*64 + lane];
        uint2 gd0 = Go[(size_t)ad0.x*64 + lane];
        uint2 gd1 = Go[(size_t)ad1.x*64 + lane];
        uint2 gd2 = Go[(size_t)ad2.x*64 + lane];
        uint2 gd3 = Go[(size_t)ad3.x*64 + lane];
        int rs = js1 - jbs, rd = jd1 - jbd;
        edge_acc(as0, gs0, rs>0, poI, wi0, wi1, wi2, ax, ay);
        edge_acc(as1, gs1, rs>1, poI, wi0, wi1, wi2, ax, ay);
        edge_acc(as2, gs2, rs>2, poI, wi0, wi1, wi2, ax, ay);
        edge_acc(as3, gs3, rs>3, poI, wi0, wi1, wi2, ax, ay);
        edge_acc(ad0, gd0, rd>0, poO, wo0, wo1, wo2, ax, ay);
        edge_acc(ad1, gd1, rd>1, poO, wo0, wo1, wo2, ax, ay);
        edge_acc(ad2, gd2, rd>2, poO, wo0, wo1, wo2, ax, ay);
        edge_acc(ad3, gd3, rd>3, poO, wo0, wo1, wo2, ax, ay);
        jbs += 4; jbd += 4;
      }
      float2 sn = ((const float2*)struct_in)[(size_t)n*64 + lane];
      float vx = sn.x + ax;
      float vy = sn.y + ay;
      float s = vx+vy, sq = vx*vx + vy*vy;
      #pragma unroll
      for (int o = 32; o; o >>= 1){ s += __shfl_xor(s, o); sq += __shfl_xor(sq, o); }
      float mean = s*(1.f/128.f);
      float inv = rsqrtf(sq*(1.f/128.f) - mean*mean + EPSF);
      float2 o2;
      o2.x = (vx-mean)*inv*g2v.x + be2.x;
      o2.y = (vy-mean)*inv*g2v.y + be2.y;
      ((float2*)struct_out)[(size_t)n*64 + lane] = o2;
    }
  } else {
    int b = blockIdx.x;
    int tid = threadIdx.x;
    int dir = tid >> 8, g = tid & 255;
    const float* Whh = dir ? Whh_b : Whh_f;
    const float* pre = dir ? pre_b : pre_f;
    float w[64];
    #pragma unroll
    for (int q = 0; q < 16; q++){
      float4 t4 = *(const float4*)(Whh + (size_t)g*64 + 4*q);
      w[4*q] = t4.x; w[4*q+1] = t4.y; w[4*q+2] = t4.z; w[4*q+3] = t4.w;
    }
    float c = 0.f;
    for (int t = 0; t < LSEQ; ++t){
      int tt = dir ? (LSEQ-1-t) : t;
      float gate = pre[((size_t)b*LSEQ + tt)*G4 + g];
      if (t > 0){
        #pragma unroll
        for (int q = 0; q < 16; q++){
          float4 h4 = *(const float4*)&hcur[dir][4*q];
          gate += w[4*q]*h4.x + w[4*q+1]*h4.y + w[4*q+2]*h4.z + w[4*q+3]*h4.w;
        }
      }
      gsh[dir][g] = gate;
      __syncthreads();
      if (g < 64){
        float iv = gsh[dir][g], fv = gsh[dir][64+g], gv = gsh[dir][128+g], ov = gsh[dir][192+g];
        c = sigf(fv)*c + sigf(iv)*tanhf(gv);
        float h = sigf(ov)*tanhf(c);
        hcur[dir][g] = h;
        h_hist[dir][tt][g] = h;
      }
      __syncthreads();
    }
    int wv = tid >> 6, lane = tid & 63;
    for (int l = wv; l < LSEQ; l += 8){
      float2 sv = ((const float2*)(seq_in + ((size_t)b*LSEQ + l)*128))[lane];
      float hv0, hv1;
      if (lane < 32){ hv0 = h_hist[0][l][2*lane];    hv1 = h_hist[0][l][2*lane+1]; }
      else          { hv0 = h_hist[1][l][2*lane-64]; hv1 = h_hist[1][l][2*lane-63]; }
      float vx = sv.x + hv0, vy = sv.y + hv1;
      float s = vx+vy, sq = vx*vx + vy*vy;
      #pragma unroll
      for (int o = 32; o; o >>= 1){ s += __shfl_xor(s, o); sq += __shfl_xor(sq, o); }
      float mean = s*(1.f/128.f);
      float inv = rsqrtf(sq*(1.f/128.f) - mean*mean + EPSF);
      float2 g2 = ((const float2*)ln_seq_g)[lane], b2 = ((const float2*)ln_seq_b)[lane];
      float2 o2;
      o2.x = (vx-mean)*inv*g2.x + b2.x;
      o2.y = (vy-mean)*inv*g2.y + b2.y;
      ((float2*)(seq_out + ((size_t)b*LSEQ + l)*128))[lane] = o2;
    }
  }
}

// ---------------------------------------------------------------- epilogue
__global__ void k_final(float* __restrict__ out, const float* __restrict__ sy,
                        const float* __restrict__ ty, const int* __restrict__ starts,
                        const float* __restrict__ g, const float* __restrict__ b,
                        const float* __restrict__ rm, const float* __restrict__ rv, int Bb){
  int i = blockIdx.x*blockDim.x + threadIdx.x;
  if (i >= Bb*D) return;
  int bb = i >> 7, d = i & 127;
  float feat = sy[((size_t)bb*LSEQ + 10)*D + d] + ty[(size_t)starts[bb]*D + d];
  out[i] = (feat - rm[d])*rsqrtf(rv[d]+EPSF)*g[d] + b[d];
}

// ---------------------------------------------------------------- host
extern "C" void kernel_launch(void* const* d_in, const int* in_sizes, int n_in,
                              void* d_out, int out_size, void* d_ws, size_t ws_size,
                              hipStream_t stream)
{
  const float* x        = (const float*)d_in[0];
  const int*   ei       = (const int*)  d_in[1];
  const float* eattr    = (const float*)d_in[2];
  const int*   batch    = (const int*)  d_in[3];
  const float* hotslice = (const float*)d_in[4];
  const float* nsy      = (const float*)d_in[5];
  const float* nsz      = (const float*)d_in[6];
  const float* nty      = (const float*)d_in[7];
  const float* ntz      = (const float*)d_in[8];
  const float* W_esm    = (const float*)d_in[9];
  const float* b_esm    = (const float*)d_in[10];
  const float* W_node   = (const float*)d_in[11];
  const float* b_node   = (const float*)d_in[12];
  const float* W_seq    = (const float*)d_in[13];
  const float* b_seq    = (const float*)d_in[14];
  const float* ln_seq_g = (const float*)d_in[15];
  const float* ln_seq_b = (const float*)d_in[16];
  const float* ln_st_g  = (const float*)d_in[17];
  const float* ln_st_b  = (const float*)d_in[18];
  const float* W_in     = (const float*)d_in[19];
  const float* b_in     = (const float*)d_in[20];
  const float* W_out    = (const float*)d_in[21];
  const float* b_out    = (const float*)d_in[22];
  const float* Wih_f    = (const float*)d_in[23];
  const float* Whh_f    = (const float*)d_in[24];
  const float* bih_f    = (const float*)d_in[25];
  const float* bhh_f    = (const float*)d_in[26];
  const float* Wih_b    = (const float*)d_in[27];
  const float* Whh_b    = (const float*)d_in[28];
  const float* bih_b    = (const float*)d_in[29];
  const float* bhh_b    = (const float*)d_in[30];
  const float* bn_g     = (const float*)d_in[31];
  const float* bn_b     = (const float*)d_in[32];
  const float* bn_rm    = (const float*)d_in[33];
  const float* bn_rv    = (const float*)d_in[34];

  const int N  = in_sizes[0] / 2561;
  const int E  = in_sizes[1] / 2;
  const int E2 = E / 2;
  const int Bb = in_sizes[4] / (LSEQ*28);
  const int BL = Bb*LSEQ;

  // ---- workspace carve
  char* p = (char*)d_ws;
  auto alloc = [&](size_t bytes)->void*{
    void* r = (void*)p; p += (bytes + 255) & ~(size_t)255; return r;
  };
  float*    seq0      = (float*)alloc((size_t)BL*D*4);
  float*    sy        = (float*)alloc((size_t)BL*D*4);
  float*    sz        = (float*)alloc((size_t)BL*D*4);
  float*    seq_in    = (float*)alloc((size_t)BL*D*4);
  float*    pre_f     = (float*)alloc((size_t)BL*G4*4);
  float*    pre_b     = (float*)alloc((size_t)BL*G4*4);
  float*    struct0   = (float*)alloc((size_t)N*D*4);
  float*    ty        = (float*)alloc((size_t)N*D*4);
  float*    tz        = (float*)alloc((size_t)N*D*4);
  float*    struct_in = (float*)alloc((size_t)N*D*4);
  unsigned* G_in      = (unsigned*)alloc((size_t)N*D*4);
  unsigned* G_out     = (unsigned*)alloc((size_t)N*D*4);
  unsigned* PownPk    = (unsigned*)alloc((size_t)N*D*4);
  u16*      PB4h      = (u16*)alloc(65536*2);
  u16*      PB4l      = (u16*)alloc(65536*2);
  u16*      PBnh      = (u16*)alloc(16384*2);
  u16*      PBnl      = (u16*)alloc(16384*2);
  u16*      PBEh      = (u16*)alloc(327680*2);
  u16*      PBEl      = (u16*)alloc(327680*2);
  float*    WEin      = (float*)alloc(384*4);
  float*    WEout     = (float*)alloc(384*4);
  float*    bsum_f    = (float*)alloc(256*4);
  float*    bsum_b    = (float*)alloc(256*4);
  int*      starts    = (int*)alloc((size_t)Bb*4);
  int*      cnt_s     = (int*)alloc((size_t)N*4);
  int*      cnt_d     = (int*)alloc((size_t)N*4);
  int*      offs_s    = (int*)alloc((size_t)(N+1)*4);
  int*      offs_d    = (int*)alloc((size_t)(N+1)*4);
  int*      cur_s     = (int*)alloc((size_t)N*4);
  int*      cur_d     = (int*)alloc((size_t)N*4);
  int4*     adj_s     = (int4*)alloc((size_t)(E2+8)*16);
  int4*     adj_d     = (int4*)alloc((size_t)(E2+8)*16);
  (void)ws_size; (void)n_in; (void)out_size;

  // ---- init state from noise inputs
  hipMemcpyAsync(sy, nsy, (size_t)BL*D*4, hipMemcpyDeviceToDevice, stream);
  hipMemcpyAsync(sz, nsz, (size_t)BL*D*4, hipMemcpyDeviceToDevice, stream);
  hipMemcpyAsync(ty, nty, (size_t)N*D*4, hipMemcpyDeviceToDevice, stream);
  hipMemcpyAsync(tz, ntz, (size_t)N*D*4, hipMemcpyDeviceToDevice, stream);

  // ---- prologue
  k_misc<<<1, 256, 0, stream>>>(starts, batch, N, Bb, WEin, WEout, W_in, W_out,
                                bsum_f, bsum_b, bih_f, bhh_f, bih_b, bhh_b);
  k_packB<<<1600, 256, 0, stream>>>(PB4h, PB4l, PBnh, PBnl, PBEh, PBEl,
                                    W_in, W_out, W_node, W_esm);
  k_seq0<<<BL, 128, 0, stream>>>(seq0, hotslice, W_seq, b_seq);
  k_esm2<<<N/32, 256, 0, stream>>>(struct0, x, PBEh, PBEl, PBnh, PBnl,
                                   b_esm, W_node, b_node);
  k_zero2<<<(N+255)/256, 256, 0, stream>>>(cnt_s, cnt_d, N);
  k_count<<<(E2+255)/256, 256, 0, stream>>>(cnt_s, cnt_d, ei, E2);
  k_scan<<<1, 1024, 0, stream>>>(cnt_s, offs_s, N);
  k_scan<<<1, 1024, 0, stream>>>(cnt_d, offs_d, N);
  k_copy2<<<(N+255)/256, 256, 0, stream>>>(cur_s, offs_s, cur_d, offs_d, N);
  k_fill<<<(E2+255)/256, 256, 0, stream>>>(ei, eattr, E2, cur_s, adj_s, cur_d, adj_d);
  k_pad<<<1, 64, 0, stream>>>(adj_s, adj_d, E2);

  const int NB_T1 = N/32;
  const int NB_T2 = N/32;   // gather: 8 waves/block x 4 nodes/wave = 32 nodes/block

  // ---- main loop: 8 outer x (4 inner + 1)
  for (int o = 0; o < 8; ++o){
    for (int it = 0; it < 5; ++it){
      bool inner = (it < 4);
      const float* s0s = inner ? seq0 : nullptr;
      const float* s0t = inner ? struct0 : nullptr;
      float* so = inner ? sz : sy;
      float* to = inner ? tz : ty;
      k_A<<<Bb + NB_T1, 256, 0, stream>>>(s0t, ty, tz, struct_in, PB4h, PB4l,
                                          G_in, G_out, PownPk, b_in, b_out,
                                          s0s, sy, sz, seq_in, pre_f, pre_b,
                                          Wih_f, Wih_b, bsum_f, bsum_b, N, Bb);
      k_B<<<Bb + NB_T2, 512, 0, stream>>>(G_in, G_out, PownPk, struct_in, to,
                                          offs_s, adj_s, offs_d, adj_d,
                                          WEin, WEout, ln_st_g, ln_st_b,
                                          pre_f, pre_b, Whh_f, Whh_b, seq_in, so,
                                          ln_seq_g, ln_seq_b, N, Bb, E2);
    }
  }

  k_final<<<(Bb*D+255)/256, 256, 0, stream>>>((float*)d_out, sy, ty, starts,
                                              bn_g, bn_b, bn_rm, bn_rv, Bb);
}

// Round 10
// 4359.651 us; speedup vs baseline: 1.0324x; 1.0324x over previous
//
#include <hip/hip_runtime.h>
#include <hip/hip_fp16.h>
#include <math.h>

#define D 128
#define G4 256
#define LSEQ 21
#define EPSF 1e-5f

typedef unsigned short u16;
typedef __attribute__((ext_vector_type(8))) short bf16x8;
typedef __attribute__((ext_vector_type(4))) float f32x4;
typedef __attribute__((ext_vector_type(2))) unsigned u32x2;
typedef __attribute__((ext_vector_type(4))) unsigned u32x4;

#define MFMA16(a,b,c) __builtin_amdgcn_mfma_f32_16x16x32_bf16(a,b,c,0,0,0)

// ---------------------------------------------------------------- helpers
__device__ __forceinline__ float sigf(float x){ return 1.0f/(1.0f+__expf(-x)); }
__device__ __forceinline__ u16 f2bf(float x){
  unsigned u = __float_as_uint(x);
  return (u16)((u + 0x7FFFu + ((u>>16)&1u)) >> 16);
}
__device__ __forceinline__ float bf2f(u16 h){ return __uint_as_float(((unsigned)h)<<16); }
__device__ __forceinline__ unsigned pack_h2(float a, float b){
  __half2 h = __floats2half2_rn(a, b);
  return *(unsigned*)&h;
}
__device__ __forceinline__ float2 unpack_h2(unsigned u){
  __half2 h = *(__half2*)&u;
  return __half22float2(h);
}
__device__ __forceinline__ u16 f2h(float v){ __half h = __float2half(v); return *(u16*)&h; }

__device__ __forceinline__ void edge_acc(u32x4 a, uint2 g, bool valid,
                                         float2 po2, float2 w0, float2 w1, float2 w2,
                                         float& ax, float& ay){
  float e0=__uint_as_float(a.y), e1=__uint_as_float(a.z), e2=__uint_as_float(a.w);
  float2 ps0 = unpack_h2(g.x);   // {P(ch0), S(ch0)}
  float2 ps1 = unpack_h2(g.y);   // {P(ch1), S(ch1)}
  float gx = po2.x + ps0.x + e0*w0.x + e1*w1.x + e2*w2.x;
  float gy = po2.y + ps1.x + e0*w0.y + e1*w1.y + e2*w2.y;
  float mm = valid ? 1.f : 0.f;
  ax = fmaf(ps0.y*mm, sigf(gx), ax);
  ay = fmaf(ps1.y*mm, sigf(gy), ay);
}

// ---------------------------------------------------------------- prologue kernels
__global__ void k_misc(int* __restrict__ starts, const int* __restrict__ batch, int N, int Bb,
                       float* __restrict__ WEin, float* __restrict__ WEout,
                       const float* __restrict__ W_in, const float* __restrict__ W_out,
                       float* __restrict__ bsum_f, float* __restrict__ bsum_b,
                       const float* __restrict__ bih_f, const float* __restrict__ bhh_f,
                       const float* __restrict__ bih_b, const float* __restrict__ bhh_b){
  int tid = threadIdx.x;
  if (tid < Bb){
    int lo = 0, hi = N;
    while (lo < hi){ int m = (lo+hi)>>1; if (batch[m] < tid) lo = m+1; else hi = m; }
    starts[tid] = lo;
  }
  for (int i = tid; i < 384; i += 256){
    int t = i >> 7, j = i & 127;
    WEin [i] = W_in [(size_t)j*259 + 256 + t];
    WEout[i] = W_out[(size_t)j*259 + 256 + t];
  }
  if (tid < 256){
    bsum_f[tid] = bih_f[tid] + bhh_f[tid];
    bsum_b[tid] = bih_b[tid] + bhh_b[tid];
  }
}

// pre-pack MFMA B-fragments (hi/lo bf16), layout [nt][ks][lane][8] contiguous
__global__ void k_packB(u16* __restrict__ PB4h, u16* __restrict__ PB4l,
                        u16* __restrict__ PBnh, u16* __restrict__ PBnl,
                        u16* __restrict__ PBEh, u16* __restrict__ PBEl,
                        const float* __restrict__ W_in, const float* __restrict__ W_out,
                        const float* __restrict__ W_node, const float* __restrict__ W_esm){
  int idx = blockIdx.x*256 + threadIdx.x;
  if (idx < 65536){
    int j = idx&7, l=(idx>>3)&63, q=idx>>9;
    int ks = q&3, nt = q>>2;
    int c = nt*16 + (l&15);
    int k = ks*32 + ((l>>4)<<3) + j;
    float v;
    if (c < 128)      v = W_in [(size_t)c*259 + k];
    else if (c < 256) v = W_in [(size_t)(c-128)*259 + 128 + k];
    else if (c < 384) v = W_out[(size_t)(c-256)*259 + k];
    else              v = W_out[(size_t)(c-384)*259 + 128 + k];
    u16 h = f2bf(v);
    PB4h[idx] = h; PB4l[idx] = f2bf(v - bf2f(h));
  } else if (idx < 65536 + 16384){
    int p = idx - 65536;
    int j = p&7, l=(p>>3)&63, q=p>>9;
    int ks = q&3, nt = q>>2;
    int c = nt*16 + (l&15);
    int k = ks*32 + ((l>>4)<<3) + j;
    float v = W_node[(size_t)c*129 + k];
    u16 h = f2bf(v);
    PBnh[p] = h; PBnl[p] = f2bf(v - bf2f(h));
  } else if (idx < 65536 + 16384 + 327680){
    int p = idx - 81920;
    int j = p&7, l=(p>>3)&63, q=p>>9;
    int ks = q%80, nt = q/80;
    int c = nt*16 + (l&15);
    int k = ks*32 + ((l>>4)<<3) + j;
    float v = W_esm[(size_t)c*2560 + k];
    u16 h = f2bf(v);
    PBEh[p] = h; PBEl[p] = f2bf(v - bf2f(h));
  }
}

__global__ void k_seq0(float* __restrict__ seq0, const float* __restrict__ hot,
                       const float* __restrict__ W_seq, const float* __restrict__ b_seq){
  int row = blockIdx.x, j = threadIdx.x;           // 128 threads
  const float* h = hot + (size_t)row*28;
  const float* w = W_seq + (size_t)j*28;
  float acc = b_seq[j];
  #pragma unroll
  for (int k = 0; k < 28; k++) acc += h[k]*w[k];
  seq0[(size_t)row*D + j] = acc;
}

// fused: esm = x[:,1:] @ W_esm.T + b_esm ; struct0 = [esm, x[:,:1]] @ W_node.T + b_node
// single launch, register double-buffered staging, conflict-free LDS writes (R8 pattern)
__global__ __launch_bounds__(256) void k_esm2(float* __restrict__ struct0, const float* __restrict__ x,
    const u16* __restrict__ PBEh, const u16* __restrict__ PBEl,
    const u16* __restrict__ PBnh, const u16* __restrict__ PBnl,
    const float* __restrict__ b_esm, const float* __restrict__ W_node,
    const float* __restrict__ b_node){
  __shared__ union {
    struct { u16 xh[32*72], xl[32*72]; } p1;
    struct { u16 Ah[32*136], Al[32*136]; } p2;
  } uu;
  __shared__ float esmF[32*132];
  int tid = threadIdx.x;
  int r0 = blockIdx.x*32;
  int w = tid>>6, l = tid&63;
  f32x4 acc[2][2];
  #pragma unroll
  for (int a=0;a<2;a++)
    #pragma unroll
    for (int b=0;b<2;b++) acc[a][b] = (f32x4){0.f,0.f,0.f,0.f};

  float xv[8];
  int rr = tid >> 5, k2i = tid & 31;      // rows rr, rr+8, rr+16, rr+24 ; col pair k2i
  #pragma unroll
  for (int q = 0; q < 4; q++){
    const float* src = x + (size_t)(r0+rr+8*q)*2561 + 1 + k2i*2;
    xv[2*q]   = src[0];
    xv[2*q+1] = src[1];
  }
  for (int kc = 0; kc < 2560; kc += 64){
    __syncthreads();
    unsigned* xh32 = (unsigned*)uu.p1.xh;
    unsigned* xl32 = (unsigned*)uu.p1.xl;
    #pragma unroll
    for (int q = 0; q < 4; q++){
      float v0 = xv[2*q], v1 = xv[2*q+1];
      u16 h0 = f2bf(v0), h1 = f2bf(v1);
      u16 l0 = f2bf(v0 - bf2f(h0)), l1 = f2bf(v1 - bf2f(h1));
      int r = rr + 8*q;
      xh32[r*36 + k2i] = (unsigned)h0 | ((unsigned)h1 << 16);
      xl32[r*36 + k2i] = (unsigned)l0 | ((unsigned)l1 << 16);
    }
    __syncthreads();
    if (kc + 64 < 2560){
      #pragma unroll
      for (int q = 0; q < 4; q++){
        const float* src = x + (size_t)(r0+rr+8*q)*2561 + 1 + kc + 64 + k2i*2;
        xv[2*q]   = src[0];
        xv[2*q+1] = src[1];
      }
    }
    #pragma unroll
    for (int ks = 0; ks < 2; ks++){
      bf16x8 ah[2], al[2];
      #pragma unroll
      for (int rt = 0; rt < 2; rt++){
        int row = rt*16 + (l&15);
        int k = ks*32 + ((l>>4)<<3);
        ah[rt] = *(const bf16x8*)&uu.p1.xh[row*72 + k];
        al[rt] = *(const bf16x8*)&uu.p1.xl[row*72 + k];
      }
      int ksg = (kc>>5) + ks;
      #pragma unroll
      for (int ctl = 0; ctl < 2; ctl++){
        int nt = w*2 + ctl;
        bf16x8 bh = *(const bf16x8*)&PBEh[((size_t)(nt*80 + ksg)*64 + l)*8];
        bf16x8 bl = *(const bf16x8*)&PBEl[((size_t)(nt*80 + ksg)*64 + l)*8];
        #pragma unroll
        for (int rt = 0; rt < 2; rt++){
          acc[rt][ctl] = MFMA16(ah[rt], bh, acc[rt][ctl]);
          acc[rt][ctl] = MFMA16(al[rt], bh, acc[rt][ctl]);
          acc[rt][ctl] = MFMA16(ah[rt], bl, acc[rt][ctl]);
        }
      }
    }
  }
  __syncthreads();
  int cq = l & 15, rqb = (l>>4)*4;
  #pragma unroll
  for (int ctl = 0; ctl < 2; ctl++){
    int coln = (w*2+ctl)*16 + cq;
    float be = b_esm[coln];
    #pragma unroll
    for (int rt = 0; rt < 2; rt++)
      #pragma unroll
      for (int r = 0; r < 4; r++)
        esmF[(rt*16+rqb+r)*132 + coln] = acc[rt][ctl][r] + be;
  }
  __syncthreads();
  {
    unsigned* Ah32 = (unsigned*)uu.p2.Ah;
    unsigned* Al32 = (unsigned*)uu.p2.Al;
    int rr2 = tid >> 6, k2 = tid & 63;   // 4 rows/iter, 64 col-pairs
    #pragma unroll
    for (int q = 0; q < 8; q++){
      int r = rr2 + 4*q;
      float v0 = esmF[r*132 + k2*2];
      float v1 = esmF[r*132 + k2*2 + 1];
      u16 h0 = f2bf(v0), h1 = f2bf(v1);
      u16 l0 = f2bf(v0 - bf2f(h0)), l1 = f2bf(v1 - bf2f(h1));
      Ah32[r*68 + k2] = (unsigned)h0 | ((unsigned)h1 << 16);
      Al32[r*68 + k2] = (unsigned)l0 | ((unsigned)l1 << 16);
    }
  }
  __syncthreads();
  f32x4 acc2[2][2];
  #pragma unroll
  for (int a=0;a<2;a++)
    #pragma unroll
    for (int b=0;b<2;b++) acc2[a][b] = (f32x4){0.f,0.f,0.f,0.f};
  #pragma unroll
  for (int ks = 0; ks < 4; ks++){
    bf16x8 ah[2], al[2];
    #pragma unroll
    for (int rt = 0; rt < 2; rt++){
      int row = rt*16 + (l&15);
      int k = ks*32 + ((l>>4)<<3);
      ah[rt] = *(const bf16x8*)&uu.p2.Ah[row*136 + k];
      al[rt] = *(const bf16x8*)&uu.p2.Al[row*136 + k];
    }
    #pragma unroll
    for (int ctl = 0; ctl < 2; ctl++){
      int nt = w*2 + ctl;
      bf16x8 bh = *(const bf16x8*)&PBnh[((size_t)(nt*4 + ks)*64 + l)*8];
      bf16x8 bl = *(const bf16x8*)&PBnl[((size_t)(nt*4 + ks)*64 + l)*8];
      #pragma unroll
      for (int rt = 0; rt < 2; rt++){
        acc2[rt][ctl] = MFMA16(ah[rt], bh, acc2[rt][ctl]);
        acc2[rt][ctl] = MFMA16(al[rt], bh, acc2[rt][ctl]);
        acc2[rt][ctl] = MFMA16(ah[rt], bl, acc2[rt][ctl]);
      }
    }
  }
  #pragma unroll
  for (int ctl = 0; ctl < 2; ctl++){
    int col = (w*2+ctl)*16 + cq;
    float wl = W_node[(size_t)col*129 + 128];
    float bn = b_node[col];
    #pragma unroll
    for (int rt = 0; rt < 2; rt++)
      #pragma unroll
      for (int r = 0; r < 4; r++){
        int row = r0 + rt*16 + rqb + r;
        float x0 = x[(size_t)row*2561];
        struct0[(size_t)row*D + col] = acc2[rt][ctl][r] + x0*wl + bn;
      }
  }
}

// ---------------------------------------------------------------- CSR build
__global__ void k_zero2(int* a, int* b, int n){
  int i = blockIdx.x*blockDim.x + threadIdx.x;
  if (i < n){ a[i] = 0; b[i] = 0; }
}
__global__ void k_count(int* cnt_s, int* cnt_d, const int* __restrict__ ei, int E2){
  int e = blockIdx.x*blockDim.x + threadIdx.x;
  if (e < E2){
    atomicAdd(&cnt_s[ei[2*e]], 1);
    atomicAdd(&cnt_d[ei[2*E2 + 2*e]], 1);
  }
}
__global__ __launch_bounds__(1024) void k_scan(const int* __restrict__ cnt, int* __restrict__ offs, int n){
  __shared__ int sh[1024];
  __shared__ int sbase;
  int tid = threadIdx.x;
  if (tid == 0) sbase = 0;
  __syncthreads();
  for (int chunk = 0; chunk < n; chunk += 1024){
    int v = (chunk+tid < n) ? cnt[chunk+tid] : 0;
    sh[tid] = v;
    __syncthreads();
    for (int off = 1; off < 1024; off <<= 1){
      int t = (tid >= off) ? sh[tid-off] : 0;
      __syncthreads();
      sh[tid] += t;
      __syncthreads();
    }
    if (chunk+tid < n) offs[chunk+tid] = sbase + sh[tid] - v;
    __syncthreads();
    if (tid == 0) sbase += sh[1023];
    __syncthreads();
  }
  if (tid == 0) offs[n] = sbase;
}
__global__ void k_copy2(int* cur_s, const int* offs_s, int* cur_d, const int* offs_d, int n){
  int i = blockIdx.x*blockDim.x + threadIdx.x;
  if (i < n){ cur_s[i] = offs_s[i]; cur_d[i] = offs_d[i]; }
}
__global__ void k_fill(const int* __restrict__ ei, const float* __restrict__ eattr, int E2,
                       int* cur_s, int4* __restrict__ adj_s,
                       int* cur_d, int4* __restrict__ adj_d){
  int e = blockIdx.x*blockDim.x + threadIdx.x;
  if (e >= E2) return;
  int s = ei[2*e];
  int d = ei[2*E2 + 2*e];
  const float* ein  = eattr + (size_t)(2*e+1)*3;
  const float* eout = eattr + (size_t)(2*e)*3;
  int ps = atomicAdd(&cur_s[s], 1);
  adj_s[ps] = make_int4(d, __float_as_int(ein[0]),  __float_as_int(ein[1]),  __float_as_int(ein[2]));
  int pd = atomicAdd(&cur_d[d], 1);
  adj_d[pd] = make_int4(s, __float_as_int(eout[0]), __float_as_int(eout[1]), __float_as_int(eout[2]));
}
__global__ void k_pad(int4* __restrict__ adj_s, int4* __restrict__ adj_d, int E2){
  int t = threadIdx.x;
  if (t < 8){
    adj_s[E2+t] = make_int4(0,0,0,0);
    adj_d[E2+t] = make_int4(0,0,0,0);
  }
}

// ---------------------------------------------------------------- per-step kernel A
// blocks [0,Bb): seq pre-GEMM ; blocks [Bb,..): struct GEMM + coalesced table writes
__global__ __launch_bounds__(256) void k_A(
  const float* __restrict__ s0t, const float* __restrict__ ty, const float* __restrict__ tz,
  float* __restrict__ struct_in,
  const u16* __restrict__ PB4h, const u16* __restrict__ PB4l,
  unsigned* __restrict__ G_in, unsigned* __restrict__ G_out,
  unsigned* __restrict__ PownPk,
  const float* __restrict__ b_in, const float* __restrict__ b_out,
  const float* __restrict__ s0s, const float* __restrict__ sy, const float* __restrict__ sz,
  float* __restrict__ seq_in, float* __restrict__ pre_f, float* __restrict__ pre_b,
  const float* __restrict__ Wih_f, const float* __restrict__ Wih_b,
  const float* __restrict__ bsum_f, const float* __restrict__ bsum_b,
  int N, int Bb)
{
  __shared__ union {
    struct { u16 Ah[32*136], Al[32*136]; float Sf[32*132]; } m;
    float sh[LSEQ*128];
  } u;
  int tid = threadIdx.x;
  if ((int)blockIdx.x >= Bb){
    int r0 = (blockIdx.x - Bb)*32;
    const float4* ty4 = (const float4*)(ty + (size_t)r0*D);
    const float4* tz4 = (const float4*)(tz + (size_t)r0*D);
    const float4* s04 = s0t ? (const float4*)(s0t + (size_t)r0*D) : nullptr;
    float4* si4 = (float4*)(struct_in + (size_t)r0*D);
    #pragma unroll
    for (int q = 0; q < 4; q++){
      int i = tid + 256*q;          // float4 index, 0..1023
      int r = i >> 5, k4 = i & 31;
      float4 v = ty4[i];
      float4 z = tz4[i];
      v.x += z.x; v.y += z.y; v.z += z.z; v.w += z.w;
      if (s04){ float4 s = s04[i]; v.x += s.x; v.y += s.y; v.z += s.z; v.w += s.w; }
      si4[i] = v;
      u16 h0 = f2bf(v.x), h1 = f2bf(v.y), h2 = f2bf(v.z), h3 = f2bf(v.w);
      *(ushort4*)&u.m.Ah[r*136 + k4*4] = make_ushort4(h0,h1,h2,h3);
      *(ushort4*)&u.m.Al[r*136 + k4*4] = make_ushort4(
          f2bf(v.x - bf2f(h0)), f2bf(v.y - bf2f(h1)),
          f2bf(v.z - bf2f(h2)), f2bf(v.w - bf2f(h3)));
      *(float4*)&u.m.Sf[r*132 + k4*4] = v;
    }
    __syncthreads();
    int w = tid >> 6, l = tid & 63;
    f32x4 acc[2][8];
    #pragma unroll
    for (int a=0;a<2;a++)
      #pragma unroll
      for (int b=0;b<8;b++) acc[a][b] = (f32x4){0.f,0.f,0.f,0.f};
    #pragma unroll
    for (int ks = 0; ks < 4; ks++){
      bf16x8 ah[2], al[2];
      #pragma unroll
      for (int rt = 0; rt < 2; rt++){
        int row = rt*16 + (l&15);
        int k = ks*32 + ((l>>4)<<3);
        ah[rt] = *(const bf16x8*)&u.m.Ah[row*136 + k];
        al[rt] = *(const bf16x8*)&u.m.Al[row*136 + k];
      }
      #pragma unroll
      for (int ct = 0; ct < 8; ct++){
        int nt = w*8 + ct;
        bf16x8 bh = *(const bf16x8*)&PB4h[((size_t)(nt*4 + ks)*64 + l)*8];
        bf16x8 bl = *(const bf16x8*)&PB4l[((size_t)(nt*4 + ks)*64 + l)*8];
        #pragma unroll
        for (int rt = 0; rt < 2; rt++){
          acc[rt][ct] = MFMA16(ah[rt], bh, acc[rt][ct]);
          acc[rt][ct] = MFMA16(al[rt], bh, acc[rt][ct]);
          acc[rt][ct] = MFMA16(ah[rt], bl, acc[rt][ct]);
        }
      }
    }
    // ---- coalesced table epilogue via LDS staging (reuses Ah/Al region) ----
    __syncthreads();                      // MFMA done reading Ah/Al
    unsigned* stg = (unsigned*)u.m.Ah;    // 32*128 u32 = 16KB (fits in Ah+Al)
    u16* stg16 = (u16*)u.m.Ah;
    int cq = l & 15, rqb = (l>>4)*4;
    // G_in (wave 1 holds quadrant 1 = P_in_d)
    if (w == 1){
      #pragma unroll
      for (int ct = 0; ct < 8; ct++){
        int coln = ct*16 + cq;
        #pragma unroll
        for (int rt = 0; rt < 2; rt++){
          #pragma unroll
          for (int r = 0; r < 4; r++){
            int lr = rt*16 + rqb + r;
            stg[lr*128 + coln] = pack_h2(acc[rt][ct][r], u.m.Sf[lr*132 + coln]);
          }
        }
      }
    }
    __syncthreads();
    {
      uint4* dst = (uint4*)(G_in + (size_t)r0*D);
      const uint4* src = (const uint4*)stg;
      #pragma unroll
      for (int q = 0; q < 4; q++) dst[tid + 256*q] = src[tid + 256*q];
    }
    __syncthreads();
    // G_out (wave 2 holds quadrant 2 = P_out_s)
    if (w == 2){
      #pragma unroll
      for (int ct = 0; ct < 8; ct++){
        int coln = ct*16 + cq;
        #pragma unroll
        for (int rt = 0; rt < 2; rt++){
          #pragma unroll
          for (int r = 0; r < 4; r++){
            int lr = rt*16 + rqb + r;
            stg[lr*128 + coln] = pack_h2(acc[rt][ct][r], u.m.Sf[lr*132 + coln]);
          }
        }
      }
    }
    __syncthreads();
    {
      uint4* dst = (uint4*)(G_out + (size_t)r0*D);
      const uint4* src = (const uint4*)stg;
      #pragma unroll
      for (int q = 0; q < 4; q++) dst[tid + 256*q] = src[tid + 256*q];
    }
    __syncthreads();
    // PownPk: wave 0 low half (+b_in), wave 3 high half (+b_out)
    if (w == 0 || w == 3){
      const float* bb = (w == 0) ? b_in : b_out;
      int half = (w == 0) ? 0 : 1;
      #pragma unroll
      for (int ct = 0; ct < 8; ct++){
        int coln = ct*16 + cq;
        float bc = bb[coln];
        #pragma unroll
        for (int rt = 0; rt < 2; rt++){
          #pragma unroll
          for (int r = 0; r < 4; r++){
            int lr = rt*16 + rqb + r;
            stg16[(lr*128 + coln)*2 + half] = f2h(acc[rt][ct][r] + bc);
          }
        }
      }
    }
    __syncthreads();
    {
      uint4* dst = (uint4*)(PownPk + (size_t)r0*D);
      const uint4* src = (const uint4*)stg;
      #pragma unroll
      for (int q = 0; q < 4; q++) dst[tid + 256*q] = src[tid + 256*q];
    }
  } else {
    int b = blockIdx.x;
    for (int idx = tid; idx < LSEQ*128; idx += 256){
      size_t off = (size_t)b*LSEQ*128 + idx;
      float v = sy[off] + sz[off];
      if (s0s) v += s0s[off];
      u.sh[idx] = v;
      seq_in[off] = v;
    }
    __syncthreads();
    int g = tid;  // 0..255
    float accf[LSEQ], accb[LSEQ];
    float bf = bsum_f[g], bb = bsum_b[g];
    #pragma unroll
    for (int l = 0; l < LSEQ; l++){ accf[l] = bf; accb[l] = bb; }
    const float* wfp = Wih_f + (size_t)g*128;
    const float* wbp = Wih_b + (size_t)g*128;
    for (int kc = 0; kc < 128; kc += 16){
      float4 wf[4], wb[4];
      #pragma unroll
      for (int q = 0; q < 4; q++){
        wf[q] = *(const float4*)(wfp + kc + 4*q);
        wb[q] = *(const float4*)(wbp + kc + 4*q);
      }
      #pragma unroll
      for (int l = 0; l < LSEQ; l++){
        #pragma unroll
        for (int q = 0; q < 4; q++){
          float4 s4 = *(const float4*)&u.sh[l*128 + kc + 4*q];
          accf[l] += s4.x*wf[q].x + s4.y*wf[q].y + s4.z*wf[q].z + s4.w*wf[q].w;
          accb[l] += s4.x*wb[q].x + s4.y*wb[q].y + s4.z*wb[q].z + s4.w*wb[q].w;
        }
      }
    }
    for (int l = 0; l < LSEQ; l++){
      pre_f[((size_t)b*LSEQ + l)*G4 + g] = accf[l];
      pre_b[((size_t)b*LSEQ + l)*G4 + g] = accb[l];
    }
  }
}

// ---------------------------------------------------------------- per-step kernel B
// blocks [0,Bb): LSTM recurrence + seq LN
// blocks [Bb, Bb+N/32): edge gather — each wave owns 4 consecutive nodes end-to-end
//   (both directions + LN), no inter-wave coupling, no __syncthreads in this path.
__global__ __launch_bounds__(512) void k_B(
  const unsigned* __restrict__ G_in, const unsigned* __restrict__ G_out,
  const unsigned* __restrict__ PownPk,
  const float* __restrict__ struct_in, float* __restrict__ struct_out,
  const int* __restrict__ offs_s, const int4* __restrict__ adj_s,
  const int* __restrict__ offs_d, const int4* __restrict__ adj_d,
  const float* __restrict__ WEin, const float* __restrict__ WEout,
  const float* __restrict__ ln_st_g, const float* __restrict__ ln_st_b,
  const float* __restrict__ pre_f, const float* __restrict__ pre_b,
  const float* __restrict__ Whh_f, const float* __restrict__ Whh_b,
  const float* __restrict__ seq_in, float* __restrict__ seq_out,
  const float* __restrict__ ln_seq_g, const float* __restrict__ ln_seq_b,
  int N, int Bb)
{
  __shared__ float h_hist[2][LSEQ][64];
  __shared__ float hcur[2][64];
  __shared__ float gsh[2][G4];
  if ((int)blockIdx.x >= Bb){
    int wv = threadIdx.x >> 6, lane = threadIdx.x & 63;
    int n0 = ((blockIdx.x - Bb)*8 + wv)*4;           // 4 consecutive nodes per wave
    const float2* WEi2 = (const float2*)WEin;
    const float2* WEo2 = (const float2*)WEout;
    float2 wi0 = WEi2[lane], wi1 = WEi2[64+lane], wi2 = WEi2[128+lane];
    float2 wo0 = WEo2[lane], wo1 = WEo2[64+lane], wo2 = WEo2[128+lane];
    float2 g2v = ((const float2*)ln_st_g)[lane], be2 = ((const float2*)ln_st_b)[lane];
    const uint2* Gi = (const uint2*)G_in;
    const uint2* Go = (const uint2*)G_out;
    #pragma unroll 1
    for (int n = n0; n < n0+4; ++n){
      u32x2 pw = *((const u32x2*)PownPk + (size_t)n*64 + lane);
      float2 pp0 = unpack_h2(pw.x), pp1 = unpack_h2(pw.y);
      float2 poI = make_float2(pp0.x, pp1.x);
      float2 poO = make_float2(pp0.y, pp1.y);
      float ax = 0.f, ay = 0.f;
      int j0 = __builtin_amdgcn_readfirstlane(offs_s[n]);
      int j1 = __builtin_amdgcn_readfirstlane(offs_s[n+1]);
      for (int jb = j0; jb < j1; jb += 4){
        int rem = j1 - jb;
        const u32x4* ap = (const u32x4*)adj_s + jb;
        u32x4 a0 = ap[0], a1 = ap[1], a2 = ap[2], a3 = ap[3];
        uint2 g0 = Gi[(size_t)a0.x*64 + lane];
        uint2 g1 = Gi[(size_t)a1.x*64 + lane];
        uint2 g2 = Gi[(size_t)a2.x*64 + lane];
        uint2 g3 = Gi[(size_t)a3.x*64 + lane];
        edge_acc(a0, g0, true,  poI, wi0, wi1, wi2, ax, ay);
        edge_acc(a1, g1, rem>1, poI, wi0, wi1, wi2, ax, ay);
        edge_acc(a2, g2, rem>2, poI, wi0, wi1, wi2, ax, ay);
        edge_acc(a3, g3, rem>3, poI, wi0, wi1, wi2, ax, ay);
      }
      j0 = __builtin_amdgcn_readfirstlane(offs_d[n]);
      j1 = __builtin_amdgcn_readfirstlane(offs_d[n+1]);
      for (int jb = j0; jb < j1; jb += 4){
        int rem = j1 - jb;
        const u32x4* ap = (const u32x4*)adj_d + jb;
        u32x4 a0 = ap[0], a1 = ap[1], a2 = ap[2], a3 = ap[3];
        uint2 g0 = Go[(size_t)a0.x*64 + lane];
        uint2 g1 = Go[(size_t)a1.x*64 + lane];
        uint2 g2 = Go[(size_t)a2.x*64 + lane];
        uint2 g3 = Go[(size_t)a3.x*64 + lane];
        edge_acc(a0, g0, true,  poO, wo0, wo1, wo2, ax, ay);
        edge_acc(a1, g1, rem>1, poO, wo0, wo1, wo2, ax, ay);
        edge_acc(a2, g2, rem>2, poO, wo0, wo1, wo2, ax, ay);
        edge_acc(a3, g3, rem>3, poO, wo0, wo1, wo2, ax, ay);
      }
      float2 sn = ((const float2*)struct_in)[(size_t)n*64 + lane];
      float vx = sn.x + ax;
      float vy = sn.y + ay;
      float s = vx+vy, sq = vx*vx + vy*vy;
      #pragma unroll
      for (int o = 32; o; o >>= 1){ s += __shfl_xor(s, o); sq += __shfl_xor(sq, o); }
      float mean = s*(1.f/128.f);
      float inv = rsqrtf(sq*(1.f/128.f) - mean*mean + EPSF);
      float2 o2;
      o2.x = (vx-mean)*inv*g2v.x + be2.x;
      o2.y = (vy-mean)*inv*g2v.y + be2.y;
      ((float2*)struct_out)[(size_t)n*64 + lane] = o2;
    }
  } else {
    int b = blockIdx.x;
    int tid = threadIdx.x;
    int dir = tid >> 8, g = tid & 255;
    const float* Whh = dir ? Whh_b : Whh_f;
    const float* pre = dir ? pre_b : pre_f;
    float w[64];
    #pragma unroll
    for (int q = 0; q < 16; q++){
      float4 t4 = *(const float4*)(Whh + (size_t)g*64 + 4*q);
      w[4*q] = t4.x; w[4*q+1] = t4.y; w[4*q+2] = t4.z; w[4*q+3] = t4.w;
    }
    float c = 0.f;
    for (int t = 0; t < LSEQ; ++t){
      int tt = dir ? (LSEQ-1-t) : t;
      float gate = pre[((size_t)b*LSEQ + tt)*G4 + g];
      if (t > 0){
        #pragma unroll
        for (int q = 0; q < 16; q++){
          float4 h4 = *(const float4*)&hcur[dir][4*q];
          gate += w[4*q]*h4.x + w[4*q+1]*h4.y + w[4*q+2]*h4.z + w[4*q+3]*h4.w;
        }
      }
      gsh[dir][g] = gate;
      __syncthreads();
      if (g < 64){
        float iv = gsh[dir][g], fv = gsh[dir][64+g], gv = gsh[dir][128+g], ov = gsh[dir][192+g];
        c = sigf(fv)*c + sigf(iv)*tanhf(gv);
        float h = sigf(ov)*tanhf(c);
        hcur[dir][g] = h;
        h_hist[dir][tt][g] = h;
      }
      __syncthreads();
    }
    int wv = tid >> 6, lane = tid & 63;
    for (int l = wv; l < LSEQ; l += 8){
      float2 sv = ((const float2*)(seq_in + ((size_t)b*LSEQ + l)*128))[lane];
      float hv0, hv1;
      if (lane < 32){ hv0 = h_hist[0][l][2*lane];    hv1 = h_hist[0][l][2*lane+1]; }
      else          { hv0 = h_hist[1][l][2*lane-64]; hv1 = h_hist[1][l][2*lane-63]; }
      float vx = sv.x + hv0, vy = sv.y + hv1;
      float s = vx+vy, sq = vx*vx + vy*vy;
      #pragma unroll
      for (int o = 32; o; o >>= 1){ s += __shfl_xor(s, o); sq += __shfl_xor(sq, o); }
      float mean = s*(1.f/128.f);
      float inv = rsqrtf(sq*(1.f/128.f) - mean*mean + EPSF);
      float2 g2 = ((const float2*)ln_seq_g)[lane], b2 = ((const float2*)ln_seq_b)[lane];
      float2 o2;
      o2.x = (vx-mean)*inv*g2.x + b2.x;
      o2.y = (vy-mean)*inv*g2.y + b2.y;
      ((float2*)(seq_out + ((size_t)b*LSEQ + l)*128))[lane] = o2;
    }
  }
}

// ---------------------------------------------------------------- epilogue
__global__ void k_final(float* __restrict__ out, const float* __restrict__ sy,
                        const float* __restrict__ ty, const int* __restrict__ starts,
                        const float* __restrict__ g, const float* __restrict__ b,
                        const float* __restrict__ rm, const float* __restrict__ rv, int Bb){
  int i = blockIdx.x*blockDim.x + threadIdx.x;
  if (i >= Bb*D) return;
  int bb = i >> 7, d = i & 127;
  float feat = sy[((size_t)bb*LSEQ + 10)*D + d] + ty[(size_t)starts[bb]*D + d];
  out[i] = (feat - rm[d])*rsqrtf(rv[d]+EPSF)*g[d] + b[d];
}

// ---------------------------------------------------------------- host
extern "C" void kernel_launch(void* const* d_in, const int* in_sizes, int n_in,
                              void* d_out, int out_size, void* d_ws, size_t ws_size,
                              hipStream_t stream)
{
  const float* x        = (const float*)d_in[0];
  const int*   ei       = (const int*)  d_in[1];
  const float* eattr    = (const float*)d_in[2];
  const int*   batch    = (const int*)  d_in[3];
  const float* hotslice = (const float*)d_in[4];
  const float* nsy      = (const float*)d_in[5];
  const float* nsz      = (const float*)d_in[6];
  const float* nty      = (const float*)d_in[7];
  const float* ntz      = (const float*)d_in[8];
  const float* W_esm    = (const float*)d_in[9];
  const float* b_esm    = (const float*)d_in[10];
  const float* W_node   = (const float*)d_in[11];
  const float* b_node   = (const float*)d_in[12];
  const float* W_seq    = (const float*)d_in[13];
  const float* b_seq    = (const float*)d_in[14];
  const float* ln_seq_g = (const float*)d_in[15];
  const float* ln_seq_b = (const float*)d_in[16];
  const float* ln_st_g  = (const float*)d_in[17];
  const float* ln_st_b  = (const float*)d_in[18];
  const float* W_in     = (const float*)d_in[19];
  const float* b_in     = (const float*)d_in[20];
  const float* W_out    = (const float*)d_in[21];
  const float* b_out    = (const float*)d_in[22];
  const float* Wih_f    = (const float*)d_in[23];
  const float* Whh_f    = (const float*)d_in[24];
  const float* bih_f    = (const float*)d_in[25];
  const float* bhh_f    = (const float*)d_in[26];
  const float* Wih_b    = (const float*)d_in[27];
  const float* Whh_b    = (const float*)d_in[28];
  const float* bih_b    = (const float*)d_in[29];
  const float* bhh_b    = (const float*)d_in[30];
  const float* bn_g     = (const float*)d_in[31];
  const float* bn_b     = (const float*)d_in[32];
  const float* bn_rm    = (const float*)d_in[33];
  const float* bn_rv    = (const float*)d_in[34];

  const int N  = in_sizes[0] / 2561;
  const int E  = in_sizes[1] / 2;
  const int E2 = E / 2;
  const int Bb = in_sizes[4] / (LSEQ*28);
  const int BL = Bb*LSEQ;

  // ---- workspace carve
  char* p = (char*)d_ws;
  auto alloc = [&](size_t bytes)->void*{
    void* r = (void*)p; p += (bytes + 255) & ~(size_t)255; return r;
  };
  float*    seq0      = (float*)alloc((size_t)BL*D*4);
  float*    sy        = (float*)alloc((size_t)BL*D*4);
  float*    sz        = (float*)alloc((size_t)BL*D*4);
  float*    seq_in    = (float*)alloc((size_t)BL*D*4);
  float*    pre_f     = (float*)alloc((size_t)BL*G4*4);
  float*    pre_b     = (float*)alloc((size_t)BL*G4*4);
  float*    struct0   = (float*)alloc((size_t)N*D*4);
  float*    ty        = (float*)alloc((size_t)N*D*4);
  float*    tz        = (float*)alloc((size_t)N*D*4);
  float*    struct_in = (float*)alloc((size_t)N*D*4);
  unsigned* G_in      = (unsigned*)alloc((size_t)N*D*4);
  unsigned* G_out     = (unsigned*)alloc((size_t)N*D*4);
  unsigned* PownPk    = (unsigned*)alloc((size_t)N*D*4);
  u16*      PB4h      = (u16*)alloc(65536*2);
  u16*      PB4l      = (u16*)alloc(65536*2);
  u16*      PBnh      = (u16*)alloc(16384*2);
  u16*      PBnl      = (u16*)alloc(16384*2);
  u16*      PBEh      = (u16*)alloc(327680*2);
  u16*      PBEl      = (u16*)alloc(327680*2);
  float*    WEin      = (float*)alloc(384*4);
  float*    WEout     = (float*)alloc(384*4);
  float*    bsum_f    = (float*)alloc(256*4);
  float*    bsum_b    = (float*)alloc(256*4);
  int*      starts    = (int*)alloc((size_t)Bb*4);
  int*      cnt_s     = (int*)alloc((size_t)N*4);
  int*      cnt_d     = (int*)alloc((size_t)N*4);
  int*      offs_s    = (int*)alloc((size_t)(N+1)*4);
  int*      offs_d    = (int*)alloc((size_t)(N+1)*4);
  int*      cur_s     = (int*)alloc((size_t)N*4);
  int*      cur_d     = (int*)alloc((size_t)N*4);
  int4*     adj_s     = (int4*)alloc((size_t)(E2+8)*16);
  int4*     adj_d     = (int4*)alloc((size_t)(E2+8)*16);
  (void)ws_size; (void)n_in; (void)out_size;

  // ---- init state from noise inputs
  hipMemcpyAsync(sy, nsy, (size_t)BL*D*4, hipMemcpyDeviceToDevice, stream);
  hipMemcpyAsync(sz, nsz, (size_t)BL*D*4, hipMemcpyDeviceToDevice, stream);
  hipMemcpyAsync(ty, nty, (size_t)N*D*4, hipMemcpyDeviceToDevice, stream);
  hipMemcpyAsync(tz, ntz, (size_t)N*D*4, hipMemcpyDeviceToDevice, stream);

  // ---- prologue
  k_misc<<<1, 256, 0, stream>>>(starts, batch, N, Bb, WEin, WEout, W_in, W_out,
                                bsum_f, bsum_b, bih_f, bhh_f, bih_b, bhh_b);
  k_packB<<<1600, 256, 0, stream>>>(PB4h, PB4l, PBnh, PBnl, PBEh, PBEl,
                                    W_in, W_out, W_node, W_esm);
  k_seq0<<<BL, 128, 0, stream>>>(seq0, hotslice, W_seq, b_seq);
  k_esm2<<<N/32, 256, 0, stream>>>(struct0, x, PBEh, PBEl, PBnh, PBnl,
                                   b_esm, W_node, b_node);
  k_zero2<<<(N+255)/256, 256, 0, stream>>>(cnt_s, cnt_d, N);
  k_count<<<(E2+255)/256, 256, 0, stream>>>(cnt_s, cnt_d, ei, E2);
  k_scan<<<1, 1024, 0, stream>>>(cnt_s, offs_s, N);
  k_scan<<<1, 1024, 0, stream>>>(cnt_d, offs_d, N);
  k_copy2<<<(N+255)/256, 256, 0, stream>>>(cur_s, offs_s, cur_d, offs_d, N);
  k_fill<<<(E2+255)/256, 256, 0, stream>>>(ei, eattr, E2, cur_s, adj_s, cur_d, adj_d);
  k_pad<<<1, 64, 0, stream>>>(adj_s, adj_d, E2);

  const int NB_T1 = N/32;
  const int NB_T2 = N/32;   // gather: 8 waves/block x 4 nodes/wave = 32 nodes/block

  // ---- main loop: 8 outer x (4 inner + 1)
  for (int o = 0; o < 8; ++o){
    for (int it = 0; it < 5; ++it){
      bool inner = (it < 4);
      const float* s0s = inner ? seq0 : nullptr;
      const float* s0t = inner ? struct0 : nullptr;
      float* so = inner ? sz : sy;
      float* to = inner ? tz : ty;
      k_A<<<Bb + NB_T1, 256, 0, stream>>>(s0t, ty, tz, struct_in, PB4h, PB4l,
                                          G_in, G_out, PownPk, b_in, b_out,
                                          s0s, sy, sz, seq_in, pre_f, pre_b,
                                          Wih_f, Wih_b, bsum_f, bsum_b, N, Bb);
      k_B<<<Bb + NB_T2, 512, 0, stream>>>(G_in, G_out, PownPk, struct_in, to,
                                          offs_s, adj_s, offs_d, adj_d,
                                          WEin, WEout, ln_st_g, ln_st_b,
                                          pre_f, pre_b, Whh_f, Whh_b, seq_in, so,
                                          ln_seq_g, ln_seq_b, N, Bb);
    }
  }

  k_final<<<(Bb*D+255)/256, 256, 0, stream>>>((float*)d_out, sy, ty, starts,
                                              bn_g, bn_b, bn_rm, bn_rv, Bb);
}

// Round 11
// 4280.096 us; speedup vs baseline: 1.0516x; 1.0186x over previous
//
#include <hip/hip_runtime.h>
#include <hip/hip_fp16.h>
#include <math.h>

#define D 128
#define G4 256
#define LSEQ 21
#define EPSF 1e-5f

typedef unsigned short u16;
typedef __attribute__((ext_vector_type(8))) short bf16x8;
typedef __attribute__((ext_vector_type(4))) float f32x4;
typedef __attribute__((ext_vector_type(2))) unsigned u32x2;
typedef __attribute__((ext_vector_type(4))) unsigned u32x4;

#define MFMA16(a,b,c) __builtin_amdgcn_mfma_f32_16x16x32_bf16(a,b,c,0,0,0)

// ---------------------------------------------------------------- helpers
__device__ __forceinline__ float sigf(float x){ return 1.0f/(1.0f+__expf(-x)); }
__device__ __forceinline__ u16 f2bf(float x){
  unsigned u = __float_as_uint(x);
  return (u16)((u + 0x7FFFu + ((u>>16)&1u)) >> 16);
}
__device__ __forceinline__ float bf2f(u16 h){ return __uint_as_float(((unsigned)h)<<16); }
__device__ __forceinline__ unsigned pack_h2(float a, float b){
  __half2 h = __floats2half2_rn(a, b);
  return *(unsigned*)&h;
}
__device__ __forceinline__ float2 unpack_h2(unsigned u){
  __half2 h = *(__half2*)&u;
  return __half22float2(h);
}
__device__ __forceinline__ u16 f2h(float v){ __half h = __float2half(v); return *(u16*)&h; }

__device__ __forceinline__ void edge_acc(u32x4 a, uint2 g, bool valid,
                                         float2 po2, float2 w0, float2 w1, float2 w2,
                                         float& ax, float& ay){
  float e0=__uint_as_float(a.y), e1=__uint_as_float(a.z), e2=__uint_as_float(a.w);
  float2 ps0 = unpack_h2(g.x);   // {P(ch0), S(ch0)}
  float2 ps1 = unpack_h2(g.y);   // {P(ch1), S(ch1)}
  float gx = po2.x + ps0.x + e0*w0.x + e1*w1.x + e2*w2.x;
  float gy = po2.y + ps1.x + e0*w0.y + e1*w1.y + e2*w2.y;
  float mm = valid ? 1.f : 0.f;
  ax = fmaf(ps0.y*mm, sigf(gx), ax);
  ay = fmaf(ps1.y*mm, sigf(gy), ay);
}

// ---------------------------------------------------------------- prologue kernels
__global__ void k_misc(int* __restrict__ starts, const int* __restrict__ batch, int N, int Bb,
                       float* __restrict__ WEin, float* __restrict__ WEout,
                       const float* __restrict__ W_in, const float* __restrict__ W_out,
                       float* __restrict__ bsum_f, float* __restrict__ bsum_b,
                       const float* __restrict__ bih_f, const float* __restrict__ bhh_f,
                       const float* __restrict__ bih_b, const float* __restrict__ bhh_b){
  int tid = threadIdx.x;
  if (tid < Bb){
    int lo = 0, hi = N;
    while (lo < hi){ int m = (lo+hi)>>1; if (batch[m] < tid) lo = m+1; else hi = m; }
    starts[tid] = lo;
  }
  for (int i = tid; i < 384; i += 256){
    int t = i >> 7, j = i & 127;
    WEin [i] = W_in [(size_t)j*259 + 256 + t];
    WEout[i] = W_out[(size_t)j*259 + 256 + t];
  }
  if (tid < 256){
    bsum_f[tid] = bih_f[tid] + bhh_f[tid];
    bsum_b[tid] = bih_b[tid] + bhh_b[tid];
  }
}

// pre-pack MFMA B-fragments (hi/lo bf16), layout [nt][ks][lane][8] contiguous
__global__ void k_packB(u16* __restrict__ PB4h, u16* __restrict__ PB4l,
                        u16* __restrict__ PBnh, u16* __restrict__ PBnl,
                        u16* __restrict__ PBEh, u16* __restrict__ PBEl,
                        const float* __restrict__ W_in, const float* __restrict__ W_out,
                        const float* __restrict__ W_node, const float* __restrict__ W_esm){
  int idx = blockIdx.x*256 + threadIdx.x;
  if (idx < 65536){
    int j = idx&7, l=(idx>>3)&63, q=idx>>9;
    int ks = q&3, nt = q>>2;
    int c = nt*16 + (l&15);
    int k = ks*32 + ((l>>4)<<3) + j;
    float v;
    if (c < 128)      v = W_in [(size_t)c*259 + k];
    else if (c < 256) v = W_in [(size_t)(c-128)*259 + 128 + k];
    else if (c < 384) v = W_out[(size_t)(c-256)*259 + k];
    else              v = W_out[(size_t)(c-384)*259 + 128 + k];
    u16 h = f2bf(v);
    PB4h[idx] = h; PB4l[idx] = f2bf(v - bf2f(h));
  } else if (idx < 65536 + 16384){
    int p = idx - 65536;
    int j = p&7, l=(p>>3)&63, q=p>>9;
    int ks = q&3, nt = q>>2;
    int c = nt*16 + (l&15);
    int k = ks*32 + ((l>>4)<<3) + j;
    float v = W_node[(size_t)c*129 + k];
    u16 h = f2bf(v);
    PBnh[p] = h; PBnl[p] = f2bf(v - bf2f(h));
  } else if (idx < 65536 + 16384 + 327680){
    int p = idx - 81920;
    int j = p&7, l=(p>>3)&63, q=p>>9;
    int ks = q%80, nt = q/80;
    int c = nt*16 + (l&15);
    int k = ks*32 + ((l>>4)<<3) + j;
    float v = W_esm[(size_t)c*2560 + k];
    u16 h = f2bf(v);
    PBEh[p] = h; PBEl[p] = f2bf(v - bf2f(h));
  }
}

__global__ void k_seq0(float* __restrict__ seq0, const float* __restrict__ hot,
                       const float* __restrict__ W_seq, const float* __restrict__ b_seq){
  int row = blockIdx.x, j = threadIdx.x;           // 128 threads
  const float* h = hot + (size_t)row*28;
  const float* w = W_seq + (size_t)j*28;
  float acc = b_seq[j];
  #pragma unroll
  for (int k = 0; k < 28; k++) acc += h[k]*w[k];
  seq0[(size_t)row*D + j] = acc;
}

// fused: esm = x[:,1:] @ W_esm.T + b_esm ; struct0 = [esm, x[:,:1]] @ W_node.T + b_node
// software-pipelined: LDS double-buffer + depth-2 register prefetch, 1 barrier/chunk
__global__ __launch_bounds__(256) void k_esm2(float* __restrict__ struct0, const float* __restrict__ x,
    const u16* __restrict__ PBEh, const u16* __restrict__ PBEl,
    const u16* __restrict__ PBnh, const u16* __restrict__ PBnl,
    const float* __restrict__ b_esm, const float* __restrict__ W_node,
    const float* __restrict__ b_node){
  __shared__ union {
    struct { u16 xh[2][32*72], xl[2][32*72]; } p1;
    struct { u16 Ah[32*136], Al[32*136]; } p2;
  } uu;
  __shared__ float esmF[32*132];
  int tid = threadIdx.x;
  int r0 = blockIdx.x*32;
  int w = tid>>6, l = tid&63;
  f32x4 acc[2][2];
  #pragma unroll
  for (int a=0;a<2;a++)
    #pragma unroll
    for (int b=0;b<2;b++) acc[a][b] = (f32x4){0.f,0.f,0.f,0.f};

  int rr = tid >> 5, k2i = tid & 31;      // rows rr, rr+8, rr+16, rr+24 ; col pair k2i
  float xv[8], xw[8];
  auto loadx = [&](float* dst, int kc){
    #pragma unroll
    for (int q = 0; q < 4; q++){
      const float* src = x + (size_t)(r0+rr+8*q)*2561 + 1 + kc + k2i*2;
      dst[2*q]   = src[0];
      dst[2*q+1] = src[1];
    }
  };
  auto stage = [&](const float* vv, int buf){
    unsigned* xh32 = (unsigned*)uu.p1.xh[buf];
    unsigned* xl32 = (unsigned*)uu.p1.xl[buf];
    #pragma unroll
    for (int q = 0; q < 4; q++){
      float v0 = vv[2*q], v1 = vv[2*q+1];
      u16 h0 = f2bf(v0), h1 = f2bf(v1);
      u16 l0 = f2bf(v0 - bf2f(h0)), l1 = f2bf(v1 - bf2f(h1));
      int r = rr + 8*q;
      xh32[r*36 + k2i] = (unsigned)h0 | ((unsigned)h1 << 16);
      xl32[r*36 + k2i] = (unsigned)l0 | ((unsigned)l1 << 16);
    }
  };
  loadx(xv, 0);
  loadx(xw, 64);
  stage(xv, 0);
  #pragma unroll
  for (int q = 0; q < 8; q++) xv[q] = xw[q];
  loadx(xw, 128);
  __syncthreads();
  int cur = 0;
  for (int kc = 0; kc < 2560; kc += 64){
    // LDS[cur] holds chunk kc; xv holds chunk kc+64; xw loading chunk kc+128
    if (kc + 64 < 2560) stage(xv, cur^1);
    #pragma unroll
    for (int ks = 0; ks < 2; ks++){
      bf16x8 ah[2], al[2];
      #pragma unroll
      for (int rt = 0; rt < 2; rt++){
        int row = rt*16 + (l&15);
        int k = ks*32 + ((l>>4)<<3);
        ah[rt] = *(const bf16x8*)&uu.p1.xh[cur][row*72 + k];
        al[rt] = *(const bf16x8*)&uu.p1.xl[cur][row*72 + k];
      }
      int ksg = (kc>>5) + ks;
      #pragma unroll
      for (int ctl = 0; ctl < 2; ctl++){
        int nt = w*2 + ctl;
        bf16x8 bh = *(const bf16x8*)&PBEh[((size_t)(nt*80 + ksg)*64 + l)*8];
        bf16x8 bl = *(const bf16x8*)&PBEl[((size_t)(nt*80 + ksg)*64 + l)*8];
        #pragma unroll
        for (int rt = 0; rt < 2; rt++){
          acc[rt][ctl] = MFMA16(ah[rt], bh, acc[rt][ctl]);
          acc[rt][ctl] = MFMA16(al[rt], bh, acc[rt][ctl]);
          acc[rt][ctl] = MFMA16(ah[rt], bl, acc[rt][ctl]);
        }
      }
    }
    #pragma unroll
    for (int q = 0; q < 8; q++) xv[q] = xw[q];
    if (kc + 192 < 2560) loadx(xw, kc + 192);
    __syncthreads();
    cur ^= 1;
  }
  int cq = l & 15, rqb = (l>>4)*4;
  #pragma unroll
  for (int ctl = 0; ctl < 2; ctl++){
    int coln = (w*2+ctl)*16 + cq;
    float be = b_esm[coln];
    #pragma unroll
    for (int rt = 0; rt < 2; rt++)
      #pragma unroll
      for (int r = 0; r < 4; r++)
        esmF[(rt*16+rqb+r)*132 + coln] = acc[rt][ctl][r] + be;
  }
  __syncthreads();
  {
    unsigned* Ah32 = (unsigned*)uu.p2.Ah;
    unsigned* Al32 = (unsigned*)uu.p2.Al;
    int rr2 = tid >> 6, k2 = tid & 63;   // 4 rows/iter, 64 col-pairs
    #pragma unroll
    for (int q = 0; q < 8; q++){
      int r = rr2 + 4*q;
      float v0 = esmF[r*132 + k2*2];
      float v1 = esmF[r*132 + k2*2 + 1];
      u16 h0 = f2bf(v0), h1 = f2bf(v1);
      u16 l0 = f2bf(v0 - bf2f(h0)), l1 = f2bf(v1 - bf2f(h1));
      Ah32[r*68 + k2] = (unsigned)h0 | ((unsigned)h1 << 16);
      Al32[r*68 + k2] = (unsigned)l0 | ((unsigned)l1 << 16);
    }
  }
  __syncthreads();
  f32x4 acc2[2][2];
  #pragma unroll
  for (int a=0;a<2;a++)
    #pragma unroll
    for (int b=0;b<2;b++) acc2[a][b] = (f32x4){0.f,0.f,0.f,0.f};
  #pragma unroll
  for (int ks = 0; ks < 4; ks++){
    bf16x8 ah[2], al[2];
    #pragma unroll
    for (int rt = 0; rt < 2; rt++){
      int row = rt*16 + (l&15);
      int k = ks*32 + ((l>>4)<<3);
      ah[rt] = *(const bf16x8*)&uu.p2.Ah[row*136 + k];
      al[rt] = *(const bf16x8*)&uu.p2.Al[row*136 + k];
    }
    #pragma unroll
    for (int ctl = 0; ctl < 2; ctl++){
      int nt = w*2 + ctl;
      bf16x8 bh = *(const bf16x8*)&PBnh[((size_t)(nt*4 + ks)*64 + l)*8];
      bf16x8 bl = *(const bf16x8*)&PBnl[((size_t)(nt*4 + ks)*64 + l)*8];
      #pragma unroll
      for (int rt = 0; rt < 2; rt++){
        acc2[rt][ctl] = MFMA16(ah[rt], bh, acc2[rt][ctl]);
        acc2[rt][ctl] = MFMA16(al[rt], bh, acc2[rt][ctl]);
        acc2[rt][ctl] = MFMA16(ah[rt], bl, acc2[rt][ctl]);
      }
    }
  }
  #pragma unroll
  for (int ctl = 0; ctl < 2; ctl++){
    int col = (w*2+ctl)*16 + cq;
    float wl = W_node[(size_t)col*129 + 128];
    float bn = b_node[col];
    #pragma unroll
    for (int rt = 0; rt < 2; rt++)
      #pragma unroll
      for (int r = 0; r < 4; r++){
        int row = r0 + rt*16 + rqb + r;
        float x0 = x[(size_t)row*2561];
        struct0[(size_t)row*D + col] = acc2[rt][ctl][r] + x0*wl + bn;
      }
  }
}

// ---------------------------------------------------------------- CSR build
__global__ void k_zero2(int* a, int* b, int n){
  int i = blockIdx.x*blockDim.x + threadIdx.x;
  if (i < n){ a[i] = 0; b[i] = 0; }
}
__global__ void k_count(int* cnt_s, int* cnt_d, const int* __restrict__ ei, int E2){
  int e = blockIdx.x*blockDim.x + threadIdx.x;
  if (e < E2){
    atomicAdd(&cnt_s[ei[2*e]], 1);
    atomicAdd(&cnt_d[ei[2*E2 + 2*e]], 1);
  }
}
__global__ __launch_bounds__(1024) void k_scan(const int* __restrict__ cnt, int* __restrict__ offs, int n){
  __shared__ int sh[1024];
  __shared__ int sbase;
  int tid = threadIdx.x;
  if (tid == 0) sbase = 0;
  __syncthreads();
  for (int chunk = 0; chunk < n; chunk += 1024){
    int v = (chunk+tid < n) ? cnt[chunk+tid] : 0;
    sh[tid] = v;
    __syncthreads();
    for (int off = 1; off < 1024; off <<= 1){
      int t = (tid >= off) ? sh[tid-off] : 0;
      __syncthreads();
      sh[tid] += t;
      __syncthreads();
    }
    if (chunk+tid < n) offs[chunk+tid] = sbase + sh[tid] - v;
    __syncthreads();
    if (tid == 0) sbase += sh[1023];
    __syncthreads();
  }
  if (tid == 0) offs[n] = sbase;
}
__global__ void k_copy2(int* cur_s, const int* offs_s, int* cur_d, const int* offs_d, int n){
  int i = blockIdx.x*blockDim.x + threadIdx.x;
  if (i < n){ cur_s[i] = offs_s[i]; cur_d[i] = offs_d[i]; }
}
__global__ void k_fill(const int* __restrict__ ei, const float* __restrict__ eattr, int E2,
                       int* cur_s, int4* __restrict__ adj_s,
                       int* cur_d, int4* __restrict__ adj_d){
  int e = blockIdx.x*blockDim.x + threadIdx.x;
  if (e >= E2) return;
  int s = ei[2*e];
  int d = ei[2*E2 + 2*e];
  const float* ein  = eattr + (size_t)(2*e+1)*3;
  const float* eout = eattr + (size_t)(2*e)*3;
  int ps = atomicAdd(&cur_s[s], 1);
  adj_s[ps] = make_int4(d, __float_as_int(ein[0]),  __float_as_int(ein[1]),  __float_as_int(ein[2]));
  int pd = atomicAdd(&cur_d[d], 1);
  adj_d[pd] = make_int4(s, __float_as_int(eout[0]), __float_as_int(eout[1]), __float_as_int(eout[2]));
}
__global__ void k_pad(int4* __restrict__ adj_s, int4* __restrict__ adj_d, int E2){
  int t = threadIdx.x;
  if (t < 8){
    adj_s[E2+t] = make_int4(0,0,0,0);
    adj_d[E2+t] = make_int4(0,0,0,0);
  }
}

// ---------------------------------------------------------------- per-step kernel A
// blocks [0,Bb): seq pre-GEMM ; blocks [Bb,..): struct GEMM + parallel table epilogue
__global__ __launch_bounds__(256) void k_A(
  const float* __restrict__ s0t, const float* __restrict__ ty, const float* __restrict__ tz,
  const u16* __restrict__ PB4h, const u16* __restrict__ PB4l,
  unsigned* __restrict__ G_in, unsigned* __restrict__ G_out,
  unsigned* __restrict__ PownPk,
  const float* __restrict__ b_in, const float* __restrict__ b_out,
  const float* __restrict__ s0s, const float* __restrict__ sy, const float* __restrict__ sz,
  float* __restrict__ seq_in, float* __restrict__ pre_f, float* __restrict__ pre_b,
  const float* __restrict__ Wih_f, const float* __restrict__ Wih_b,
  const float* __restrict__ bsum_f, const float* __restrict__ bsum_b,
  int N, int Bb)
{
  __shared__ union {
    struct { u16 Ah[32*136], Al[32*136]; float Sf[32*132]; unsigned stg2[32*128]; } m;
    float sh[LSEQ*128];
  } u;
  int tid = threadIdx.x;
  if ((int)blockIdx.x >= Bb){
    int r0 = (blockIdx.x - Bb)*32;
    const float4* ty4 = (const float4*)(ty + (size_t)r0*D);
    const float4* tz4 = (const float4*)(tz + (size_t)r0*D);
    const float4* s04 = s0t ? (const float4*)(s0t + (size_t)r0*D) : nullptr;
    #pragma unroll
    for (int q = 0; q < 4; q++){
      int i = tid + 256*q;          // float4 index, 0..1023
      int r = i >> 5, k4 = i & 31;
      float4 v = ty4[i];
      float4 z = tz4[i];
      v.x += z.x; v.y += z.y; v.z += z.z; v.w += z.w;
      if (s04){ float4 s = s04[i]; v.x += s.x; v.y += s.y; v.z += s.z; v.w += s.w; }
      u16 h0 = f2bf(v.x), h1 = f2bf(v.y), h2 = f2bf(v.z), h3 = f2bf(v.w);
      *(ushort4*)&u.m.Ah[r*136 + k4*4] = make_ushort4(h0,h1,h2,h3);
      *(ushort4*)&u.m.Al[r*136 + k4*4] = make_ushort4(
          f2bf(v.x - bf2f(h0)), f2bf(v.y - bf2f(h1)),
          f2bf(v.z - bf2f(h2)), f2bf(v.w - bf2f(h3)));
      *(float4*)&u.m.Sf[r*132 + k4*4] = v;
    }
    __syncthreads();
    int w = tid >> 6, l = tid & 63;
    f32x4 acc[2][8];
    #pragma unroll
    for (int a=0;a<2;a++)
      #pragma unroll
      for (int b=0;b<8;b++) acc[a][b] = (f32x4){0.f,0.f,0.f,0.f};
    #pragma unroll
    for (int ks = 0; ks < 4; ks++){
      bf16x8 ah[2], al[2];
      #pragma unroll
      for (int rt = 0; rt < 2; rt++){
        int row = rt*16 + (l&15);
        int k = ks*32 + ((l>>4)<<3);
        ah[rt] = *(const bf16x8*)&u.m.Ah[row*136 + k];
        al[rt] = *(const bf16x8*)&u.m.Al[row*136 + k];
      }
      #pragma unroll
      for (int ct = 0; ct < 8; ct++){
        int nt = w*8 + ct;
        bf16x8 bh = *(const bf16x8*)&PB4h[((size_t)(nt*4 + ks)*64 + l)*8];
        bf16x8 bl = *(const bf16x8*)&PB4l[((size_t)(nt*4 + ks)*64 + l)*8];
        #pragma unroll
        for (int rt = 0; rt < 2; rt++){
          acc[rt][ct] = MFMA16(ah[rt], bh, acc[rt][ct]);
          acc[rt][ct] = MFMA16(al[rt], bh, acc[rt][ct]);
          acc[rt][ct] = MFMA16(ah[rt], bl, acc[rt][ct]);
        }
      }
    }
    // ---- parallel epilogue: concurrent In/Out fills, pair-wave copies, then Pk ----
    __syncthreads();                      // MFMA done reading Ah/Al
    unsigned* stg1 = (unsigned*)u.m.Ah;   // 16KB region (Ah+Al): G_in staging, then Pk
    unsigned* stg2 = u.m.stg2;            // 16KB region: G_out staging
    int cq = l & 15, rqb = (l>>4)*4;
    if (w == 1){
      #pragma unroll
      for (int ct = 0; ct < 8; ct++){
        int coln = ct*16 + cq;
        #pragma unroll
        for (int rt = 0; rt < 2; rt++)
          #pragma unroll
          for (int r = 0; r < 4; r++){
            int lr = rt*16 + rqb + r;
            stg1[lr*128 + coln] = pack_h2(acc[rt][ct][r], u.m.Sf[lr*132 + coln]);
          }
      }
    } else if (w == 2){
      #pragma unroll
      for (int ct = 0; ct < 8; ct++){
        int coln = ct*16 + cq;
        #pragma unroll
        for (int rt = 0; rt < 2; rt++)
          #pragma unroll
          for (int r = 0; r < 4; r++){
            int lr = rt*16 + rqb + r;
            stg2[lr*128 + coln] = pack_h2(acc[rt][ct][r], u.m.Sf[lr*132 + coln]);
          }
      }
    }
    __syncthreads();
    {
      int grp = w >> 1;                   // waves 0,1 -> G_in ; waves 2,3 -> G_out
      uint4* dst = grp ? (uint4*)(G_out + (size_t)r0*D) : (uint4*)(G_in + (size_t)r0*D);
      const uint4* src = grp ? (const uint4*)stg2 : (const uint4*)stg1;
      int base = (w & 1)*64 + l;          // 0..127 within pair
      #pragma unroll
      for (int q = 0; q < 8; q++) dst[base + 128*q] = src[base + 128*q];
    }
    __syncthreads();
    if (w == 0 || w == 3){
      u16* stgPk16 = (u16*)stg1;
      const float* bb = (w == 0) ? b_in : b_out;
      int half = (w == 0) ? 0 : 1;
      #pragma unroll
      for (int ct = 0; ct < 8; ct++){
        int coln = ct*16 + cq;
        float bc = bb[coln];
        #pragma unroll
        for (int rt = 0; rt < 2; rt++)
          #pragma unroll
          for (int r = 0; r < 4; r++){
            int lr = rt*16 + rqb + r;
            stgPk16[(lr*128 + coln)*2 + half] = f2h(acc[rt][ct][r] + bc);
          }
      }
    }
    __syncthreads();
    {
      uint4* dst = (uint4*)(PownPk + (size_t)r0*D);
      const uint4* src = (const uint4*)stg1;
      #pragma unroll
      for (int q = 0; q < 4; q++) dst[tid + 256*q] = src[tid + 256*q];
    }
  } else {
    int b = blockIdx.x;
    for (int idx = tid; idx < LSEQ*128; idx += 256){
      size_t off = (size_t)b*LSEQ*128 + idx;
      float v = sy[off] + sz[off];
      if (s0s) v += s0s[off];
      u.sh[idx] = v;
      seq_in[off] = v;
    }
    __syncthreads();
    int g = tid;  // 0..255
    float accf[LSEQ], accb[LSEQ];
    float bf = bsum_f[g], bb = bsum_b[g];
    #pragma unroll
    for (int l = 0; l < LSEQ; l++){ accf[l] = bf; accb[l] = bb; }
    const float* wfp = Wih_f + (size_t)g*128;
    const float* wbp = Wih_b + (size_t)g*128;
    for (int kc = 0; kc < 128; kc += 16){
      float4 wf[4], wb[4];
      #pragma unroll
      for (int q = 0; q < 4; q++){
        wf[q] = *(const float4*)(wfp + kc + 4*q);
        wb[q] = *(const float4*)(wbp + kc + 4*q);
      }
      #pragma unroll
      for (int l = 0; l < LSEQ; l++){
        #pragma unroll
        for (int q = 0; q < 4; q++){
          float4 s4 = *(const float4*)&u.sh[l*128 + kc + 4*q];
          accf[l] += s4.x*wf[q].x + s4.y*wf[q].y + s4.z*wf[q].z + s4.w*wf[q].w;
          accb[l] += s4.x*wb[q].x + s4.y*wb[q].y + s4.z*wb[q].z + s4.w*wb[q].w;
        }
      }
    }
    for (int l = 0; l < LSEQ; l++){
      pre_f[((size_t)b*LSEQ + l)*G4 + g] = accf[l];
      pre_b[((size_t)b*LSEQ + l)*G4 + g] = accb[l];
    }
  }
}

// ---------------------------------------------------------------- per-step kernel B
// blocks [0,Bb): LSTM recurrence + seq LN
// blocks [Bb, Bb+N/32): edge gather — each wave owns 4 consecutive nodes end-to-end
//   (both directions + LN), own-S read from G_in row, no barriers in gather path.
__global__ __launch_bounds__(512) void k_B(
  const unsigned* __restrict__ G_in, const unsigned* __restrict__ G_out,
  const unsigned* __restrict__ PownPk,
  float* __restrict__ struct_out,
  const int* __restrict__ offs_s, const int4* __restrict__ adj_s,
  const int* __restrict__ offs_d, const int4* __restrict__ adj_d,
  const float* __restrict__ WEin, const float* __restrict__ WEout,
  const float* __restrict__ ln_st_g, const float* __restrict__ ln_st_b,
  const float* __restrict__ pre_f, const float* __restrict__ pre_b,
  const float* __restrict__ Whh_f, const float* __restrict__ Whh_b,
  const float* __restrict__ seq_in, float* __restrict__ seq_out,
  const float* __restrict__ ln_seq_g, const float* __restrict__ ln_seq_b,
  int N, int Bb)
{
  __shared__ float h_hist[2][LSEQ][64];
  __shared__ float hcur[2][64];
  __shared__ float gsh[2][G4];
  if ((int)blockIdx.x >= Bb){
    int wv = threadIdx.x >> 6, lane = threadIdx.x & 63;
    int n0 = ((blockIdx.x - Bb)*8 + wv)*4;           // 4 consecutive nodes per wave
    const float2* WEi2 = (const float2*)WEin;
    const float2* WEo2 = (const float2*)WEout;
    float2 wi0 = WEi2[lane], wi1 = WEi2[64+lane], wi2 = WEi2[128+lane];
    float2 wo0 = WEo2[lane], wo1 = WEo2[64+lane], wo2 = WEo2[128+lane];
    float2 g2v = ((const float2*)ln_st_g)[lane], be2 = ((const float2*)ln_st_b)[lane];
    const uint2* Gi = (const uint2*)G_in;
    const uint2* Go = (const uint2*)G_out;
    #pragma unroll 1
    for (int n = n0; n < n0+4; ++n){
      u32x2 pw = *((const u32x2*)PownPk + (size_t)n*64 + lane);
      float2 pp0 = unpack_h2(pw.x), pp1 = unpack_h2(pw.y);
      float2 poI = make_float2(pp0.x, pp1.x);
      float2 poO = make_float2(pp0.y, pp1.y);
      uint2 gown = Gi[(size_t)n*64 + lane];          // own row: {P_in, S} per channel
      float ax = 0.f, ay = 0.f;
      int j0 = __builtin_amdgcn_readfirstlane(offs_s[n]);
      int j1 = __builtin_amdgcn_readfirstlane(offs_s[n+1]);
      for (int jb = j0; jb < j1; jb += 4){
        int rem = j1 - jb;
        const u32x4* ap = (const u32x4*)adj_s + jb;
        u32x4 a0 = ap[0], a1 = ap[1], a2 = ap[2], a3 = ap[3];
        uint2 g0 = Gi[(size_t)a0.x*64 + lane];
        uint2 g1 = Gi[(size_t)a1.x*64 + lane];
        uint2 g2 = Gi[(size_t)a2.x*64 + lane];
        uint2 g3 = Gi[(size_t)a3.x*64 + lane];
        edge_acc(a0, g0, true,  poI, wi0, wi1, wi2, ax, ay);
        edge_acc(a1, g1, rem>1, poI, wi0, wi1, wi2, ax, ay);
        edge_acc(a2, g2, rem>2, poI, wi0, wi1, wi2, ax, ay);
        edge_acc(a3, g3, rem>3, poI, wi0, wi1, wi2, ax, ay);
      }
      j0 = __builtin_amdgcn_readfirstlane(offs_d[n]);
      j1 = __builtin_amdgcn_readfirstlane(offs_d[n+1]);
      for (int jb = j0; jb < j1; jb += 4){
        int rem = j1 - jb;
        const u32x4* ap = (const u32x4*)adj_d + jb;
        u32x4 a0 = ap[0], a1 = ap[1], a2 = ap[2], a3 = ap[3];
        uint2 g0 = Go[(size_t)a0.x*64 + lane];
        uint2 g1 = Go[(size_t)a1.x*64 + lane];
        uint2 g2 = Go[(size_t)a2.x*64 + lane];
        uint2 g3 = Go[(size_t)a3.x*64 + lane];
        edge_acc(a0, g0, true,  poO, wo0, wo1, wo2, ax, ay);
        edge_acc(a1, g1, rem>1, poO, wo0, wo1, wo2, ax, ay);
        edge_acc(a2, g2, rem>2, poO, wo0, wo1, wo2, ax, ay);
        edge_acc(a3, g3, rem>3, poO, wo0, wo1, wo2, ax, ay);
      }
      float vx = unpack_h2(gown.x).y + ax;
      float vy = unpack_h2(gown.y).y + ay;
      float s = vx+vy, sq = vx*vx + vy*vy;
      #pragma unroll
      for (int o = 32; o; o >>= 1){ s += __shfl_xor(s, o); sq += __shfl_xor(sq, o); }
      float mean = s*(1.f/128.f);
      float inv = rsqrtf(sq*(1.f/128.f) - mean*mean + EPSF);
      float2 o2;
      o2.x = (vx-mean)*inv*g2v.x + be2.x;
      o2.y = (vy-mean)*inv*g2v.y + be2.y;
      ((float2*)struct_out)[(size_t)n*64 + lane] = o2;
    }
  } else {
    int b = blockIdx.x;
    int tid = threadIdx.x;
    int dir = tid >> 8, g = tid & 255;
    const float* Whh = dir ? Whh_b : Whh_f;
    const float* pre = dir ? pre_b : pre_f;
    float w[64];
    #pragma unroll
    for (int q = 0; q < 16; q++){
      float4 t4 = *(const float4*)(Whh + (size_t)g*64 + 4*q);
      w[4*q] = t4.x; w[4*q+1] = t4.y; w[4*q+2] = t4.z; w[4*q+3] = t4.w;
    }
    float c = 0.f;
    for (int t = 0; t < LSEQ; ++t){
      int tt = dir ? (LSEQ-1-t) : t;
      float gate = pre[((size_t)b*LSEQ + tt)*G4 + g];
      if (t > 0){
        #pragma unroll
        for (int q = 0; q < 16; q++){
          float4 h4 = *(const float4*)&hcur[dir][4*q];
          gate += w[4*q]*h4.x + w[4*q+1]*h4.y + w[4*q+2]*h4.z + w[4*q+3]*h4.w;
        }
      }
      gsh[dir][g] = gate;
      __syncthreads();
      if (g < 64){
        float iv = gsh[dir][g], fv = gsh[dir][64+g], gv = gsh[dir][128+g], ov = gsh[dir][192+g];
        c = sigf(fv)*c + sigf(iv)*tanhf(gv);
        float h = sigf(ov)*tanhf(c);
        hcur[dir][g] = h;
        h_hist[dir][tt][g] = h;
      }
      __syncthreads();
    }
    int wv = tid >> 6, lane = tid & 63;
    for (int l = wv; l < LSEQ; l += 8){
      float2 sv = ((const float2*)(seq_in + ((size_t)b*LSEQ + l)*128))[lane];
      float hv0, hv1;
      if (lane < 32){ hv0 = h_hist[0][l][2*lane];    hv1 = h_hist[0][l][2*lane+1]; }
      else          { hv0 = h_hist[1][l][2*lane-64]; hv1 = h_hist[1][l][2*lane-63]; }
      float vx = sv.x + hv0, vy = sv.y + hv1;
      float s = vx+vy, sq = vx*vx + vy*vy;
      #pragma unroll
      for (int o = 32; o; o >>= 1){ s += __shfl_xor(s, o); sq += __shfl_xor(sq, o); }
      float mean = s*(1.f/128.f);
      float inv = rsqrtf(sq*(1.f/128.f) - mean*mean + EPSF);
      float2 g2 = ((const float2*)ln_seq_g)[lane], b2 = ((const float2*)ln_seq_b)[lane];
      float2 o2;
      o2.x = (vx-mean)*inv*g2.x + b2.x;
      o2.y = (vy-mean)*inv*g2.y + b2.y;
      ((float2*)(seq_out + ((size_t)b*LSEQ + l)*128))[lane] = o2;
    }
  }
}

// ---------------------------------------------------------------- epilogue
__global__ void k_final(float* __restrict__ out, const float* __restrict__ sy,
                        const float* __restrict__ ty, const int* __restrict__ starts,
                        const float* __restrict__ g, const float* __restrict__ b,
                        const float* __restrict__ rm, const float* __restrict__ rv, int Bb){
  int i = blockIdx.x*blockDim.x + threadIdx.x;
  if (i >= Bb*D) return;
  int bb = i >> 7, d = i & 127;
  float feat = sy[((size_t)bb*LSEQ + 10)*D + d] + ty[(size_t)starts[bb]*D + d];
  out[i] = (feat - rm[d])*rsqrtf(rv[d]+EPSF)*g[d] + b[d];
}

// ---------------------------------------------------------------- host
extern "C" void kernel_launch(void* const* d_in, const int* in_sizes, int n_in,
                              void* d_out, int out_size, void* d_ws, size_t ws_size,
                              hipStream_t stream)
{
  const float* x        = (const float*)d_in[0];
  const int*   ei       = (const int*)  d_in[1];
  const float* eattr    = (const float*)d_in[2];
  const int*   batch    = (const int*)  d_in[3];
  const float* hotslice = (const float*)d_in[4];
  const float* nsy      = (const float*)d_in[5];
  const float* nsz      = (const float*)d_in[6];
  const float* nty      = (const float*)d_in[7];
  const float* ntz      = (const float*)d_in[8];
  const float* W_esm    = (const float*)d_in[9];
  const float* b_esm    = (const float*)d_in[10];
  const float* W_node   = (const float*)d_in[11];
  const float* b_node   = (const float*)d_in[12];
  const float* W_seq    = (const float*)d_in[13];
  const float* b_seq    = (const float*)d_in[14];
  const float* ln_seq_g = (const float*)d_in[15];
  const float* ln_seq_b = (const float*)d_in[16];
  const float* ln_st_g  = (const float*)d_in[17];
  const float* ln_st_b  = (const float*)d_in[18];
  const float* W_in     = (const float*)d_in[19];
  const float* b_in     = (const float*)d_in[20];
  const float* W_out    = (const float*)d_in[21];
  const float* b_out    = (const float*)d_in[22];
  const float* Wih_f    = (const float*)d_in[23];
  const float* Whh_f    = (const float*)d_in[24];
  const float* bih_f    = (const float*)d_in[25];
  const float* bhh_f    = (const float*)d_in[26];
  const float* Wih_b    = (const float*)d_in[27];
  const float* Whh_b    = (const float*)d_in[28];
  const float* bih_b    = (const float*)d_in[29];
  const float* bhh_b    = (const float*)d_in[30];
  const float* bn_g     = (const float*)d_in[31];
  const float* bn_b     = (const float*)d_in[32];
  const float* bn_rm    = (const float*)d_in[33];
  const float* bn_rv    = (const float*)d_in[34];

  const int N  = in_sizes[0] / 2561;
  const int E  = in_sizes[1] / 2;
  const int E2 = E / 2;
  const int Bb = in_sizes[4] / (LSEQ*28);
  const int BL = Bb*LSEQ;

  // ---- workspace carve
  char* p = (char*)d_ws;
  auto alloc = [&](size_t bytes)->void*{
    void* r = (void*)p; p += (bytes + 255) & ~(size_t)255; return r;
  };
  float*    seq0      = (float*)alloc((size_t)BL*D*4);
  float*    sy        = (float*)alloc((size_t)BL*D*4);
  float*    sz        = (float*)alloc((size_t)BL*D*4);
  float*    seq_in    = (float*)alloc((size_t)BL*D*4);
  float*    pre_f     = (float*)alloc((size_t)BL*G4*4);
  float*    pre_b     = (float*)alloc((size_t)BL*G4*4);
  float*    struct0   = (float*)alloc((size_t)N*D*4);
  float*    ty        = (float*)alloc((size_t)N*D*4);
  float*    tz        = (float*)alloc((size_t)N*D*4);
  unsigned* G_in      = (unsigned*)alloc((size_t)N*D*4);
  unsigned* G_out     = (unsigned*)alloc((size_t)N*D*4);
  unsigned* PownPk    = (unsigned*)alloc((size_t)N*D*4);
  u16*      PB4h      = (u16*)alloc(65536*2);
  u16*      PB4l      = (u16*)alloc(65536*2);
  u16*      PBnh      = (u16*)alloc(16384*2);
  u16*      PBnl      = (u16*)alloc(16384*2);
  u16*      PBEh      = (u16*)alloc(327680*2);
  u16*      PBEl      = (u16*)alloc(327680*2);
  float*    WEin      = (float*)alloc(384*4);
  float*    WEout     = (float*)alloc(384*4);
  float*    bsum_f    = (float*)alloc(256*4);
  float*    bsum_b    = (float*)alloc(256*4);
  int*      starts    = (int*)alloc((size_t)Bb*4);
  int*      cnt_s     = (int*)alloc((size_t)N*4);
  int*      cnt_d     = (int*)alloc((size_t)N*4);
  int*      offs_s    = (int*)alloc((size_t)(N+1)*4);
  int*      offs_d    = (int*)alloc((size_t)(N+1)*4);
  int*      cur_s     = (int*)alloc((size_t)N*4);
  int*      cur_d     = (int*)alloc((size_t)N*4);
  int4*     adj_s     = (int4*)alloc((size_t)(E2+8)*16);
  int4*     adj_d     = (int4*)alloc((size_t)(E2+8)*16);
  (void)ws_size; (void)n_in; (void)out_size;

  // ---- init state from noise inputs
  hipMemcpyAsync(sy, nsy, (size_t)BL*D*4, hipMemcpyDeviceToDevice, stream);
  hipMemcpyAsync(sz, nsz, (size_t)BL*D*4, hipMemcpyDeviceToDevice, stream);
  hipMemcpyAsync(ty, nty, (size_t)N*D*4, hipMemcpyDeviceToDevice, stream);
  hipMemcpyAsync(tz, ntz, (size_t)N*D*4, hipMemcpyDeviceToDevice, stream);

  // ---- prologue
  k_misc<<<1, 256, 0, stream>>>(starts, batch, N, Bb, WEin, WEout, W_in, W_out,
                                bsum_f, bsum_b, bih_f, bhh_f, bih_b, bhh_b);
  k_packB<<<1600, 256, 0, stream>>>(PB4h, PB4l, PBnh, PBnl, PBEh, PBEl,
                                    W_in, W_out, W_node, W_esm);
  k_seq0<<<BL, 128, 0, stream>>>(seq0, hotslice, W_seq, b_seq);
  k_esm2<<<N/32, 256, 0, stream>>>(struct0, x, PBEh, PBEl, PBnh, PBnl,
                                   b_esm, W_node, b_node);
  k_zero2<<<(N+255)/256, 256, 0, stream>>>(cnt_s, cnt_d, N);
  k_count<<<(E2+255)/256, 256, 0, stream>>>(cnt_s, cnt_d, ei, E2);
  k_scan<<<1, 1024, 0, stream>>>(cnt_s, offs_s, N);
  k_scan<<<1, 1024, 0, stream>>>(cnt_d, offs_d, N);
  k_copy2<<<(N+255)/256, 256, 0, stream>>>(cur_s, offs_s, cur_d, offs_d, N);
  k_fill<<<(E2+255)/256, 256, 0, stream>>>(ei, eattr, E2, cur_s, adj_s, cur_d, adj_d);
  k_pad<<<1, 64, 0, stream>>>(adj_s, adj_d, E2);

  const int NB_T1 = N/32;
  const int NB_T2 = N/32;   // gather: 8 waves/block x 4 nodes/wave = 32 nodes/block

  // ---- main loop: 8 outer x (4 inner + 1)
  for (int o = 0; o < 8; ++o){
    for (int it = 0; it < 5; ++it){
      bool inner = (it < 4);
      const float* s0s = inner ? seq0 : nullptr;
      const float* s0t = inner ? struct0 : nullptr;
      float* so = inner ? sz : sy;
      float* to = inner ? tz : ty;
      k_A<<<Bb + NB_T1, 256, 0, stream>>>(s0t, ty, tz, PB4h, PB4l,
                                          G_in, G_out, PownPk, b_in, b_out,
                                          s0s, sy, sz, seq_in, pre_f, pre_b,
                                          Wih_f, Wih_b, bsum_f, bsum_b, N, Bb);
      k_B<<<Bb + NB_T2, 512, 0, stream>>>(G_in, G_out, PownPk, to,
                                          offs_s, adj_s, offs_d, adj_d,
                                          WEin, WEout, ln_st_g, ln_st_b,
                                          pre_f, pre_b, Whh_f, Whh_b, seq_in, so,
                                          ln_seq_g, ln_seq_b, N, Bb);
    }
  }

  k_final<<<(Bb*D+255)/256, 256, 0, stream>>>((float*)d_out, sy, ty, starts,
                                              bn_g, bn_b, bn_rm, bn_rv, Bb);
}

// Round 12
// 3629.417 us; speedup vs baseline: 1.2402x; 1.1793x over previous
//
#include <hip/hip_runtime.h>
#include <hip/hip_fp16.h>
#include <math.h>

#define D 128
#define G4 256
#define LSEQ 21
#define EPSF 1e-5f

typedef unsigned short u16;
typedef __attribute__((ext_vector_type(8))) short bf16x8;
typedef __attribute__((ext_vector_type(4))) float f32x4;
typedef __attribute__((ext_vector_type(2))) unsigned u32x2;
typedef __attribute__((ext_vector_type(4))) unsigned u32x4;

#define MFMA16(a,b,c) __builtin_amdgcn_mfma_f32_16x16x32_bf16(a,b,c,0,0,0)

// ---------------------------------------------------------------- helpers
__device__ __forceinline__ float sigf(float x){ return 1.0f/(1.0f+__expf(-x)); }
__device__ __forceinline__ u16 f2bf(float x){
  unsigned u = __float_as_uint(x);
  return (u16)((u + 0x7FFFu + ((u>>16)&1u)) >> 16);
}
__device__ __forceinline__ float bf2f(u16 h){ return __uint_as_float(((unsigned)h)<<16); }
__device__ __forceinline__ unsigned pack_h2(float a, float b){
  __half2 h = __floats2half2_rn(a, b);
  return *(unsigned*)&h;
}
__device__ __forceinline__ float2 unpack_h2(unsigned u){
  __half2 h = *(__half2*)&u;
  return __half22float2(h);
}
__device__ __forceinline__ u16 f2h(float v){ __half h = __float2half(v); return *(u16*)&h; }

__device__ __forceinline__ void edge_acc(u32x4 a, uint2 g, bool valid,
                                         float2 po2, float2 w0, float2 w1, float2 w2,
                                         float& ax, float& ay){
  float e0=__uint_as_float(a.y), e1=__uint_as_float(a.z), e2=__uint_as_float(a.w);
  float2 ps0 = unpack_h2(g.x);   // {P(ch0), S(ch0)}
  float2 ps1 = unpack_h2(g.y);   // {P(ch1), S(ch1)}
  float gx = po2.x + ps0.x + e0*w0.x + e1*w1.x + e2*w2.x;
  float gy = po2.y + ps1.x + e0*w0.y + e1*w1.y + e2*w2.y;
  float mm = valid ? 1.f : 0.f;
  ax = fmaf(ps0.y*mm, sigf(gx), ax);
  ay = fmaf(ps1.y*mm, sigf(gy), ay);
}

// ---------------------------------------------------------------- prologue kernels
__global__ void k_misc(int* __restrict__ starts, const int* __restrict__ batch, int N, int Bb,
                       float* __restrict__ WEin, float* __restrict__ WEout,
                       const float* __restrict__ W_in, const float* __restrict__ W_out,
                       float* __restrict__ bsum_f, float* __restrict__ bsum_b,
                       const float* __restrict__ bih_f, const float* __restrict__ bhh_f,
                       const float* __restrict__ bih_b, const float* __restrict__ bhh_b){
  int tid = threadIdx.x;
  if (tid < Bb){
    int lo = 0, hi = N;
    while (lo < hi){ int m = (lo+hi)>>1; if (batch[m] < tid) lo = m+1; else hi = m; }
    starts[tid] = lo;
  }
  for (int i = tid; i < 384; i += 256){
    int t = i >> 7, j = i & 127;
    WEin [i] = W_in [(size_t)j*259 + 256 + t];
    WEout[i] = W_out[(size_t)j*259 + 256 + t];
  }
  if (tid < 256){
    bsum_f[tid] = bih_f[tid] + bhh_f[tid];
    bsum_b[tid] = bih_b[tid] + bhh_b[tid];
  }
}

// pre-pack MFMA B-fragments (hi/lo bf16), layout [nt][ks][lane][8] contiguous
__global__ void k_packB(u16* __restrict__ PB4h, u16* __restrict__ PB4l,
                        u16* __restrict__ PBnh, u16* __restrict__ PBnl,
                        u16* __restrict__ PBEh, u16* __restrict__ PBEl,
                        const float* __restrict__ W_in, const float* __restrict__ W_out,
                        const float* __restrict__ W_node, const float* __restrict__ W_esm){
  int idx = blockIdx.x*256 + threadIdx.x;
  if (idx < 65536){
    int j = idx&7, l=(idx>>3)&63, q=idx>>9;
    int ks = q&3, nt = q>>2;
    int c = nt*16 + (l&15);
    int k = ks*32 + ((l>>4)<<3) + j;
    float v;
    if (c < 128)      v = W_in [(size_t)c*259 + k];
    else if (c < 256) v = W_in [(size_t)(c-128)*259 + 128 + k];
    else if (c < 384) v = W_out[(size_t)(c-256)*259 + k];
    else              v = W_out[(size_t)(c-384)*259 + 128 + k];
    u16 h = f2bf(v);
    PB4h[idx] = h; PB4l[idx] = f2bf(v - bf2f(h));
  } else if (idx < 65536 + 16384){
    int p = idx - 65536;
    int j = p&7, l=(p>>3)&63, q=p>>9;
    int ks = q&3, nt = q>>2;
    int c = nt*16 + (l&15);
    int k = ks*32 + ((l>>4)<<3) + j;
    float v = W_node[(size_t)c*129 + k];
    u16 h = f2bf(v);
    PBnh[p] = h; PBnl[p] = f2bf(v - bf2f(h));
  } else if (idx < 65536 + 16384 + 327680){
    int p = idx - 81920;
    int j = p&7, l=(p>>3)&63, q=p>>9;
    int ks = q%80, nt = q/80;
    int c = nt*16 + (l&15);
    int k = ks*32 + ((l>>4)<<3) + j;
    float v = W_esm[(size_t)c*2560 + k];
    u16 h = f2bf(v);
    PBEh[p] = h; PBEl[p] = f2bf(v - bf2f(h));
  }
}

__global__ void k_seq0(float* __restrict__ seq0, const float* __restrict__ hot,
                       const float* __restrict__ W_seq, const float* __restrict__ b_seq){
  int row = blockIdx.x, j = threadIdx.x;           // 128 threads
  const float* h = hot + (size_t)row*28;
  const float* w = W_seq + (size_t)j*28;
  float acc = b_seq[j];
  #pragma unroll
  for (int k = 0; k < 28; k++) acc += h[k]*w[k];
  seq0[(size_t)row*D + j] = acc;
}

// fused: esm = x[:,1:] @ W_esm.T + b_esm ; struct0 = [esm, x[:,:1]] @ W_node.T + b_node
// R10 form: register double-buffered staging, conflict-free LDS writes
__global__ __launch_bounds__(256) void k_esm2(float* __restrict__ struct0, const float* __restrict__ x,
    const u16* __restrict__ PBEh, const u16* __restrict__ PBEl,
    const u16* __restrict__ PBnh, const u16* __restrict__ PBnl,
    const float* __restrict__ b_esm, const float* __restrict__ W_node,
    const float* __restrict__ b_node){
  __shared__ union {
    struct { u16 xh[32*72], xl[32*72]; } p1;
    struct { u16 Ah[32*136], Al[32*136]; } p2;
  } uu;
  __shared__ float esmF[32*132];
  int tid = threadIdx.x;
  int r0 = blockIdx.x*32;
  int w = tid>>6, l = tid&63;
  f32x4 acc[2][2];
  #pragma unroll
  for (int a=0;a<2;a++)
    #pragma unroll
    for (int b=0;b<2;b++) acc[a][b] = (f32x4){0.f,0.f,0.f,0.f};

  float xv[8];
  int rr = tid >> 5, k2i = tid & 31;      // rows rr, rr+8, rr+16, rr+24 ; col pair k2i
  #pragma unroll
  for (int q = 0; q < 4; q++){
    const float* src = x + (size_t)(r0+rr+8*q)*2561 + 1 + k2i*2;
    xv[2*q]   = src[0];
    xv[2*q+1] = src[1];
  }
  for (int kc = 0; kc < 2560; kc += 64){
    __syncthreads();
    unsigned* xh32 = (unsigned*)uu.p1.xh;
    unsigned* xl32 = (unsigned*)uu.p1.xl;
    #pragma unroll
    for (int q = 0; q < 4; q++){
      float v0 = xv[2*q], v1 = xv[2*q+1];
      u16 h0 = f2bf(v0), h1 = f2bf(v1);
      u16 l0 = f2bf(v0 - bf2f(h0)), l1 = f2bf(v1 - bf2f(h1));
      int r = rr + 8*q;
      xh32[r*36 + k2i] = (unsigned)h0 | ((unsigned)h1 << 16);
      xl32[r*36 + k2i] = (unsigned)l0 | ((unsigned)l1 << 16);
    }
    __syncthreads();
    if (kc + 64 < 2560){
      #pragma unroll
      for (int q = 0; q < 4; q++){
        const float* src = x + (size_t)(r0+rr+8*q)*2561 + 1 + kc + 64 + k2i*2;
        xv[2*q]   = src[0];
        xv[2*q+1] = src[1];
      }
    }
    #pragma unroll
    for (int ks = 0; ks < 2; ks++){
      bf16x8 ah[2], al[2];
      #pragma unroll
      for (int rt = 0; rt < 2; rt++){
        int row = rt*16 + (l&15);
        int k = ks*32 + ((l>>4)<<3);
        ah[rt] = *(const bf16x8*)&uu.p1.xh[row*72 + k];
        al[rt] = *(const bf16x8*)&uu.p1.xl[row*72 + k];
      }
      int ksg = (kc>>5) + ks;
      #pragma unroll
      for (int ctl = 0; ctl < 2; ctl++){
        int nt = w*2 + ctl;
        bf16x8 bh = *(const bf16x8*)&PBEh[((size_t)(nt*80 + ksg)*64 + l)*8];
        bf16x8 bl = *(const bf16x8*)&PBEl[((size_t)(nt*80 + ksg)*64 + l)*8];
        #pragma unroll
        for (int rt = 0; rt < 2; rt++){
          acc[rt][ctl] = MFMA16(ah[rt], bh, acc[rt][ctl]);
          acc[rt][ctl] = MFMA16(al[rt], bh, acc[rt][ctl]);
          acc[rt][ctl] = MFMA16(ah[rt], bl, acc[rt][ctl]);
        }
      }
    }
  }
  __syncthreads();
  int cq = l & 15, rqb = (l>>4)*4;
  #pragma unroll
  for (int ctl = 0; ctl < 2; ctl++){
    int coln = (w*2+ctl)*16 + cq;
    float be = b_esm[coln];
    #pragma unroll
    for (int rt = 0; rt < 2; rt++)
      #pragma unroll
      for (int r = 0; r < 4; r++)
        esmF[(rt*16+rqb+r)*132 + coln] = acc[rt][ctl][r] + be;
  }
  __syncthreads();
  {
    unsigned* Ah32 = (unsigned*)uu.p2.Ah;
    unsigned* Al32 = (unsigned*)uu.p2.Al;
    int rr2 = tid >> 6, k2 = tid & 63;   // 4 rows/iter, 64 col-pairs
    #pragma unroll
    for (int q = 0; q < 8; q++){
      int r = rr2 + 4*q;
      float v0 = esmF[r*132 + k2*2];
      float v1 = esmF[r*132 + k2*2 + 1];
      u16 h0 = f2bf(v0), h1 = f2bf(v1);
      u16 l0 = f2bf(v0 - bf2f(h0)), l1 = f2bf(v1 - bf2f(h1));
      Ah32[r*68 + k2] = (unsigned)h0 | ((unsigned)h1 << 16);
      Al32[r*68 + k2] = (unsigned)l0 | ((unsigned)l1 << 16);
    }
  }
  __syncthreads();
  f32x4 acc2[2][2];
  #pragma unroll
  for (int a=0;a<2;a++)
    #pragma unroll
    for (int b=0;b<2;b++) acc2[a][b] = (f32x4){0.f,0.f,0.f,0.f};
  #pragma unroll
  for (int ks = 0; ks < 4; ks++){
    bf16x8 ah[2], al[2];
    #pragma unroll
    for (int rt = 0; rt < 2; rt++){
      int row = rt*16 + (l&15);
      int k = ks*32 + ((l>>4)<<3);
      ah[rt] = *(const bf16x8*)&uu.p2.Ah[row*136 + k];
      al[rt] = *(const bf16x8*)&uu.p2.Al[row*136 + k];
    }
    #pragma unroll
    for (int ctl = 0; ctl < 2; ctl++){
      int nt = w*2 + ctl;
      bf16x8 bh = *(const bf16x8*)&PBnh[((size_t)(nt*4 + ks)*64 + l)*8];
      bf16x8 bl = *(const bf16x8*)&PBnl[((size_t)(nt*4 + ks)*64 + l)*8];
      #pragma unroll
      for (int rt = 0; rt < 2; rt++){
        acc2[rt][ctl] = MFMA16(ah[rt], bh, acc2[rt][ctl]);
        acc2[rt][ctl] = MFMA16(al[rt], bh, acc2[rt][ctl]);
        acc2[rt][ctl] = MFMA16(ah[rt], bl, acc2[rt][ctl]);
      }
    }
  }
  #pragma unroll
  for (int ctl = 0; ctl < 2; ctl++){
    int col = (w*2+ctl)*16 + cq;
    float wl = W_node[(size_t)col*129 + 128];
    float bn = b_node[col];
    #pragma unroll
    for (int rt = 0; rt < 2; rt++)
      #pragma unroll
      for (int r = 0; r < 4; r++){
        int row = r0 + rt*16 + rqb + r;
        float x0 = x[(size_t)row*2561];
        struct0[(size_t)row*D + col] = acc2[rt][ctl][r] + x0*wl + bn;
      }
  }
}

// ---------------------------------------------------------------- CSR build
__global__ void k_zero2(int* a, int* b, int n){
  int i = blockIdx.x*blockDim.x + threadIdx.x;
  if (i < n){ a[i] = 0; b[i] = 0; }
}
__global__ void k_count(int* cnt_s, int* cnt_d, const int* __restrict__ ei, int E2){
  int e = blockIdx.x*blockDim.x + threadIdx.x;
  if (e < E2){
    atomicAdd(&cnt_s[ei[2*e]], 1);
    atomicAdd(&cnt_d[ei[2*E2 + 2*e]], 1);
  }
}
__global__ __launch_bounds__(1024) void k_scan(const int* __restrict__ cnt, int* __restrict__ offs, int n){
  __shared__ int sh[1024];
  __shared__ int sbase;
  int tid = threadIdx.x;
  if (tid == 0) sbase = 0;
  __syncthreads();
  for (int chunk = 0; chunk < n; chunk += 1024){
    int v = (chunk+tid < n) ? cnt[chunk+tid] : 0;
    sh[tid] = v;
    __syncthreads();
    for (int off = 1; off < 1024; off <<= 1){
      int t = (tid >= off) ? sh[tid-off] : 0;
      __syncthreads();
      sh[tid] += t;
      __syncthreads();
    }
    if (chunk+tid < n) offs[chunk+tid] = sbase + sh[tid] - v;
    __syncthreads();
    if (tid == 0) sbase += sh[1023];
    __syncthreads();
  }
  if (tid == 0) offs[n] = sbase;
}
__global__ void k_copy2(int* cur_s, const int* offs_s, int* cur_d, const int* offs_d, int n){
  int i = blockIdx.x*blockDim.x + threadIdx.x;
  if (i < n){ cur_s[i] = offs_s[i]; cur_d[i] = offs_d[i]; }
}
__global__ void k_fill(const int* __restrict__ ei, const float* __restrict__ eattr, int E2,
                       int* cur_s, int4* __restrict__ adj_s,
                       int* cur_d, int4* __restrict__ adj_d){
  int e = blockIdx.x*blockDim.x + threadIdx.x;
  if (e >= E2) return;
  int s = ei[2*e];
  int d = ei[2*E2 + 2*e];
  const float* ein  = eattr + (size_t)(2*e+1)*3;
  const float* eout = eattr + (size_t)(2*e)*3;
  int ps = atomicAdd(&cur_s[s], 1);
  adj_s[ps] = make_int4(d, __float_as_int(ein[0]),  __float_as_int(ein[1]),  __float_as_int(ein[2]));
  int pd = atomicAdd(&cur_d[d], 1);
  adj_d[pd] = make_int4(s, __float_as_int(eout[0]), __float_as_int(eout[1]), __float_as_int(eout[2]));
}
__global__ void k_pad(int4* __restrict__ adj_s, int4* __restrict__ adj_d, int E2){
  int t = threadIdx.x;
  if (t < 8){
    adj_s[E2+t] = make_int4(0,0,0,0);
    adj_d[E2+t] = make_int4(0,0,0,0);
  }
}

// ---------------------------------------------------------------- initial seq pre-GEMM
__global__ __launch_bounds__(256) void k_seqA(
  const float* __restrict__ s0s, const float* __restrict__ sy, const float* __restrict__ sz,
  float* __restrict__ seq_in, float* __restrict__ pre_f, float* __restrict__ pre_b,
  const float* __restrict__ Wih_f, const float* __restrict__ Wih_b,
  const float* __restrict__ bsum_f, const float* __restrict__ bsum_b)
{
  __shared__ float sh[LSEQ*128];
  int tid = threadIdx.x;
  int b = blockIdx.x;
  for (int idx = tid; idx < LSEQ*128; idx += 256){
    size_t off = (size_t)b*LSEQ*128 + idx;
    float v = sy[off] + sz[off];
    if (s0s) v += s0s[off];
    sh[idx] = v;
    seq_in[off] = v;
  }
  __syncthreads();
  int g = tid;  // 0..255
  float accf[LSEQ], accb[LSEQ];
  float bf = bsum_f[g], bb = bsum_b[g];
  #pragma unroll
  for (int l = 0; l < LSEQ; l++){ accf[l] = bf; accb[l] = bb; }
  const float* wfp = Wih_f + (size_t)g*128;
  const float* wbp = Wih_b + (size_t)g*128;
  for (int kc = 0; kc < 128; kc += 16){
    float4 wf[4], wb[4];
    #pragma unroll
    for (int q = 0; q < 4; q++){
      wf[q] = *(const float4*)(wfp + kc + 4*q);
      wb[q] = *(const float4*)(wbp + kc + 4*q);
    }
    #pragma unroll
    for (int l = 0; l < LSEQ; l++){
      #pragma unroll
      for (int q = 0; q < 4; q++){
        float4 s4 = *(const float4*)&sh[l*128 + kc + 4*q];
        accf[l] += s4.x*wf[q].x + s4.y*wf[q].y + s4.z*wf[q].z + s4.w*wf[q].w;
        accb[l] += s4.x*wb[q].x + s4.y*wb[q].y + s4.z*wb[q].z + s4.w*wb[q].w;
      }
    }
  }
  for (int l = 0; l < LSEQ; l++){
    pre_f[((size_t)b*LSEQ + l)*G4 + g] = accf[l];
    pre_b[((size_t)b*LSEQ + l)*G4 + g] = accb[l];
  }
}

// ---------------------------------------------------------------- per-step kernel A (struct only)
__global__ __launch_bounds__(256) void k_A(
  const float* __restrict__ s0t, const float* __restrict__ ty, const float* __restrict__ tz,
  const u16* __restrict__ PB4h, const u16* __restrict__ PB4l,
  unsigned* __restrict__ G_in, unsigned* __restrict__ G_out,
  unsigned* __restrict__ PownPk,
  const float* __restrict__ b_in, const float* __restrict__ b_out, int N)
{
  __shared__ struct { u16 Ah[32*136], Al[32*136]; float Sf[32*132]; } m;
  int tid = threadIdx.x;
  int r0 = blockIdx.x*32;
  const float4* ty4 = (const float4*)(ty + (size_t)r0*D);
  const float4* tz4 = (const float4*)(tz + (size_t)r0*D);
  const float4* s04 = s0t ? (const float4*)(s0t + (size_t)r0*D) : nullptr;
  #pragma unroll
  for (int q = 0; q < 4; q++){
    int i = tid + 256*q;          // float4 index, 0..1023
    int r = i >> 5, k4 = i & 31;
    float4 v = ty4[i];
    float4 z = tz4[i];
    v.x += z.x; v.y += z.y; v.z += z.z; v.w += z.w;
    if (s04){ float4 s = s04[i]; v.x += s.x; v.y += s.y; v.z += s.z; v.w += s.w; }
    u16 h0 = f2bf(v.x), h1 = f2bf(v.y), h2 = f2bf(v.z), h3 = f2bf(v.w);
    *(ushort4*)&m.Ah[r*136 + k4*4] = make_ushort4(h0,h1,h2,h3);
    *(ushort4*)&m.Al[r*136 + k4*4] = make_ushort4(
        f2bf(v.x - bf2f(h0)), f2bf(v.y - bf2f(h1)),
        f2bf(v.z - bf2f(h2)), f2bf(v.w - bf2f(h3)));
    *(float4*)&m.Sf[r*132 + k4*4] = v;
  }
  __syncthreads();
  int w = tid >> 6, l = tid & 63;
  f32x4 acc[2][8];
  #pragma unroll
  for (int a=0;a<2;a++)
    #pragma unroll
    for (int b=0;b<8;b++) acc[a][b] = (f32x4){0.f,0.f,0.f,0.f};
  #pragma unroll
  for (int ks = 0; ks < 4; ks++){
    bf16x8 ah[2], al[2];
    #pragma unroll
    for (int rt = 0; rt < 2; rt++){
      int row = rt*16 + (l&15);
      int k = ks*32 + ((l>>4)<<3);
      ah[rt] = *(const bf16x8*)&m.Ah[row*136 + k];
      al[rt] = *(const bf16x8*)&m.Al[row*136 + k];
    }
    #pragma unroll
    for (int ct = 0; ct < 8; ct++){
      int nt = w*8 + ct;
      bf16x8 bh = *(const bf16x8*)&PB4h[((size_t)(nt*4 + ks)*64 + l)*8];
      bf16x8 bl = *(const bf16x8*)&PB4l[((size_t)(nt*4 + ks)*64 + l)*8];
      #pragma unroll
      for (int rt = 0; rt < 2; rt++){
        acc[rt][ct] = MFMA16(ah[rt], bh, acc[rt][ct]);
        acc[rt][ct] = MFMA16(al[rt], bh, acc[rt][ct]);
        acc[rt][ct] = MFMA16(ah[rt], bl, acc[rt][ct]);
      }
    }
  }
  // ---- coalesced table epilogue via LDS staging (reuses Ah/Al region) ----
  __syncthreads();                      // MFMA done reading Ah/Al
  unsigned* stg = (unsigned*)m.Ah;      // 32*128 u32 = 16KB (fits in Ah+Al)
  u16* stg16 = (u16*)m.Ah;
  int cq = l & 15, rqb = (l>>4)*4;
  if (w == 1){
    #pragma unroll
    for (int ct = 0; ct < 8; ct++){
      int coln = ct*16 + cq;
      #pragma unroll
      for (int rt = 0; rt < 2; rt++){
        #pragma unroll
        for (int r = 0; r < 4; r++){
          int lr = rt*16 + rqb + r;
          stg[lr*128 + coln] = pack_h2(acc[rt][ct][r], m.Sf[lr*132 + coln]);
        }
      }
    }
  }
  __syncthreads();
  {
    uint4* dst = (uint4*)(G_in + (size_t)r0*D);
    const uint4* src = (const uint4*)stg;
    #pragma unroll
    for (int q = 0; q < 4; q++) dst[tid + 256*q] = src[tid + 256*q];
  }
  __syncthreads();
  if (w == 2){
    #pragma unroll
    for (int ct = 0; ct < 8; ct++){
      int coln = ct*16 + cq;
      #pragma unroll
      for (int rt = 0; rt < 2; rt++){
        #pragma unroll
        for (int r = 0; r < 4; r++){
          int lr = rt*16 + rqb + r;
          stg[lr*128 + coln] = pack_h2(acc[rt][ct][r], m.Sf[lr*132 + coln]);
        }
      }
    }
  }
  __syncthreads();
  {
    uint4* dst = (uint4*)(G_out + (size_t)r0*D);
    const uint4* src = (const uint4*)stg;
    #pragma unroll
    for (int q = 0; q < 4; q++) dst[tid + 256*q] = src[tid + 256*q];
  }
  __syncthreads();
  if (w == 0 || w == 3){
    const float* bb = (w == 0) ? b_in : b_out;
    int half = (w == 0) ? 0 : 1;
    #pragma unroll
    for (int ct = 0; ct < 8; ct++){
      int coln = ct*16 + cq;
      float bc = bb[coln];
      #pragma unroll
      for (int rt = 0; rt < 2; rt++){
        #pragma unroll
        for (int r = 0; r < 4; r++){
          int lr = rt*16 + rqb + r;
          stg16[(lr*128 + coln)*2 + half] = f2h(acc[rt][ct][r] + bc);
        }
      }
    }
  }
  __syncthreads();
  {
    uint4* dst = (uint4*)(PownPk + (size_t)r0*D);
    const uint4* src = (const uint4*)stg;
    #pragma unroll
    for (int q = 0; q < 4; q++) dst[tid + 256*q] = src[tid + 256*q];
  }
}

// ---------------------------------------------------------------- per-step kernel B
// blocks [0,Bb): LSTM(i) + seq LN -> so ; then (doNext) seq_in(i+1) staging + pre-GEMM(i+1)
// blocks [Bb, Bb+N/32): edge gather — wave owns 4 consecutive nodes (both dirs + LN)
__global__ __launch_bounds__(512) void k_B(
  const unsigned* __restrict__ G_in, const unsigned* __restrict__ G_out,
  const unsigned* __restrict__ PownPk,
  float* __restrict__ to,
  const int* __restrict__ offs_s, const int4* __restrict__ adj_s,
  const int* __restrict__ offs_d, const int4* __restrict__ adj_d,
  const float* __restrict__ WEin, const float* __restrict__ WEout,
  const float* __restrict__ ln_st_g, const float* __restrict__ ln_st_b,
  float* pre_f, float* pre_b,
  const float* __restrict__ Whh_f, const float* __restrict__ Whh_b,
  float* seq_in, float* __restrict__ so,
  const float* __restrict__ otherS, const float* __restrict__ s0s_n,
  const float* __restrict__ Wih_f, const float* __restrict__ Wih_b,
  const float* __restrict__ bsum_f, const float* __restrict__ bsum_b,
  const float* __restrict__ ln_seq_g, const float* __restrict__ ln_seq_b,
  int doNext, int N, int Bb)
{
  __shared__ union {
    struct {
      float h_hist[2][LSEQ][64];
      float hcur[2][64];
      float gsh[2][G4];
      float soL[LSEQ*128];
      float shG[LSEQ*128];
    } sq;
  } u;
  if ((int)blockIdx.x >= Bb){
    int wv = threadIdx.x >> 6, lane = threadIdx.x & 63;
    int n0 = ((blockIdx.x - Bb)*8 + wv)*4;           // 4 consecutive nodes per wave
    const float2* WEi2 = (const float2*)WEin;
    const float2* WEo2 = (const float2*)WEout;
    float2 wi0 = WEi2[lane], wi1 = WEi2[64+lane], wi2 = WEi2[128+lane];
    float2 wo0 = WEo2[lane], wo1 = WEo2[64+lane], wo2 = WEo2[128+lane];
    float2 g2v = ((const float2*)ln_st_g)[lane], be2 = ((const float2*)ln_st_b)[lane];
    const uint2* Gi = (const uint2*)G_in;
    const uint2* Go = (const uint2*)G_out;
    #pragma unroll 1
    for (int n = n0; n < n0+4; ++n){
      u32x2 pw = *((const u32x2*)PownPk + (size_t)n*64 + lane);
      float2 pp0 = unpack_h2(pw.x), pp1 = unpack_h2(pw.y);
      float2 poI = make_float2(pp0.x, pp1.x);
      float2 poO = make_float2(pp0.y, pp1.y);
      uint2 gown = Gi[(size_t)n*64 + lane];          // own row: {P_in, S} per channel
      float ax = 0.f, ay = 0.f;
      int j0 = __builtin_amdgcn_readfirstlane(offs_s[n]);
      int j1 = __builtin_amdgcn_readfirstlane(offs_s[n+1]);
      for (int jb = j0; jb < j1; jb += 4){
        int rem = j1 - jb;
        const u32x4* ap = (const u32x4*)adj_s + jb;
        u32x4 a0 = ap[0], a1 = ap[1], a2 = ap[2], a3 = ap[3];
        uint2 g0 = Gi[(size_t)a0.x*64 + lane];
        uint2 g1 = Gi[(size_t)a1.x*64 + lane];
        uint2 g2 = Gi[(size_t)a2.x*64 + lane];
        uint2 g3 = Gi[(size_t)a3.x*64 + lane];
        edge_acc(a0, g0, true,  poI, wi0, wi1, wi2, ax, ay);
        edge_acc(a1, g1, rem>1, poI, wi0, wi1, wi2, ax, ay);
        edge_acc(a2, g2, rem>2, poI, wi0, wi1, wi2, ax, ay);
        edge_acc(a3, g3, rem>3, poI, wi0, wi1, wi2, ax, ay);
      }
      j0 = __builtin_amdgcn_readfirstlane(offs_d[n]);
      j1 = __builtin_amdgcn_readfirstlane(offs_d[n+1]);
      for (int jb = j0; jb < j1; jb += 4){
        int rem = j1 - jb;
        const u32x4* ap = (const u32x4*)adj_d + jb;
        u32x4 a0 = ap[0], a1 = ap[1], a2 = ap[2], a3 = ap[3];
        uint2 g0 = Go[(size_t)a0.x*64 + lane];
        uint2 g1 = Go[(size_t)a1.x*64 + lane];
        uint2 g2 = Go[(size_t)a2.x*64 + lane];
        uint2 g3 = Go[(size_t)a3.x*64 + lane];
        edge_acc(a0, g0, true,  poO, wo0, wo1, wo2, ax, ay);
        edge_acc(a1, g1, rem>1, poO, wo0, wo1, wo2, ax, ay);
        edge_acc(a2, g2, rem>2, poO, wo0, wo1, wo2, ax, ay);
        edge_acc(a3, g3, rem>3, poO, wo0, wo1, wo2, ax, ay);
      }
      float vx = unpack_h2(gown.x).y + ax;
      float vy = unpack_h2(gown.y).y + ay;
      float s = vx+vy, sq = vx*vx + vy*vy;
      #pragma unroll
      for (int o = 32; o; o >>= 1){ s += __shfl_xor(s, o); sq += __shfl_xor(sq, o); }
      float mean = s*(1.f/128.f);
      float inv = rsqrtf(sq*(1.f/128.f) - mean*mean + EPSF);
      float2 o2;
      o2.x = (vx-mean)*inv*g2v.x + be2.x;
      o2.y = (vy-mean)*inv*g2v.y + be2.y;
      ((float2*)to)[(size_t)n*64 + lane] = o2;
    }
  } else {
    int b = blockIdx.x;
    int tid = threadIdx.x;
    int dir = tid >> 8, g = tid & 255;
    const float* Whh = dir ? Whh_b : Whh_f;
    const float* pre = dir ? pre_b : pre_f;
    float w[64];
    #pragma unroll
    for (int q = 0; q < 16; q++){
      float4 t4 = *(const float4*)(Whh + (size_t)g*64 + 4*q);
      w[4*q] = t4.x; w[4*q+1] = t4.y; w[4*q+2] = t4.z; w[4*q+3] = t4.w;
    }
    float c = 0.f;
    for (int t = 0; t < LSEQ; ++t){
      int tt = dir ? (LSEQ-1-t) : t;
      float gate = pre[((size_t)b*LSEQ + tt)*G4 + g];
      if (t > 0){
        #pragma unroll
        for (int q = 0; q < 16; q++){
          float4 h4 = *(const float4*)&u.sq.hcur[dir][4*q];
          gate += w[4*q]*h4.x + w[4*q+1]*h4.y + w[4*q+2]*h4.z + w[4*q+3]*h4.w;
        }
      }
      u.sq.gsh[dir][g] = gate;
      __syncthreads();
      if (g < 64){
        float iv = u.sq.gsh[dir][g], fv = u.sq.gsh[dir][64+g];
        float gv = u.sq.gsh[dir][128+g], ov = u.sq.gsh[dir][192+g];
        c = sigf(fv)*c + sigf(iv)*tanhf(gv);
        float h = sigf(ov)*tanhf(c);
        u.sq.hcur[dir][g] = h;
        u.sq.h_hist[dir][tt][g] = h;
      }
      __syncthreads();
    }
    // residual + LN, wave per row; keep result in soL for next-step pre-GEMM
    int wv = tid >> 6, lane = tid & 63;
    for (int l = wv; l < LSEQ; l += 8){
      float2 sv = ((const float2*)(seq_in + ((size_t)b*LSEQ + l)*128))[lane];
      float hv0, hv1;
      if (lane < 32){ hv0 = u.sq.h_hist[0][l][2*lane];    hv1 = u.sq.h_hist[0][l][2*lane+1]; }
      else          { hv0 = u.sq.h_hist[1][l][2*lane-64]; hv1 = u.sq.h_hist[1][l][2*lane-63]; }
      float vx = sv.x + hv0, vy = sv.y + hv1;
      float s = vx+vy, sq = vx*vx + vy*vy;
      #pragma unroll
      for (int o = 32; o; o >>= 1){ s += __shfl_xor(s, o); sq += __shfl_xor(sq, o); }
      float mean = s*(1.f/128.f);
      float inv = rsqrtf(sq*(1.f/128.f) - mean*mean + EPSF);
      float2 g2 = ((const float2*)ln_seq_g)[lane], b2 = ((const float2*)ln_seq_b)[lane];
      float2 o2;
      o2.x = (vx-mean)*inv*g2.x + b2.x;
      o2.y = (vy-mean)*inv*g2.y + b2.y;
      ((float2*)(so + ((size_t)b*LSEQ + l)*128))[lane] = o2;
      u.sq.soL[l*128 + 2*lane]     = o2.x;
      u.sq.soL[l*128 + 2*lane + 1] = o2.y;
    }
    if (!doNext) return;
    __syncthreads();
    // stage seq_in(i+1) = s0s_n? + soL + otherS -> shG + global seq_in
    {
      const float4* oS4 = (const float4*)(otherS + (size_t)b*LSEQ*128);
      const float4* s04 = s0s_n ? (const float4*)(s0s_n + (size_t)b*LSEQ*128) : nullptr;
      float4* gi4 = (float4*)(seq_in + (size_t)b*LSEQ*128);
      for (int idx = tid; idx < LSEQ*32; idx += 512){
        float4 v = *(const float4*)&u.sq.soL[idx*4];
        float4 o = oS4[idx];
        v.x += o.x; v.y += o.y; v.z += o.z; v.w += o.w;
        if (s04){ float4 s0 = s04[idx]; v.x += s0.x; v.y += s0.y; v.z += s0.z; v.w += s0.w; }
        *(float4*)&u.sq.shG[idx*4] = v;
        gi4[idx] = v;
      }
    }
    __syncthreads();
    // pre-GEMM(i+1): 512 threads, dir-split
    {
      int g2 = tid & 255;
      int dn = tid >> 8;
      const float* wp = (dn ? Wih_b : Wih_f) + (size_t)g2*128;
      float bsv = dn ? bsum_b[g2] : bsum_f[g2];
      float accv[LSEQ];
      #pragma unroll
      for (int l = 0; l < LSEQ; l++) accv[l] = bsv;
      for (int kc = 0; kc < 128; kc += 16){
        float4 wf[4];
        #pragma unroll
        for (int q = 0; q < 4; q++) wf[q] = *(const float4*)(wp + kc + 4*q);
        #pragma unroll
        for (int l = 0; l < LSEQ; l++){
          #pragma unroll
          for (int q = 0; q < 4; q++){
            float4 s4 = *(const float4*)&u.sq.shG[l*128 + kc + 4*q];
            accv[l] += s4.x*wf[q].x + s4.y*wf[q].y + s4.z*wf[q].z + s4.w*wf[q].w;
          }
        }
      }
      float* dst = dn ? pre_b : pre_f;
      for (int l = 0; l < LSEQ; l++)
        dst[((size_t)b*LSEQ + l)*G4 + g2] = accv[l];
    }
  }
}

// ---------------------------------------------------------------- epilogue
__global__ void k_final(float* __restrict__ out, const float* __restrict__ sy,
                        const float* __restrict__ ty, const int* __restrict__ starts,
                        const float* __restrict__ g, const float* __restrict__ b,
                        const float* __restrict__ rm, const float* __restrict__ rv, int Bb){
  int i = blockIdx.x*blockDim.x + threadIdx.x;
  if (i >= Bb*D) return;
  int bb = i >> 7, d = i & 127;
  float feat = sy[((size_t)bb*LSEQ + 10)*D + d] + ty[(size_t)starts[bb]*D + d];
  out[i] = (feat - rm[d])*rsqrtf(rv[d]+EPSF)*g[d] + b[d];
}

// ---------------------------------------------------------------- host
extern "C" void kernel_launch(void* const* d_in, const int* in_sizes, int n_in,
                              void* d_out, int out_size, void* d_ws, size_t ws_size,
                              hipStream_t stream)
{
  const float* x        = (const float*)d_in[0];
  const int*   ei       = (const int*)  d_in[1];
  const float* eattr    = (const float*)d_in[2];
  const int*   batch    = (const int*)  d_in[3];
  const float* hotslice = (const float*)d_in[4];
  const float* nsy      = (const float*)d_in[5];
  const float* nsz      = (const float*)d_in[6];
  const float* nty      = (const float*)d_in[7];
  const float* ntz      = (const float*)d_in[8];
  const float* W_esm    = (const float*)d_in[9];
  const float* b_esm    = (const float*)d_in[10];
  const float* W_node   = (const float*)d_in[11];
  const float* b_node   = (const float*)d_in[12];
  const float* W_seq    = (const float*)d_in[13];
  const float* b_seq    = (const float*)d_in[14];
  const float* ln_seq_g = (const float*)d_in[15];
  const float* ln_seq_b = (const float*)d_in[16];
  const float* ln_st_g  = (const float*)d_in[17];
  const float* ln_st_b  = (const float*)d_in[18];
  const float* W_in     = (const float*)d_in[19];
  const float* b_in     = (const float*)d_in[20];
  const float* W_out    = (const float*)d_in[21];
  const float* b_out    = (const float*)d_in[22];
  const float* Wih_f    = (const float*)d_in[23];
  const float* Whh_f    = (const float*)d_in[24];
  const float* bih_f    = (const float*)d_in[25];
  const float* bhh_f    = (const float*)d_in[26];
  const float* Wih_b    = (const float*)d_in[27];
  const float* Whh_b    = (const float*)d_in[28];
  const float* bih_b    = (const float*)d_in[29];
  const float* bhh_b    = (const float*)d_in[30];
  const float* bn_g     = (const float*)d_in[31];
  const float* bn_b     = (const float*)d_in[32];
  const float* bn_rm    = (const float*)d_in[33];
  const float* bn_rv    = (const float*)d_in[34];

  const int N  = in_sizes[0] / 2561;
  const int E  = in_sizes[1] / 2;
  const int E2 = E / 2;
  const int Bb = in_sizes[4] / (LSEQ*28);
  const int BL = Bb*LSEQ;

  // ---- workspace carve
  char* p = (char*)d_ws;
  auto alloc = [&](size_t bytes)->void*{
    void* r = (void*)p; p += (bytes + 255) & ~(size_t)255; return r;
  };
  float*    seq0      = (float*)alloc((size_t)BL*D*4);
  float*    sy        = (float*)alloc((size_t)BL*D*4);
  float*    sz        = (float*)alloc((size_t)BL*D*4);
  float*    seq_in    = (float*)alloc((size_t)BL*D*4);
  float*    pre_f     = (float*)alloc((size_t)BL*G4*4);
  float*    pre_b     = (float*)alloc((size_t)BL*G4*4);
  float*    struct0   = (float*)alloc((size_t)N*D*4);
  float*    ty        = (float*)alloc((size_t)N*D*4);
  float*    tz        = (float*)alloc((size_t)N*D*4);
  unsigned* G_in      = (unsigned*)alloc((size_t)N*D*4);
  unsigned* G_out     = (unsigned*)alloc((size_t)N*D*4);
  unsigned* PownPk    = (unsigned*)alloc((size_t)N*D*4);
  u16*      PB4h      = (u16*)alloc(65536*2);
  u16*      PB4l      = (u16*)alloc(65536*2);
  u16*      PBnh      = (u16*)alloc(16384*2);
  u16*      PBnl      = (u16*)alloc(16384*2);
  u16*      PBEh      = (u16*)alloc(327680*2);
  u16*      PBEl      = (u16*)alloc(327680*2);
  float*    WEin      = (float*)alloc(384*4);
  float*    WEout     = (float*)alloc(384*4);
  float*    bsum_f    = (float*)alloc(256*4);
  float*    bsum_b    = (float*)alloc(256*4);
  int*      starts    = (int*)alloc((size_t)Bb*4);
  int*      cnt_s     = (int*)alloc((size_t)N*4);
  int*      cnt_d     = (int*)alloc((size_t)N*4);
  int*      offs_s    = (int*)alloc((size_t)(N+1)*4);
  int*      offs_d    = (int*)alloc((size_t)(N+1)*4);
  int*      cur_s     = (int*)alloc((size_t)N*4);
  int*      cur_d     = (int*)alloc((size_t)N*4);
  int4*     adj_s     = (int4*)alloc((size_t)(E2+8)*16);
  int4*     adj_d     = (int4*)alloc((size_t)(E2+8)*16);
  (void)ws_size; (void)n_in; (void)out_size;

  // ---- init state from noise inputs
  hipMemcpyAsync(sy, nsy, (size_t)BL*D*4, hipMemcpyDeviceToDevice, stream);
  hipMemcpyAsync(sz, nsz, (size_t)BL*D*4, hipMemcpyDeviceToDevice, stream);
  hipMemcpyAsync(ty, nty, (size_t)N*D*4, hipMemcpyDeviceToDevice, stream);
  hipMemcpyAsync(tz, ntz, (size_t)N*D*4, hipMemcpyDeviceToDevice, stream);

  // ---- prologue
  k_misc<<<1, 256, 0, stream>>>(starts, batch, N, Bb, WEin, WEout, W_in, W_out,
                                bsum_f, bsum_b, bih_f, bhh_f, bih_b, bhh_b);
  k_packB<<<1600, 256, 0, stream>>>(PB4h, PB4l, PBnh, PBnl, PBEh, PBEl,
                                    W_in, W_out, W_node, W_esm);
  k_seq0<<<BL, 128, 0, stream>>>(seq0, hotslice, W_seq, b_seq);
  k_esm2<<<N/32, 256, 0, stream>>>(struct0, x, PBEh, PBEl, PBnh, PBnl,
                                   b_esm, W_node, b_node);
  k_zero2<<<(N+255)/256, 256, 0, stream>>>(cnt_s, cnt_d, N);
  k_count<<<(E2+255)/256, 256, 0, stream>>>(cnt_s, cnt_d, ei, E2);
  k_scan<<<1, 1024, 0, stream>>>(cnt_s, offs_s, N);
  k_scan<<<1, 1024, 0, stream>>>(cnt_d, offs_d, N);
  k_copy2<<<(N+255)/256, 256, 0, stream>>>(cur_s, offs_s, cur_d, offs_d, N);
  k_fill<<<(E2+255)/256, 256, 0, stream>>>(ei, eattr, E2, cur_s, adj_s, cur_d, adj_d);
  k_pad<<<1, 64, 0, stream>>>(adj_s, adj_d, E2);
  // initial seq_in(0)/pre(0)  (step 0 is inner: s0s = seq0)
  k_seqA<<<Bb, 256, 0, stream>>>(seq0, sy, sz, seq_in, pre_f, pre_b,
                                 Wih_f, Wih_b, bsum_f, bsum_b);

  const int NB = N/32;

  // ---- main loop: 8 outer x (4 inner + 1)
  for (int o = 0; o < 8; ++o){
    for (int it = 0; it < 5; ++it){
      int gi = o*5 + it;
      bool inner = (it < 4);
      const float* s0t = inner ? struct0 : nullptr;
      float* to_ = inner ? tz : ty;
      float* so_ = inner ? sz : sy;
      const float* otherS = inner ? sy : sz;
      int itn = (gi+1) % 5;
      const float* s0s_n = (itn < 4) ? seq0 : nullptr;
      int doNext = (gi < 39) ? 1 : 0;
      k_A<<<NB, 256, 0, stream>>>(s0t, ty, tz, PB4h, PB4l,
                                  G_in, G_out, PownPk, b_in, b_out, N);
      k_B<<<Bb + NB, 512, 0, stream>>>(G_in, G_out, PownPk, to_,
                                       offs_s, adj_s, offs_d, adj_d,
                                       WEin, WEout, ln_st_g, ln_st_b,
                                       pre_f, pre_b, Whh_f, Whh_b,
                                       seq_in, so_, otherS, s0s_n,
                                       Wih_f, Wih_b, bsum_f, bsum_b,
                                       ln_seq_g, ln_seq_b, doNext, N, Bb);
    }
  }

  k_final<<<(Bb*D+255)/256, 256, 0, stream>>>((float*)d_out, sy, ty, starts,
                                              bn_g, bn_b, bn_rm, bn_rv, Bb);
}

// Round 13
// 3573.372 us; speedup vs baseline: 1.2596x; 1.0157x over previous
//
#include <hip/hip_runtime.h>
#include <hip/hip_fp16.h>
#include <math.h>

#define D 128
#define G4 256
#define LSEQ 21
#define EPSF 1e-5f

typedef unsigned short u16;
typedef __attribute__((ext_vector_type(8))) short bf16x8;
typedef __attribute__((ext_vector_type(4))) float f32x4;
typedef __attribute__((ext_vector_type(2))) unsigned u32x2;
typedef __attribute__((ext_vector_type(4))) unsigned u32x4;

#define MFMA16(a,b,c) __builtin_amdgcn_mfma_f32_16x16x32_bf16(a,b,c,0,0,0)

// ---------------------------------------------------------------- helpers
__device__ __forceinline__ float sigf(float x){ return 1.0f/(1.0f+__expf(-x)); }
__device__ __forceinline__ u16 f2bf(float x){
  unsigned u = __float_as_uint(x);
  return (u16)((u + 0x7FFFu + ((u>>16)&1u)) >> 16);
}
__device__ __forceinline__ float bf2f(u16 h){ return __uint_as_float(((unsigned)h)<<16); }
__device__ __forceinline__ unsigned pack_h2(float a, float b){
  __half2 h = __floats2half2_rn(a, b);
  return *(unsigned*)&h;
}
__device__ __forceinline__ float2 unpack_h2(unsigned u){
  __half2 h = *(__half2*)&u;
  return __half22float2(h);
}
__device__ __forceinline__ u16 f2h(float v){ __half h = __float2half(v); return *(u16*)&h; }

__device__ __forceinline__ void edge_acc(u32x4 a, uint2 g, bool valid,
                                         float2 po2, float2 w0, float2 w1, float2 w2,
                                         float& ax, float& ay){
  float e0=__uint_as_float(a.y), e1=__uint_as_float(a.z), e2=__uint_as_float(a.w);
  float2 ps0 = unpack_h2(g.x);   // {P(ch0), S(ch0)}
  float2 ps1 = unpack_h2(g.y);   // {P(ch1), S(ch1)}
  float gx = po2.x + ps0.x + e0*w0.x + e1*w1.x + e2*w2.x;
  float gy = po2.y + ps1.x + e0*w0.y + e1*w1.y + e2*w2.y;
  float mm = valid ? 1.f : 0.f;
  ax = fmaf(ps0.y*mm, sigf(gx), ax);
  ay = fmaf(ps1.y*mm, sigf(gy), ay);
}

// ---------------------------------------------------------------- prologue kernels
__global__ void k_misc(int* __restrict__ starts, const int* __restrict__ batch, int N, int Bb,
                       float* __restrict__ WEin, float* __restrict__ WEout,
                       const float* __restrict__ W_in, const float* __restrict__ W_out,
                       float* __restrict__ bsum_f, float* __restrict__ bsum_b,
                       const float* __restrict__ bih_f, const float* __restrict__ bhh_f,
                       const float* __restrict__ bih_b, const float* __restrict__ bhh_b){
  int tid = threadIdx.x;
  if (tid < Bb){
    int lo = 0, hi = N;
    while (lo < hi){ int m = (lo+hi)>>1; if (batch[m] < tid) lo = m+1; else hi = m; }
    starts[tid] = lo;
  }
  for (int i = tid; i < 384; i += 256){
    int t = i >> 7, j = i & 127;
    WEin [i] = W_in [(size_t)j*259 + 256 + t];
    WEout[i] = W_out[(size_t)j*259 + 256 + t];
  }
  if (tid < 256){
    bsum_f[tid] = bih_f[tid] + bhh_f[tid];
    bsum_b[tid] = bih_b[tid] + bhh_b[tid];
  }
}

// pre-pack MFMA B-fragments (hi/lo bf16), layout [nt][ks][lane][8] contiguous
__global__ void k_packB(u16* __restrict__ PB4h, u16* __restrict__ PB4l,
                        u16* __restrict__ PBnh, u16* __restrict__ PBnl,
                        u16* __restrict__ PBEh, u16* __restrict__ PBEl,
                        const float* __restrict__ W_in, const float* __restrict__ W_out,
                        const float* __restrict__ W_node, const float* __restrict__ W_esm){
  int idx = blockIdx.x*256 + threadIdx.x;
  if (idx < 65536){
    int j = idx&7, l=(idx>>3)&63, q=idx>>9;
    int ks = q&3, nt = q>>2;
    int c = nt*16 + (l&15);
    int k = ks*32 + ((l>>4)<<3) + j;
    float v;
    if (c < 128)      v = W_in [(size_t)c*259 + k];
    else if (c < 256) v = W_in [(size_t)(c-128)*259 + 128 + k];
    else if (c < 384) v = W_out[(size_t)(c-256)*259 + k];
    else              v = W_out[(size_t)(c-384)*259 + 128 + k];
    u16 h = f2bf(v);
    PB4h[idx] = h; PB4l[idx] = f2bf(v - bf2f(h));
  } else if (idx < 65536 + 16384){
    int p = idx - 65536;
    int j = p&7, l=(p>>3)&63, q=p>>9;
    int ks = q&3, nt = q>>2;
    int c = nt*16 + (l&15);
    int k = ks*32 + ((l>>4)<<3) + j;
    float v = W_node[(size_t)c*129 + k];
    u16 h = f2bf(v);
    PBnh[p] = h; PBnl[p] = f2bf(v - bf2f(h));
  } else if (idx < 65536 + 16384 + 327680){
    int p = idx - 81920;
    int j = p&7, l=(p>>3)&63, q=p>>9;
    int ks = q%80, nt = q/80;
    int c = nt*16 + (l&15);
    int k = ks*32 + ((l>>4)<<3) + j;
    float v = W_esm[(size_t)c*2560 + k];
    u16 h = f2bf(v);
    PBEh[p] = h; PBEl[p] = f2bf(v - bf2f(h));
  }
}

__global__ void k_seq0(float* __restrict__ seq0, const float* __restrict__ hot,
                       const float* __restrict__ W_seq, const float* __restrict__ b_seq){
  int row = blockIdx.x, j = threadIdx.x;           // 128 threads
  const float* h = hot + (size_t)row*28;
  const float* w = W_seq + (size_t)j*28;
  float acc = b_seq[j];
  #pragma unroll
  for (int k = 0; k < 28; k++) acc += h[k]*w[k];
  seq0[(size_t)row*D + j] = acc;
}

// fused: esm = x[:,1:] @ W_esm.T + b_esm ; struct0 = [esm, x[:,:1]] @ W_node.T + b_node
// 16 rows/block (1024 blocks -> 4 blocks/CU), register dbuf staging, conflict-free writes
__global__ __launch_bounds__(256) void k_esm2(float* __restrict__ struct0, const float* __restrict__ x,
    const u16* __restrict__ PBEh, const u16* __restrict__ PBEl,
    const u16* __restrict__ PBnh, const u16* __restrict__ PBnl,
    const float* __restrict__ b_esm, const float* __restrict__ W_node,
    const float* __restrict__ b_node){
  __shared__ union {
    struct { u16 xh[16*72], xl[16*72]; } p1;
    struct { u16 Ah[16*136], Al[16*136]; } p2;
  } uu;
  __shared__ float esmF[16*132];
  int tid = threadIdx.x;
  int r0 = blockIdx.x*16;
  int w = tid>>6, l = tid&63;
  f32x4 acc[2];
  acc[0] = (f32x4){0.f,0.f,0.f,0.f};
  acc[1] = (f32x4){0.f,0.f,0.f,0.f};

  float xv[4];
  int rr = tid >> 5, k2i = tid & 31;      // rows rr, rr+8 ; col pair k2i
  #pragma unroll
  for (int q = 0; q < 2; q++){
    const float* src = x + (size_t)(r0+rr+8*q)*2561 + 1 + k2i*2;
    xv[2*q]   = src[0];
    xv[2*q+1] = src[1];
  }
  for (int kc = 0; kc < 2560; kc += 64){
    __syncthreads();
    unsigned* xh32 = (unsigned*)uu.p1.xh;
    unsigned* xl32 = (unsigned*)uu.p1.xl;
    #pragma unroll
    for (int q = 0; q < 2; q++){
      float v0 = xv[2*q], v1 = xv[2*q+1];
      u16 h0 = f2bf(v0), h1 = f2bf(v1);
      u16 l0 = f2bf(v0 - bf2f(h0)), l1 = f2bf(v1 - bf2f(h1));
      int r = rr + 8*q;
      xh32[r*36 + k2i] = (unsigned)h0 | ((unsigned)h1 << 16);
      xl32[r*36 + k2i] = (unsigned)l0 | ((unsigned)l1 << 16);
    }
    __syncthreads();
    if (kc + 64 < 2560){
      #pragma unroll
      for (int q = 0; q < 2; q++){
        const float* src = x + (size_t)(r0+rr+8*q)*2561 + 1 + kc + 64 + k2i*2;
        xv[2*q]   = src[0];
        xv[2*q+1] = src[1];
      }
    }
    #pragma unroll
    for (int ks = 0; ks < 2; ks++){
      bf16x8 ah, al;
      {
        int row = l&15;
        int k = ks*32 + ((l>>4)<<3);
        ah = *(const bf16x8*)&uu.p1.xh[row*72 + k];
        al = *(const bf16x8*)&uu.p1.xl[row*72 + k];
      }
      int ksg = (kc>>5) + ks;
      #pragma unroll
      for (int ctl = 0; ctl < 2; ctl++){
        int nt = w*2 + ctl;
        bf16x8 bh = *(const bf16x8*)&PBEh[((size_t)(nt*80 + ksg)*64 + l)*8];
        bf16x8 bl = *(const bf16x8*)&PBEl[((size_t)(nt*80 + ksg)*64 + l)*8];
        acc[ctl] = MFMA16(ah, bh, acc[ctl]);
        acc[ctl] = MFMA16(al, bh, acc[ctl]);
        acc[ctl] = MFMA16(ah, bl, acc[ctl]);
      }
    }
  }
  __syncthreads();
  int cq = l & 15, rqb = (l>>4)*4;
  #pragma unroll
  for (int ctl = 0; ctl < 2; ctl++){
    int coln = (w*2+ctl)*16 + cq;
    float be = b_esm[coln];
    #pragma unroll
    for (int r = 0; r < 4; r++)
      esmF[(rqb+r)*132 + coln] = acc[ctl][r] + be;
  }
  __syncthreads();
  {
    unsigned* Ah32 = (unsigned*)uu.p2.Ah;
    unsigned* Al32 = (unsigned*)uu.p2.Al;
    int rr2 = tid >> 6, k2 = tid & 63;   // 4 rows/iter, 64 col-pairs
    #pragma unroll
    for (int q = 0; q < 4; q++){
      int r = rr2 + 4*q;
      float v0 = esmF[r*132 + k2*2];
      float v1 = esmF[r*132 + k2*2 + 1];
      u16 h0 = f2bf(v0), h1 = f2bf(v1);
      u16 l0 = f2bf(v0 - bf2f(h0)), l1 = f2bf(v1 - bf2f(h1));
      Ah32[r*68 + k2] = (unsigned)h0 | ((unsigned)h1 << 16);
      Al32[r*68 + k2] = (unsigned)l0 | ((unsigned)l1 << 16);
    }
  }
  __syncthreads();
  f32x4 acc2[2];
  acc2[0] = (f32x4){0.f,0.f,0.f,0.f};
  acc2[1] = (f32x4){0.f,0.f,0.f,0.f};
  #pragma unroll
  for (int ks = 0; ks < 4; ks++){
    bf16x8 ah, al;
    {
      int row = l&15;
      int k = ks*32 + ((l>>4)<<3);
      ah = *(const bf16x8*)&uu.p2.Ah[row*136 + k];
      al = *(const bf16x8*)&uu.p2.Al[row*136 + k];
    }
    #pragma unroll
    for (int ctl = 0; ctl < 2; ctl++){
      int nt = w*2 + ctl;
      bf16x8 bh = *(const bf16x8*)&PBnh[((size_t)(nt*4 + ks)*64 + l)*8];
      bf16x8 bl = *(const bf16x8*)&PBnl[((size_t)(nt*4 + ks)*64 + l)*8];
      acc2[ctl] = MFMA16(ah, bh, acc2[ctl]);
      acc2[ctl] = MFMA16(al, bh, acc2[ctl]);
      acc2[ctl] = MFMA16(ah, bl, acc2[ctl]);
    }
  }
  #pragma unroll
  for (int ctl = 0; ctl < 2; ctl++){
    int col = (w*2+ctl)*16 + cq;
    float wl = W_node[(size_t)col*129 + 128];
    float bn = b_node[col];
    #pragma unroll
    for (int r = 0; r < 4; r++){
      int row = r0 + rqb + r;
      float x0 = x[(size_t)row*2561];
      struct0[(size_t)row*D + col] = acc2[ctl][r] + x0*wl + bn;
    }
  }
}

// ---------------------------------------------------------------- CSR build
__global__ void k_zero2(int* a, int* b, int n){
  int i = blockIdx.x*blockDim.x + threadIdx.x;
  if (i < n){ a[i] = 0; b[i] = 0; }
}
__global__ void k_count(int* cnt_s, int* cnt_d, const int* __restrict__ ei, int E2){
  int e = blockIdx.x*blockDim.x + threadIdx.x;
  if (e < E2){
    atomicAdd(&cnt_s[ei[2*e]], 1);
    atomicAdd(&cnt_d[ei[2*E2 + 2*e]], 1);
  }
}
// parallel 3-phase scan over cnt_s and cnt_d together
__global__ __launch_bounds__(1024) void k_scanp1(const int* __restrict__ cnt_s,
                                                 const int* __restrict__ cnt_d,
                                                 int* __restrict__ part, int n, int nch){
  int arr = blockIdx.x / nch, chunk = blockIdx.x % nch;
  const int* cnt = arr ? cnt_d : cnt_s;
  int i = chunk*1024 + threadIdx.x;
  int v = (i < n) ? cnt[i] : 0;
  __shared__ int ws[16];
  #pragma unroll
  for (int o = 32; o; o >>= 1) v += __shfl_down(v, o);
  if ((threadIdx.x & 63) == 0) ws[threadIdx.x >> 6] = v;
  __syncthreads();
  if (threadIdx.x == 0){
    int t = 0;
    #pragma unroll
    for (int q = 0; q < 16; q++) t += ws[q];
    part[blockIdx.x] = t;
  }
}
__global__ void k_scanp2(int* part, int nch){
  int tid = threadIdx.x;
  if (tid < 2){
    int base = 0;
    for (int i = 0; i < nch; i++){
      int v = part[tid*nch + i];
      part[tid*nch + i] = base;
      base += v;
    }
  }
}
__global__ __launch_bounds__(1024) void k_scanp3(const int* __restrict__ cnt_s,
                                                 const int* __restrict__ cnt_d,
                                                 const int* __restrict__ part,
                                                 int* __restrict__ offs_s, int* __restrict__ offs_d,
                                                 int n, int nch){
  int arr = blockIdx.x / nch, chunk = blockIdx.x % nch;
  const int* cnt = arr ? cnt_d : cnt_s;
  int* offs = arr ? offs_d : offs_s;
  __shared__ int sh[1024];
  int tid = threadIdx.x;
  int i = chunk*1024 + tid;
  int v = (i < n) ? cnt[i] : 0;
  sh[tid] = v;
  __syncthreads();
  for (int off = 1; off < 1024; off <<= 1){
    int t = (tid >= off) ? sh[tid-off] : 0;
    __syncthreads();
    sh[tid] += t;
    __syncthreads();
  }
  int base = part[blockIdx.x];
  if (i < n) offs[i] = base + sh[tid] - v;
  if (i == n-1) offs[n] = base + sh[tid];
}
__global__ void k_copy2(int* cur_s, const int* offs_s, int* cur_d, const int* offs_d, int n){
  int i = blockIdx.x*blockDim.x + threadIdx.x;
  if (i < n){ cur_s[i] = offs_s[i]; cur_d[i] = offs_d[i]; }
}
__global__ void k_fill(const int* __restrict__ ei, const float* __restrict__ eattr, int E2,
                       int* cur_s, int4* __restrict__ adj_s,
                       int* cur_d, int4* __restrict__ adj_d){
  int e = blockIdx.x*blockDim.x + threadIdx.x;
  if (e >= E2) return;
  int s = ei[2*e];
  int d = ei[2*E2 + 2*e];
  const float* ein  = eattr + (size_t)(2*e+1)*3;
  const float* eout = eattr + (size_t)(2*e)*3;
  int ps = atomicAdd(&cur_s[s], 1);
  adj_s[ps] = make_int4(d, __float_as_int(ein[0]),  __float_as_int(ein[1]),  __float_as_int(ein[2]));
  int pd = atomicAdd(&cur_d[d], 1);
  adj_d[pd] = make_int4(s, __float_as_int(eout[0]), __float_as_int(eout[1]), __float_as_int(eout[2]));
}
__global__ void k_pad(int4* __restrict__ adj_s, int4* __restrict__ adj_d, int E2){
  int t = threadIdx.x;
  if (t < 8){
    adj_s[E2+t] = make_int4(0,0,0,0);
    adj_d[E2+t] = make_int4(0,0,0,0);
  }
}

// ---------------------------------------------------------------- initial seq pre-GEMM
__global__ __launch_bounds__(256) void k_seqA(
  const float* __restrict__ s0s, const float* __restrict__ sy, const float* __restrict__ sz,
  float* __restrict__ seq_in, float* __restrict__ pre_f, float* __restrict__ pre_b,
  const float* __restrict__ Wih_f, const float* __restrict__ Wih_b,
  const float* __restrict__ bsum_f, const float* __restrict__ bsum_b)
{
  __shared__ float sh[LSEQ*128];
  int tid = threadIdx.x;
  int b = blockIdx.x;
  for (int idx = tid; idx < LSEQ*128; idx += 256){
    size_t off = (size_t)b*LSEQ*128 + idx;
    float v = sy[off] + sz[off];
    if (s0s) v += s0s[off];
    sh[idx] = v;
    seq_in[off] = v;
  }
  __syncthreads();
  int g = tid;  // 0..255
  float accf[LSEQ], accb[LSEQ];
  float bf = bsum_f[g], bb = bsum_b[g];
  #pragma unroll
  for (int l = 0; l < LSEQ; l++){ accf[l] = bf; accb[l] = bb; }
  const float* wfp = Wih_f + (size_t)g*128;
  const float* wbp = Wih_b + (size_t)g*128;
  for (int kc = 0; kc < 128; kc += 16){
    float4 wf[4], wb[4];
    #pragma unroll
    for (int q = 0; q < 4; q++){
      wf[q] = *(const float4*)(wfp + kc + 4*q);
      wb[q] = *(const float4*)(wbp + kc + 4*q);
    }
    #pragma unroll
    for (int l = 0; l < LSEQ; l++){
      #pragma unroll
      for (int q = 0; q < 4; q++){
        float4 s4 = *(const float4*)&sh[l*128 + kc + 4*q];
        accf[l] += s4.x*wf[q].x + s4.y*wf[q].y + s4.z*wf[q].z + s4.w*wf[q].w;
        accb[l] += s4.x*wb[q].x + s4.y*wb[q].y + s4.z*wb[q].z + s4.w*wb[q].w;
      }
    }
  }
  for (int l = 0; l < LSEQ; l++){
    pre_f[((size_t)b*LSEQ + l)*G4 + g] = accf[l];
    pre_b[((size_t)b*LSEQ + l)*G4 + g] = accb[l];
  }
}

// ---------------------------------------------------------------- per-step kernel A (struct only)
__global__ __launch_bounds__(256) void k_A(
  const float* __restrict__ s0t, const float* __restrict__ ty, const float* __restrict__ tz,
  const u16* __restrict__ PB4h, const u16* __restrict__ PB4l,
  unsigned* __restrict__ G_in, unsigned* __restrict__ G_out,
  unsigned* __restrict__ PownPk,
  const float* __restrict__ b_in, const float* __restrict__ b_out, int N)
{
  __shared__ struct { u16 Ah[32*136], Al[32*136]; float Sf[32*132]; } m;
  int tid = threadIdx.x;
  int r0 = blockIdx.x*32;
  const float4* ty4 = (const float4*)(ty + (size_t)r0*D);
  const float4* tz4 = (const float4*)(tz + (size_t)r0*D);
  const float4* s04 = s0t ? (const float4*)(s0t + (size_t)r0*D) : nullptr;
  #pragma unroll
  for (int q = 0; q < 4; q++){
    int i = tid + 256*q;          // float4 index, 0..1023
    int r = i >> 5, k4 = i & 31;
    float4 v = ty4[i];
    float4 z = tz4[i];
    v.x += z.x; v.y += z.y; v.z += z.z; v.w += z.w;
    if (s04){ float4 s = s04[i]; v.x += s.x; v.y += s.y; v.z += s.z; v.w += s.w; }
    u16 h0 = f2bf(v.x), h1 = f2bf(v.y), h2 = f2bf(v.z), h3 = f2bf(v.w);
    *(ushort4*)&m.Ah[r*136 + k4*4] = make_ushort4(h0,h1,h2,h3);
    *(ushort4*)&m.Al[r*136 + k4*4] = make_ushort4(
        f2bf(v.x - bf2f(h0)), f2bf(v.y - bf2f(h1)),
        f2bf(v.z - bf2f(h2)), f2bf(v.w - bf2f(h3)));
    *(float4*)&m.Sf[r*132 + k4*4] = v;
  }
  __syncthreads();
  int w = tid >> 6, l = tid & 63;
  f32x4 acc[2][8];
  #pragma unroll
  for (int a=0;a<2;a++)
    #pragma unroll
    for (int b=0;b<8;b++) acc[a][b] = (f32x4){0.f,0.f,0.f,0.f};
  #pragma unroll
  for (int ks = 0; ks < 4; ks++){
    bf16x8 ah[2], al[2];
    #pragma unroll
    for (int rt = 0; rt < 2; rt++){
      int row = rt*16 + (l&15);
      int k = ks*32 + ((l>>4)<<3);
      ah[rt] = *(const bf16x8*)&m.Ah[row*136 + k];
      al[rt] = *(const bf16x8*)&m.Al[row*136 + k];
    }
    #pragma unroll
    for (int ct = 0; ct < 8; ct++){
      int nt = w*8 + ct;
      bf16x8 bh = *(const bf16x8*)&PB4h[((size_t)(nt*4 + ks)*64 + l)*8];
      bf16x8 bl = *(const bf16x8*)&PB4l[((size_t)(nt*4 + ks)*64 + l)*8];
      #pragma unroll
      for (int rt = 0; rt < 2; rt++){
        acc[rt][ct] = MFMA16(ah[rt], bh, acc[rt][ct]);
        acc[rt][ct] = MFMA16(al[rt], bh, acc[rt][ct]);
        acc[rt][ct] = MFMA16(ah[rt], bl, acc[rt][ct]);
      }
    }
  }
  // ---- coalesced table epilogue via LDS staging (reuses Ah/Al region) ----
  __syncthreads();                      // MFMA done reading Ah/Al
  unsigned* stg = (unsigned*)m.Ah;      // 32*128 u32 = 16KB (fits in Ah+Al)
  u16* stg16 = (u16*)m.Ah;
  int cq = l & 15, rqb = (l>>4)*4;
  if (w == 1){
    #pragma unroll
    for (int ct = 0; ct < 8; ct++){
      int coln = ct*16 + cq;
      #pragma unroll
      for (int rt = 0; rt < 2; rt++){
        #pragma unroll
        for (int r = 0; r < 4; r++){
          int lr = rt*16 + rqb + r;
          stg[lr*128 + coln] = pack_h2(acc[rt][ct][r], m.Sf[lr*132 + coln]);
        }
      }
    }
  }
  __syncthreads();
  {
    uint4* dst = (uint4*)(G_in + (size_t)r0*D);
    const uint4* src = (const uint4*)stg;
    #pragma unroll
    for (int q = 0; q < 4; q++) dst[tid + 256*q] = src[tid + 256*q];
  }
  __syncthreads();
  if (w == 2){
    #pragma unroll
    for (int ct = 0; ct < 8; ct++){
      int coln = ct*16 + cq;
      #pragma unroll
      for (int rt = 0; rt < 2; rt++){
        #pragma unroll
        for (int r = 0; r < 4; r++){
          int lr = rt*16 + rqb + r;
          stg[lr*128 + coln] = pack_h2(acc[rt][ct][r], m.Sf[lr*132 + coln]);
        }
      }
    }
  }
  __syncthreads();
  {
    uint4* dst = (uint4*)(G_out + (size_t)r0*D);
    const uint4* src = (const uint4*)stg;
    #pragma unroll
    for (int q = 0; q < 4; q++) dst[tid + 256*q] = src[tid + 256*q];
  }
  __syncthreads();
  if (w == 0 || w == 3){
    const float* bb = (w == 0) ? b_in : b_out;
    int half = (w == 0) ? 0 : 1;
    #pragma unroll
    for (int ct = 0; ct < 8; ct++){
      int coln = ct*16 + cq;
      float bc = bb[coln];
      #pragma unroll
      for (int rt = 0; rt < 2; rt++){
        #pragma unroll
        for (int r = 0; r < 4; r++){
          int lr = rt*16 + rqb + r;
          stg16[(lr*128 + coln)*2 + half] = f2h(acc[rt][ct][r] + bc);
        }
      }
    }
  }
  __syncthreads();
  {
    uint4* dst = (uint4*)(PownPk + (size_t)r0*D);
    const uint4* src = (const uint4*)stg;
    #pragma unroll
    for (int q = 0; q < 4; q++) dst[tid + 256*q] = src[tid + 256*q];
  }
}

// ---------------------------------------------------------------- per-step kernel B
// blocks [0,Bb): LSTM(i) + seq LN -> so ; then (doNext) seq_in(i+1) staging + pre-GEMM(i+1)
// blocks [Bb, Bb+N/32): edge gather — wave owns 4 consecutive nodes (both dirs + LN)
__global__ __launch_bounds__(512) void k_B(
  const unsigned* __restrict__ G_in, const unsigned* __restrict__ G_out,
  const unsigned* __restrict__ PownPk,
  float* __restrict__ to,
  const int* __restrict__ offs_s, const int4* __restrict__ adj_s,
  const int* __restrict__ offs_d, const int4* __restrict__ adj_d,
  const float* __restrict__ WEin, const float* __restrict__ WEout,
  const float* __restrict__ ln_st_g, const float* __restrict__ ln_st_b,
  float* pre_f, float* pre_b,
  const float* __restrict__ Whh_f, const float* __restrict__ Whh_b,
  float* seq_in, float* __restrict__ so,
  const float* __restrict__ otherS, const float* __restrict__ s0s_n,
  const float* __restrict__ Wih_f, const float* __restrict__ Wih_b,
  const float* __restrict__ bsum_f, const float* __restrict__ bsum_b,
  const float* __restrict__ ln_seq_g, const float* __restrict__ ln_seq_b,
  int doNext, int N, int Bb)
{
  __shared__ union {
    struct {
      float h_hist[2][LSEQ][64];
      float hcur[2][64];
      float gsh[2][G4];
      float soL[LSEQ*128];
      float shG[LSEQ*128];
    } sq;
  } u;
  if ((int)blockIdx.x >= Bb){
    int wv = threadIdx.x >> 6, lane = threadIdx.x & 63;
    int n0 = ((blockIdx.x - Bb)*8 + wv)*4;           // 4 consecutive nodes per wave
    const float2* WEi2 = (const float2*)WEin;
    const float2* WEo2 = (const float2*)WEout;
    float2 wi0 = WEi2[lane], wi1 = WEi2[64+lane], wi2 = WEi2[128+lane];
    float2 wo0 = WEo2[lane], wo1 = WEo2[64+lane], wo2 = WEo2[128+lane];
    float2 g2v = ((const float2*)ln_st_g)[lane], be2 = ((const float2*)ln_st_b)[lane];
    const uint2* Gi = (const uint2*)G_in;
    const uint2* Go = (const uint2*)G_out;
    #pragma unroll 1
    for (int n = n0; n < n0+4; ++n){
      u32x2 pw = *((const u32x2*)PownPk + (size_t)n*64 + lane);
      float2 pp0 = unpack_h2(pw.x), pp1 = unpack_h2(pw.y);
      float2 poI = make_float2(pp0.x, pp1.x);
      float2 poO = make_float2(pp0.y, pp1.y);
      uint2 gown = Gi[(size_t)n*64 + lane];          // own row: {P_in, S} per channel
      float ax = 0.f, ay = 0.f;
      int j0 = __builtin_amdgcn_readfirstlane(offs_s[n]);
      int j1 = __builtin_amdgcn_readfirstlane(offs_s[n+1]);
      for (int jb = j0; jb < j1; jb += 4){
        int rem = j1 - jb;
        const u32x4* ap = (const u32x4*)adj_s + jb;
        u32x4 a0 = ap[0], a1 = ap[1], a2 = ap[2], a3 = ap[3];
        uint2 g0 = Gi[(size_t)a0.x*64 + lane];
        uint2 g1 = Gi[(size_t)a1.x*64 + lane];
        uint2 g2 = Gi[(size_t)a2.x*64 + lane];
        uint2 g3 = Gi[(size_t)a3.x*64 + lane];
        edge_acc(a0, g0, true,  poI, wi0, wi1, wi2, ax, ay);
        edge_acc(a1, g1, rem>1, poI, wi0, wi1, wi2, ax, ay);
        edge_acc(a2, g2, rem>2, poI, wi0, wi1, wi2, ax, ay);
        edge_acc(a3, g3, rem>3, poI, wi0, wi1, wi2, ax, ay);
      }
      j0 = __builtin_amdgcn_readfirstlane(offs_d[n]);
      j1 = __builtin_amdgcn_readfirstlane(offs_d[n+1]);
      for (int jb = j0; jb < j1; jb += 4){
        int rem = j1 - jb;
        const u32x4* ap = (const u32x4*)adj_d + jb;
        u32x4 a0 = ap[0], a1 = ap[1], a2 = ap[2], a3 = ap[3];
        uint2 g0 = Go[(size_t)a0.x*64 + lane];
        uint2 g1 = Go[(size_t)a1.x*64 + lane];
        uint2 g2 = Go[(size_t)a2.x*64 + lane];
        uint2 g3 = Go[(size_t)a3.x*64 + lane];
        edge_acc(a0, g0, true,  poO, wo0, wo1, wo2, ax, ay);
        edge_acc(a1, g1, rem>1, poO, wo0, wo1, wo2, ax, ay);
        edge_acc(a2, g2, rem>2, poO, wo0, wo1, wo2, ax, ay);
        edge_acc(a3, g3, rem>3, poO, wo0, wo1, wo2, ax, ay);
      }
      float vx = unpack_h2(gown.x).y + ax;
      float vy = unpack_h2(gown.y).y + ay;
      float s = vx+vy, sq = vx*vx + vy*vy;
      #pragma unroll
      for (int o = 32; o; o >>= 1){ s += __shfl_xor(s, o); sq += __shfl_xor(sq, o); }
      float mean = s*(1.f/128.f);
      float inv = rsqrtf(sq*(1.f/128.f) - mean*mean + EPSF);
      float2 o2;
      o2.x = (vx-mean)*inv*g2v.x + be2.x;
      o2.y = (vy-mean)*inv*g2v.y + be2.y;
      ((float2*)to)[(size_t)n*64 + lane] = o2;
    }
  } else {
    int b = blockIdx.x;
    int tid = threadIdx.x;
    int dir = tid >> 8, g = tid & 255;
    const float* Whh = dir ? Whh_b : Whh_f;
    const float* pre = dir ? pre_b : pre_f;
    float w[64];
    #pragma unroll
    for (int q = 0; q < 16; q++){
      float4 t4 = *(const float4*)(Whh + (size_t)g*64 + 4*q);
      w[4*q] = t4.x; w[4*q+1] = t4.y; w[4*q+2] = t4.z; w[4*q+3] = t4.w;
    }
    float c = 0.f;
    for (int t = 0; t < LSEQ; ++t){
      int tt = dir ? (LSEQ-1-t) : t;
      float gate = pre[((size_t)b*LSEQ + tt)*G4 + g];
      if (t > 0){
        #pragma unroll
        for (int q = 0; q < 16; q++){
          float4 h4 = *(const float4*)&u.sq.hcur[dir][4*q];
          gate += w[4*q]*h4.x + w[4*q+1]*h4.y + w[4*q+2]*h4.z + w[4*q+3]*h4.w;
        }
      }
      u.sq.gsh[dir][g] = gate;
      __syncthreads();
      if (g < 64){
        float iv = u.sq.gsh[dir][g], fv = u.sq.gsh[dir][64+g];
        float gv = u.sq.gsh[dir][128+g], ov = u.sq.gsh[dir][192+g];
        c = sigf(fv)*c + sigf(iv)*tanhf(gv);
        float h = sigf(ov)*tanhf(c);
        u.sq.hcur[dir][g] = h;
        u.sq.h_hist[dir][tt][g] = h;
      }
      __syncthreads();
    }
    // residual + LN, wave per row; keep result in soL for next-step pre-GEMM
    int wv = tid >> 6, lane = tid & 63;
    for (int l = wv; l < LSEQ; l += 8){
      float2 sv = ((const float2*)(seq_in + ((size_t)b*LSEQ + l)*128))[lane];
      float hv0, hv1;
      if (lane < 32){ hv0 = u.sq.h_hist[0][l][2*lane];    hv1 = u.sq.h_hist[0][l][2*lane+1]; }
      else          { hv0 = u.sq.h_hist[1][l][2*lane-64]; hv1 = u.sq.h_hist[1][l][2*lane-63]; }
      float vx = sv.x + hv0, vy = sv.y + hv1;
      float s = vx+vy, sq = vx*vx + vy*vy;
      #pragma unroll
      for (int o = 32; o; o >>= 1){ s += __shfl_xor(s, o); sq += __shfl_xor(sq, o); }
      float mean = s*(1.f/128.f);
      float inv = rsqrtf(sq*(1.f/128.f) - mean*mean + EPSF);
      float2 g2 = ((const float2*)ln_seq_g)[lane], b2 = ((const float2*)ln_seq_b)[lane];
      float2 o2;
      o2.x = (vx-mean)*inv*g2.x + b2.x;
      o2.y = (vy-mean)*inv*g2.y + b2.y;
      ((float2*)(so + ((size_t)b*LSEQ + l)*128))[lane] = o2;
      u.sq.soL[l*128 + 2*lane]     = o2.x;
      u.sq.soL[l*128 + 2*lane + 1] = o2.y;
    }
    if (!doNext) return;
    __syncthreads();
    // stage seq_in(i+1) = s0s_n? + soL + otherS -> shG + global seq_in
    {
      const float4* oS4 = (const float4*)(otherS + (size_t)b*LSEQ*128);
      const float4* s04 = s0s_n ? (const float4*)(s0s_n + (size_t)b*LSEQ*128) : nullptr;
      float4* gi4 = (float4*)(seq_in + (size_t)b*LSEQ*128);
      for (int idx = tid; idx < LSEQ*32; idx += 512){
        float4 v = *(const float4*)&u.sq.soL[idx*4];
        float4 o = oS4[idx];
        v.x += o.x; v.y += o.y; v.z += o.z; v.w += o.w;
        if (s04){ float4 s0 = s04[idx]; v.x += s0.x; v.y += s0.y; v.z += s0.z; v.w += s0.w; }
        *(float4*)&u.sq.shG[idx*4] = v;
        gi4[idx] = v;
      }
    }
    __syncthreads();
    // pre-GEMM(i+1): 512 threads, dir-split
    {
      int g2 = tid & 255;
      int dn = tid >> 8;
      const float* wp = (dn ? Wih_b : Wih_f) + (size_t)g2*128;
      float bsv = dn ? bsum_b[g2] : bsum_f[g2];
      float accv[LSEQ];
      #pragma unroll
      for (int l = 0; l < LSEQ; l++) accv[l] = bsv;
      for (int kc = 0; kc < 128; kc += 16){
        float4 wf[4];
        #pragma unroll
        for (int q = 0; q < 4; q++) wf[q] = *(const float4*)(wp + kc + 4*q);
        #pragma unroll
        for (int l = 0; l < LSEQ; l++){
          #pragma unroll
          for (int q = 0; q < 4; q++){
            float4 s4 = *(const float4*)&u.sq.shG[l*128 + kc + 4*q];
            accv[l] += s4.x*wf[q].x + s4.y*wf[q].y + s4.z*wf[q].z + s4.w*wf[q].w;
          }
        }
      }
      float* dst = dn ? pre_b : pre_f;
      for (int l = 0; l < LSEQ; l++)
        dst[((size_t)b*LSEQ + l)*G4 + g2] = accv[l];
    }
  }
}

// ---------------------------------------------------------------- epilogue
__global__ void k_final(float* __restrict__ out, const float* __restrict__ sy,
                        const float* __restrict__ ty, const int* __restrict__ starts,
                        const float* __restrict__ g, const float* __restrict__ b,
                        const float* __restrict__ rm, const float* __restrict__ rv, int Bb){
  int i = blockIdx.x*blockDim.x + threadIdx.x;
  if (i >= Bb*D) return;
  int bb = i >> 7, d = i & 127;
  float feat = sy[((size_t)bb*LSEQ + 10)*D + d] + ty[(size_t)starts[bb]*D + d];
  out[i] = (feat - rm[d])*rsqrtf(rv[d]+EPSF)*g[d] + b[d];
}

// ---------------------------------------------------------------- host
extern "C" void kernel_launch(void* const* d_in, const int* in_sizes, int n_in,
                              void* d_out, int out_size, void* d_ws, size_t ws_size,
                              hipStream_t stream)
{
  const float* x        = (const float*)d_in[0];
  const int*   ei       = (const int*)  d_in[1];
  const float* eattr    = (const float*)d_in[2];
  const int*   batch    = (const int*)  d_in[3];
  const float* hotslice = (const float*)d_in[4];
  const float* nsy      = (const float*)d_in[5];
  const float* nsz      = (const float*)d_in[6];
  const float* nty      = (const float*)d_in[7];
  const float* ntz      = (const float*)d_in[8];
  const float* W_esm    = (const float*)d_in[9];
  const float* b_esm    = (const float*)d_in[10];
  const float* W_node   = (const float*)d_in[11];
  const float* b_node   = (const float*)d_in[12];
  const float* W_seq    = (const float*)d_in[13];
  const float* b_seq    = (const float*)d_in[14];
  const float* ln_seq_g = (const float*)d_in[15];
  const float* ln_seq_b = (const float*)d_in[16];
  const float* ln_st_g  = (const float*)d_in[17];
  const float* ln_st_b  = (const float*)d_in[18];
  const float* W_in     = (const float*)d_in[19];
  const float* b_in     = (const float*)d_in[20];
  const float* W_out    = (const float*)d_in[21];
  const float* b_out    = (const float*)d_in[22];
  const float* Wih_f    = (const float*)d_in[23];
  const float* Whh_f    = (const float*)d_in[24];
  const float* bih_f    = (const float*)d_in[25];
  const float* bhh_f    = (const float*)d_in[26];
  const float* Wih_b    = (const float*)d_in[27];
  const float* Whh_b    = (const float*)d_in[28];
  const float* bih_b    = (const float*)d_in[29];
  const float* bhh_b    = (const float*)d_in[30];
  const float* bn_g     = (const float*)d_in[31];
  const float* bn_b     = (const float*)d_in[32];
  const float* bn_rm    = (const float*)d_in[33];
  const float* bn_rv    = (const float*)d_in[34];

  const int N  = in_sizes[0] / 2561;
  const int E  = in_sizes[1] / 2;
  const int E2 = E / 2;
  const int Bb = in_sizes[4] / (LSEQ*28);
  const int BL = Bb*LSEQ;

  // ---- workspace carve
  char* p = (char*)d_ws;
  auto alloc = [&](size_t bytes)->void*{
    void* r = (void*)p; p += (bytes + 255) & ~(size_t)255; return r;
  };
  float*    seq0      = (float*)alloc((size_t)BL*D*4);
  float*    sy        = (float*)alloc((size_t)BL*D*4);
  float*    sz        = (float*)alloc((size_t)BL*D*4);
  float*    seq_in    = (float*)alloc((size_t)BL*D*4);
  float*    pre_f     = (float*)alloc((size_t)BL*G4*4);
  float*    pre_b     = (float*)alloc((size_t)BL*G4*4);
  float*    struct0   = (float*)alloc((size_t)N*D*4);
  float*    ty        = (float*)alloc((size_t)N*D*4);
  float*    tz        = (float*)alloc((size_t)N*D*4);
  unsigned* G_in      = (unsigned*)alloc((size_t)N*D*4);
  unsigned* G_out     = (unsigned*)alloc((size_t)N*D*4);
  unsigned* PownPk    = (unsigned*)alloc((size_t)N*D*4);
  u16*      PB4h      = (u16*)alloc(65536*2);
  u16*      PB4l      = (u16*)alloc(65536*2);
  u16*      PBnh      = (u16*)alloc(16384*2);
  u16*      PBnl      = (u16*)alloc(16384*2);
  u16*      PBEh      = (u16*)alloc(327680*2);
  u16*      PBEl      = (u16*)alloc(327680*2);
  float*    WEin      = (float*)alloc(384*4);
  float*    WEout     = (float*)alloc(384*4);
  float*    bsum_f    = (float*)alloc(256*4);
  float*    bsum_b    = (float*)alloc(256*4);
  int*      starts    = (int*)alloc((size_t)Bb*4);
  int*      cnt_s     = (int*)alloc((size_t)N*4);
  int*      cnt_d     = (int*)alloc((size_t)N*4);
  int*      offs_s    = (int*)alloc((size_t)(N+1)*4);
  int*      offs_d    = (int*)alloc((size_t)(N+1)*4);
  int*      cur_s     = (int*)alloc((size_t)N*4);
  int*      cur_d     = (int*)alloc((size_t)N*4);
  int*      part      = (int*)alloc(2*((size_t)(N+1023)>>10)*4 + 256);
  int4*     adj_s     = (int4*)alloc((size_t)(E2+8)*16);
  int4*     adj_d     = (int4*)alloc((size_t)(E2+8)*16);
  (void)ws_size; (void)n_in; (void)out_size;

  // ---- init state from noise inputs
  hipMemcpyAsync(sy, nsy, (size_t)BL*D*4, hipMemcpyDeviceToDevice, stream);
  hipMemcpyAsync(sz, nsz, (size_t)BL*D*4, hipMemcpyDeviceToDevice, stream);
  hipMemcpyAsync(ty, nty, (size_t)N*D*4, hipMemcpyDeviceToDevice, stream);
  hipMemcpyAsync(tz, ntz, (size_t)N*D*4, hipMemcpyDeviceToDevice, stream);

  // ---- prologue
  k_misc<<<1, 256, 0, stream>>>(starts, batch, N, Bb, WEin, WEout, W_in, W_out,
                                bsum_f, bsum_b, bih_f, bhh_f, bih_b, bhh_b);
  k_packB<<<1600, 256, 0, stream>>>(PB4h, PB4l, PBnh, PBnl, PBEh, PBEl,
                                    W_in, W_out, W_node, W_esm);
  k_seq0<<<BL, 128, 0, stream>>>(seq0, hotslice, W_seq, b_seq);
  k_esm2<<<N/16, 256, 0, stream>>>(struct0, x, PBEh, PBEl, PBnh, PBnl,
                                   b_esm, W_node, b_node);
  k_zero2<<<(N+255)/256, 256, 0, stream>>>(cnt_s, cnt_d, N);
  k_count<<<(E2+255)/256, 256, 0, stream>>>(cnt_s, cnt_d, ei, E2);
  {
    int nch = (N + 1023) >> 10;
    k_scanp1<<<2*nch, 1024, 0, stream>>>(cnt_s, cnt_d, part, N, nch);
    k_scanp2<<<1, 64, 0, stream>>>(part, nch);
    k_scanp3<<<2*nch, 1024, 0, stream>>>(cnt_s, cnt_d, part, offs_s, offs_d, N, nch);
  }
  k_copy2<<<(N+255)/256, 256, 0, stream>>>(cur_s, offs_s, cur_d, offs_d, N);
  k_fill<<<(E2+255)/256, 256, 0, stream>>>(ei, eattr, E2, cur_s, adj_s, cur_d, adj_d);
  k_pad<<<1, 64, 0, stream>>>(adj_s, adj_d, E2);
  // initial seq_in(0)/pre(0)  (step 0 is inner: s0s = seq0)
  k_seqA<<<Bb, 256, 0, stream>>>(seq0, sy, sz, seq_in, pre_f, pre_b,
                                 Wih_f, Wih_b, bsum_f, bsum_b);

  const int NB = N/32;

  // ---- main loop: 8 outer x (4 inner + 1)
  for (int o = 0; o < 8; ++o){
    for (int it = 0; it < 5; ++it){
      int gi = o*5 + it;
      bool inner = (it < 4);
      const float* s0t = inner ? struct0 : nullptr;
      float* to_ = inner ? tz : ty;
      float* so_ = inner ? sz : sy;
      const float* otherS = inner ? sy : sz;
      int itn = (gi+1) % 5;
      const float* s0s_n = (itn < 4) ? seq0 : nullptr;
      int doNext = (gi < 39) ? 1 : 0;
      k_A<<<NB, 256, 0, stream>>>(s0t, ty, tz, PB4h, PB4l,
                                  G_in, G_out, PownPk, b_in, b_out, N);
      k_B<<<Bb + NB, 512, 0, stream>>>(G_in, G_out, PownPk, to_,
                                       offs_s, adj_s, offs_d, adj_d,
                                       WEin, WEout, ln_st_g, ln_st_b,
                                       pre_f, pre_b, Whh_f, Whh_b,
                                       seq_in, so_, otherS, s0s_n,
                                       Wih_f, Wih_b, bsum_f, bsum_b,
                                       ln_seq_g, ln_seq_b, doNext, N, Bb);
    }
  }

  k_final<<<(Bb*D+255)/256, 256, 0, stream>>>((float*)d_out, sy, ty, starts,
                                              bn_g, bn_b, bn_rm, bn_rv, Bb);
}

// Round 14
// 3553.632 us; speedup vs baseline: 1.2666x; 1.0056x over previous
//
#include <hip/hip_runtime.h>
#include <hip/hip_fp16.h>
#include <math.h>

#define D 128
#define G4 256
#define LSEQ 21
#define EPSF 1e-5f

typedef unsigned short u16;
typedef __attribute__((ext_vector_type(8))) short bf16x8;
typedef __attribute__((ext_vector_type(4))) float f32x4;
typedef __attribute__((ext_vector_type(2))) unsigned u32x2;
typedef __attribute__((ext_vector_type(4))) unsigned u32x4;

#define MFMA16(a,b,c) __builtin_amdgcn_mfma_f32_16x16x32_bf16(a,b,c,0,0,0)

// ---------------------------------------------------------------- helpers
__device__ __forceinline__ float sigf(float x){ return 1.0f/(1.0f+__expf(-x)); }
__device__ __forceinline__ u16 f2bf(float x){
  unsigned u = __float_as_uint(x);
  return (u16)((u + 0x7FFFu + ((u>>16)&1u)) >> 16);
}
__device__ __forceinline__ float bf2f(u16 h){ return __uint_as_float(((unsigned)h)<<16); }
__device__ __forceinline__ unsigned pack_h2(float a, float b){
  __half2 h = __floats2half2_rn(a, b);
  return *(unsigned*)&h;
}
__device__ __forceinline__ float2 unpack_h2(unsigned u){
  __half2 h = *(__half2*)&u;
  return __half22float2(h);
}
__device__ __forceinline__ u16 f2h(float v){ __half h = __float2half(v); return *(u16*)&h; }

__device__ __forceinline__ void edge_acc(u32x4 a, uint2 g, bool valid,
                                         float2 po2, float2 w0, float2 w1, float2 w2,
                                         float& ax, float& ay){
  float e0=__uint_as_float(a.y), e1=__uint_as_float(a.z), e2=__uint_as_float(a.w);
  float2 ps0 = unpack_h2(g.x);   // {P(ch0), S(ch0)}
  float2 ps1 = unpack_h2(g.y);   // {P(ch1), S(ch1)}
  float gx = po2.x + ps0.x + e0*w0.x + e1*w1.x + e2*w2.x;
  float gy = po2.y + ps1.x + e0*w0.y + e1*w1.y + e2*w2.y;
  float mm = valid ? 1.f : 0.f;
  ax = fmaf(ps0.y*mm, sigf(gx), ax);
  ay = fmaf(ps1.y*mm, sigf(gy), ay);
}

// ---------------------------------------------------------------- prologue kernels
__global__ void k_misc(int* __restrict__ starts, const int* __restrict__ batch, int N, int Bb,
                       float* __restrict__ WEin, float* __restrict__ WEout,
                       const float* __restrict__ W_in, const float* __restrict__ W_out,
                       float* __restrict__ bsum_f, float* __restrict__ bsum_b,
                       const float* __restrict__ bih_f, const float* __restrict__ bhh_f,
                       const float* __restrict__ bih_b, const float* __restrict__ bhh_b){
  int tid = threadIdx.x;
  if (tid < Bb){
    int lo = 0, hi = N;
    while (lo < hi){ int m = (lo+hi)>>1; if (batch[m] < tid) lo = m+1; else hi = m; }
    starts[tid] = lo;
  }
  for (int i = tid; i < 384; i += 256){
    int t = i >> 7, j = i & 127;
    WEin [i] = W_in [(size_t)j*259 + 256 + t];
    WEout[i] = W_out[(size_t)j*259 + 256 + t];
  }
  if (tid < 256){
    bsum_f[tid] = bih_f[tid] + bhh_f[tid];
    bsum_b[tid] = bih_b[tid] + bhh_b[tid];
  }
}

// pre-pack MFMA B-fragments (hi/lo bf16), layout [nt][ks][lane][8] contiguous
__global__ void k_packB(u16* __restrict__ PB4h, u16* __restrict__ PB4l,
                        u16* __restrict__ PBnh, u16* __restrict__ PBnl,
                        u16* __restrict__ PBEh, u16* __restrict__ PBEl,
                        const float* __restrict__ W_in, const float* __restrict__ W_out,
                        const float* __restrict__ W_node, const float* __restrict__ W_esm){
  int idx = blockIdx.x*256 + threadIdx.x;
  if (idx < 65536){
    int j = idx&7, l=(idx>>3)&63, q=idx>>9;
    int ks = q&3, nt = q>>2;
    int c = nt*16 + (l&15);
    int k = ks*32 + ((l>>4)<<3) + j;
    float v;
    if (c < 128)      v = W_in [(size_t)c*259 + k];
    else if (c < 256) v = W_in [(size_t)(c-128)*259 + 128 + k];
    else if (c < 384) v = W_out[(size_t)(c-256)*259 + k];
    else              v = W_out[(size_t)(c-384)*259 + 128 + k];
    u16 h = f2bf(v);
    PB4h[idx] = h; PB4l[idx] = f2bf(v - bf2f(h));
  } else if (idx < 65536 + 16384){
    int p = idx - 65536;
    int j = p&7, l=(p>>3)&63, q=p>>9;
    int ks = q&3, nt = q>>2;
    int c = nt*16 + (l&15);
    int k = ks*32 + ((l>>4)<<3) + j;
    float v = W_node[(size_t)c*129 + k];
    u16 h = f2bf(v);
    PBnh[p] = h; PBnl[p] = f2bf(v - bf2f(h));
  } else if (idx < 65536 + 16384 + 327680){
    int p = idx - 81920;
    int j = p&7, l=(p>>3)&63, q=p>>9;
    int ks = q%80, nt = q/80;
    int c = nt*16 + (l&15);
    int k = ks*32 + ((l>>4)<<3) + j;
    float v = W_esm[(size_t)c*2560 + k];
    u16 h = f2bf(v);
    PBEh[p] = h; PBEl[p] = f2bf(v - bf2f(h));
  }
}

__global__ void k_seq0(float* __restrict__ seq0, const float* __restrict__ hot,
                       const float* __restrict__ W_seq, const float* __restrict__ b_seq){
  int row = blockIdx.x, j = threadIdx.x;           // 128 threads
  const float* h = hot + (size_t)row*28;
  const float* w = W_seq + (size_t)j*28;
  float acc = b_seq[j];
  #pragma unroll
  for (int k = 0; k < 28; k++) acc += h[k]*w[k];
  seq0[(size_t)row*D + j] = acc;
}

// fused: esm = x[:,1:] @ W_esm.T + b_esm ; struct0 = [esm, x[:,:1]] @ W_node.T + b_node
// 32 rows/block x 512 threads (8 waves, 1 coltile/wave): halves B-fragment L2 traffic
__global__ __launch_bounds__(512) void k_esm2(float* __restrict__ struct0, const float* __restrict__ x,
    const u16* __restrict__ PBEh, const u16* __restrict__ PBEl,
    const u16* __restrict__ PBnh, const u16* __restrict__ PBnl,
    const float* __restrict__ b_esm, const float* __restrict__ W_node,
    const float* __restrict__ b_node){
  __shared__ union {
    struct { u16 xh[32*72], xl[32*72]; } p1;
    struct { u16 Ah[32*136], Al[32*136]; } p2;
  } uu;
  __shared__ float esmF[32*132];
  int tid = threadIdx.x;
  int r0 = blockIdx.x*32;
  int w = tid>>6, l = tid&63;           // 8 waves, wave w owns coltile w
  f32x4 acc[2];
  acc[0] = (f32x4){0.f,0.f,0.f,0.f};
  acc[1] = (f32x4){0.f,0.f,0.f,0.f};

  float xv[4];
  int rr = tid >> 5, k2i = tid & 31;    // rows rr, rr+16 ; col pair k2i
  #pragma unroll
  for (int q = 0; q < 2; q++){
    const float* src = x + (size_t)(r0+rr+16*q)*2561 + 1 + k2i*2;
    xv[2*q]   = src[0];
    xv[2*q+1] = src[1];
  }
  for (int kc = 0; kc < 2560; kc += 64){
    __syncthreads();
    unsigned* xh32 = (unsigned*)uu.p1.xh;
    unsigned* xl32 = (unsigned*)uu.p1.xl;
    #pragma unroll
    for (int q = 0; q < 2; q++){
      float v0 = xv[2*q], v1 = xv[2*q+1];
      u16 h0 = f2bf(v0), h1 = f2bf(v1);
      u16 l0 = f2bf(v0 - bf2f(h0)), l1 = f2bf(v1 - bf2f(h1));
      int r = rr + 16*q;
      xh32[r*36 + k2i] = (unsigned)h0 | ((unsigned)h1 << 16);
      xl32[r*36 + k2i] = (unsigned)l0 | ((unsigned)l1 << 16);
    }
    __syncthreads();
    if (kc + 64 < 2560){
      #pragma unroll
      for (int q = 0; q < 2; q++){
        const float* src = x + (size_t)(r0+rr+16*q)*2561 + 1 + kc + 64 + k2i*2;
        xv[2*q]   = src[0];
        xv[2*q+1] = src[1];
      }
    }
    #pragma unroll
    for (int ks = 0; ks < 2; ks++){
      bf16x8 ah[2], al[2];
      #pragma unroll
      for (int rt = 0; rt < 2; rt++){
        int row = rt*16 + (l&15);
        int k = ks*32 + ((l>>4)<<3);
        ah[rt] = *(const bf16x8*)&uu.p1.xh[row*72 + k];
        al[rt] = *(const bf16x8*)&uu.p1.xl[row*72 + k];
      }
      int ksg = (kc>>5) + ks;
      bf16x8 bh = *(const bf16x8*)&PBEh[((size_t)(w*80 + ksg)*64 + l)*8];
      bf16x8 bl = *(const bf16x8*)&PBEl[((size_t)(w*80 + ksg)*64 + l)*8];
      #pragma unroll
      for (int rt = 0; rt < 2; rt++){
        acc[rt] = MFMA16(ah[rt], bh, acc[rt]);
        acc[rt] = MFMA16(al[rt], bh, acc[rt]);
        acc[rt] = MFMA16(ah[rt], bl, acc[rt]);
      }
    }
  }
  __syncthreads();
  int cq = l & 15, rqb = (l>>4)*4;
  {
    int coln = w*16 + cq;
    float be = b_esm[coln];
    #pragma unroll
    for (int rt = 0; rt < 2; rt++)
      #pragma unroll
      for (int r = 0; r < 4; r++)
        esmF[(rt*16+rqb+r)*132 + coln] = acc[rt][r] + be;
  }
  __syncthreads();
  {
    unsigned* Ah32 = (unsigned*)uu.p2.Ah;
    unsigned* Al32 = (unsigned*)uu.p2.Al;
    int rr2 = tid >> 6, k2 = tid & 63;   // 8 rows/iter, 64 col-pairs
    #pragma unroll
    for (int q = 0; q < 4; q++){
      int r = rr2 + 8*q;
      float v0 = esmF[r*132 + k2*2];
      float v1 = esmF[r*132 + k2*2 + 1];
      u16 h0 = f2bf(v0), h1 = f2bf(v1);
      u16 l0 = f2bf(v0 - bf2f(h0)), l1 = f2bf(v1 - bf2f(h1));
      Ah32[r*68 + k2] = (unsigned)h0 | ((unsigned)h1 << 16);
      Al32[r*68 + k2] = (unsigned)l0 | ((unsigned)l1 << 16);
    }
  }
  __syncthreads();
  f32x4 acc2[2];
  acc2[0] = (f32x4){0.f,0.f,0.f,0.f};
  acc2[1] = (f32x4){0.f,0.f,0.f,0.f};
  #pragma unroll
  for (int ks = 0; ks < 4; ks++){
    bf16x8 ah[2], al[2];
    #pragma unroll
    for (int rt = 0; rt < 2; rt++){
      int row = rt*16 + (l&15);
      int k = ks*32 + ((l>>4)<<3);
      ah[rt] = *(const bf16x8*)&uu.p2.Ah[row*136 + k];
      al[rt] = *(const bf16x8*)&uu.p2.Al[row*136 + k];
    }
    bf16x8 bh = *(const bf16x8*)&PBnh[((size_t)(w*4 + ks)*64 + l)*8];
    bf16x8 bl = *(const bf16x8*)&PBnl[((size_t)(w*4 + ks)*64 + l)*8];
    #pragma unroll
    for (int rt = 0; rt < 2; rt++){
      acc2[rt] = MFMA16(ah[rt], bh, acc2[rt]);
      acc2[rt] = MFMA16(al[rt], bh, acc2[rt]);
      acc2[rt] = MFMA16(ah[rt], bl, acc2[rt]);
    }
  }
  {
    int col = w*16 + cq;
    float wl = W_node[(size_t)col*129 + 128];
    float bn = b_node[col];
    #pragma unroll
    for (int rt = 0; rt < 2; rt++)
      #pragma unroll
      for (int r = 0; r < 4; r++){
        int row = r0 + rt*16 + rqb + r;
        float x0 = x[(size_t)row*2561];
        struct0[(size_t)row*D + col] = acc2[rt][r] + x0*wl + bn;
      }
  }
}

// ---------------------------------------------------------------- CSR build
__global__ void k_zero2(int* a, int* b, int n){
  int i = blockIdx.x*blockDim.x + threadIdx.x;
  if (i < n){ a[i] = 0; b[i] = 0; }
}
__global__ void k_count(int* cnt_s, int* cnt_d, const int* __restrict__ ei, int E2){
  int e = blockIdx.x*blockDim.x + threadIdx.x;
  if (e < E2){
    atomicAdd(&cnt_s[ei[2*e]], 1);
    atomicAdd(&cnt_d[ei[2*E2 + 2*e]], 1);
  }
}
// parallel 3-phase scan over cnt_s and cnt_d together
__global__ __launch_bounds__(1024) void k_scanp1(const int* __restrict__ cnt_s,
                                                 const int* __restrict__ cnt_d,
                                                 int* __restrict__ part, int n, int nch){
  int arr = blockIdx.x / nch, chunk = blockIdx.x % nch;
  const int* cnt = arr ? cnt_d : cnt_s;
  int i = chunk*1024 + threadIdx.x;
  int v = (i < n) ? cnt[i] : 0;
  __shared__ int ws[16];
  #pragma unroll
  for (int o = 32; o; o >>= 1) v += __shfl_down(v, o);
  if ((threadIdx.x & 63) == 0) ws[threadIdx.x >> 6] = v;
  __syncthreads();
  if (threadIdx.x == 0){
    int t = 0;
    #pragma unroll
    for (int q = 0; q < 16; q++) t += ws[q];
    part[blockIdx.x] = t;
  }
}
__global__ void k_scanp2(int* part, int nch){
  int tid = threadIdx.x;
  if (tid < 2){
    int base = 0;
    for (int i = 0; i < nch; i++){
      int v = part[tid*nch + i];
      part[tid*nch + i] = base;
      base += v;
    }
  }
}
__global__ __launch_bounds__(1024) void k_scanp3(const int* __restrict__ cnt_s,
                                                 const int* __restrict__ cnt_d,
                                                 const int* __restrict__ part,
                                                 int* __restrict__ offs_s, int* __restrict__ offs_d,
                                                 int n, int nch){
  int arr = blockIdx.x / nch, chunk = blockIdx.x % nch;
  const int* cnt = arr ? cnt_d : cnt_s;
  int* offs = arr ? offs_d : offs_s;
  __shared__ int sh[1024];
  int tid = threadIdx.x;
  int i = chunk*1024 + tid;
  int v = (i < n) ? cnt[i] : 0;
  sh[tid] = v;
  __syncthreads();
  for (int off = 1; off < 1024; off <<= 1){
    int t = (tid >= off) ? sh[tid-off] : 0;
    __syncthreads();
    sh[tid] += t;
    __syncthreads();
  }
  int base = part[blockIdx.x];
  if (i < n) offs[i] = base + sh[tid] - v;
  if (i == n-1) offs[n] = base + sh[tid];
}
__global__ void k_copy2(int* cur_s, const int* offs_s, int* cur_d, const int* offs_d, int n){
  int i = blockIdx.x*blockDim.x + threadIdx.x;
  if (i < n){ cur_s[i] = offs_s[i]; cur_d[i] = offs_d[i]; }
}
__global__ void k_fill(const int* __restrict__ ei, const float* __restrict__ eattr, int E2,
                       int* cur_s, int4* __restrict__ adj_s,
                       int* cur_d, int4* __restrict__ adj_d){
  int e = blockIdx.x*blockDim.x + threadIdx.x;
  if (e >= E2) return;
  int s = ei[2*e];
  int d = ei[2*E2 + 2*e];
  const float* ein  = eattr + (size_t)(2*e+1)*3;
  const float* eout = eattr + (size_t)(2*e)*3;
  int ps = atomicAdd(&cur_s[s], 1);
  adj_s[ps] = make_int4(d, __float_as_int(ein[0]),  __float_as_int(ein[1]),  __float_as_int(ein[2]));
  int pd = atomicAdd(&cur_d[d], 1);
  adj_d[pd] = make_int4(s, __float_as_int(eout[0]), __float_as_int(eout[1]), __float_as_int(eout[2]));
}
__global__ void k_pad(int4* __restrict__ adj_s, int4* __restrict__ adj_d, int E2){
  int t = threadIdx.x;
  if (t < 8){
    adj_s[E2+t] = make_int4(0,0,0,0);
    adj_d[E2+t] = make_int4(0,0,0,0);
  }
}

// ---------------------------------------------------------------- initial seq pre-GEMM
__global__ __launch_bounds__(256) void k_seqA(
  const float* __restrict__ s0s, const float* __restrict__ sy, const float* __restrict__ sz,
  float* __restrict__ seq_in, float* __restrict__ pre_f, float* __restrict__ pre_b,
  const float* __restrict__ Wih_f, const float* __restrict__ Wih_b,
  const float* __restrict__ bsum_f, const float* __restrict__ bsum_b)
{
  __shared__ float sh[LSEQ*128];
  int tid = threadIdx.x;
  int b = blockIdx.x;
  for (int idx = tid; idx < LSEQ*128; idx += 256){
    size_t off = (size_t)b*LSEQ*128 + idx;
    float v = sy[off] + sz[off];
    if (s0s) v += s0s[off];
    sh[idx] = v;
    seq_in[off] = v;
  }
  __syncthreads();
  int g = tid;  // 0..255
  float accf[LSEQ], accb[LSEQ];
  float bf = bsum_f[g], bb = bsum_b[g];
  #pragma unroll
  for (int l = 0; l < LSEQ; l++){ accf[l] = bf; accb[l] = bb; }
  const float* wfp = Wih_f + (size_t)g*128;
  const float* wbp = Wih_b + (size_t)g*128;
  for (int kc = 0; kc < 128; kc += 16){
    float4 wf[4], wb[4];
    #pragma unroll
    for (int q = 0; q < 4; q++){
      wf[q] = *(const float4*)(wfp + kc + 4*q);
      wb[q] = *(const float4*)(wbp + kc + 4*q);
    }
    #pragma unroll
    for (int l = 0; l < LSEQ; l++){
      #pragma unroll
      for (int q = 0; q < 4; q++){
        float4 s4 = *(const float4*)&sh[l*128 + kc + 4*q];
        accf[l] += s4.x*wf[q].x + s4.y*wf[q].y + s4.z*wf[q].z + s4.w*wf[q].w;
        accb[l] += s4.x*wb[q].x + s4.y*wb[q].y + s4.z*wb[q].z + s4.w*wb[q].w;
      }
    }
  }
  for (int l = 0; l < LSEQ; l++){
    pre_f[((size_t)b*LSEQ + l)*G4 + g] = accf[l];
    pre_b[((size_t)b*LSEQ + l)*G4 + g] = accb[l];
  }
}

// ---------------------------------------------------------------- per-step kernel A (struct only)
__global__ __launch_bounds__(256) void k_A(
  const float* __restrict__ s0t, const float* __restrict__ ty, const float* __restrict__ tz,
  const u16* __restrict__ PB4h, const u16* __restrict__ PB4l,
  unsigned* __restrict__ G_in, unsigned* __restrict__ G_out,
  unsigned* __restrict__ PownPk,
  const float* __restrict__ b_in, const float* __restrict__ b_out, int N)
{
  __shared__ struct { u16 Ah[32*136], Al[32*136]; float Sf[32*132]; } m;
  int tid = threadIdx.x;
  int r0 = blockIdx.x*32;
  const float4* ty4 = (const float4*)(ty + (size_t)r0*D);
  const float4* tz4 = (const float4*)(tz + (size_t)r0*D);
  const float4* s04 = s0t ? (const float4*)(s0t + (size_t)r0*D) : nullptr;
  #pragma unroll
  for (int q = 0; q < 4; q++){
    int i = tid + 256*q;          // float4 index, 0..1023
    int r = i >> 5, k4 = i & 31;
    float4 v = ty4[i];
    float4 z = tz4[i];
    v.x += z.x; v.y += z.y; v.z += z.z; v.w += z.w;
    if (s04){ float4 s = s04[i]; v.x += s.x; v.y += s.y; v.z += s.z; v.w += s.w; }
    u16 h0 = f2bf(v.x), h1 = f2bf(v.y), h2 = f2bf(v.z), h3 = f2bf(v.w);
    *(ushort4*)&m.Ah[r*136 + k4*4] = make_ushort4(h0,h1,h2,h3);
    *(ushort4*)&m.Al[r*136 + k4*4] = make_ushort4(
        f2bf(v.x - bf2f(h0)), f2bf(v.y - bf2f(h1)),
        f2bf(v.z - bf2f(h2)), f2bf(v.w - bf2f(h3)));
    *(float4*)&m.Sf[r*132 + k4*4] = v;
  }
  __syncthreads();
  int w = tid >> 6, l = tid & 63;
  f32x4 acc[2][8];
  #pragma unroll
  for (int a=0;a<2;a++)
    #pragma unroll
    for (int b=0;b<8;b++) acc[a][b] = (f32x4){0.f,0.f,0.f,0.f};
  #pragma unroll
  for (int ks = 0; ks < 4; ks++){
    bf16x8 ah[2], al[2];
    #pragma unroll
    for (int rt = 0; rt < 2; rt++){
      int row = rt*16 + (l&15);
      int k = ks*32 + ((l>>4)<<3);
      ah[rt] = *(const bf16x8*)&m.Ah[row*136 + k];
      al[rt] = *(const bf16x8*)&m.Al[row*136 + k];
    }
    #pragma unroll
    for (int ct = 0; ct < 8; ct++){
      int nt = w*8 + ct;
      bf16x8 bh = *(const bf16x8*)&PB4h[((size_t)(nt*4 + ks)*64 + l)*8];
      bf16x8 bl = *(const bf16x8*)&PB4l[((size_t)(nt*4 + ks)*64 + l)*8];
      #pragma unroll
      for (int rt = 0; rt < 2; rt++){
        acc[rt][ct] = MFMA16(ah[rt], bh, acc[rt][ct]);
        acc[rt][ct] = MFMA16(al[rt], bh, acc[rt][ct]);
        acc[rt][ct] = MFMA16(ah[rt], bl, acc[rt][ct]);
      }
    }
  }
  // ---- coalesced table epilogue via LDS staging (reuses Ah/Al region) ----
  __syncthreads();                      // MFMA done reading Ah/Al
  unsigned* stg = (unsigned*)m.Ah;      // 32*128 u32 = 16KB (fits in Ah+Al)
  u16* stg16 = (u16*)m.Ah;
  int cq = l & 15, rqb = (l>>4)*4;
  if (w == 1){
    #pragma unroll
    for (int ct = 0; ct < 8; ct++){
      int coln = ct*16 + cq;
      #pragma unroll
      for (int rt = 0; rt < 2; rt++){
        #pragma unroll
        for (int r = 0; r < 4; r++){
          int lr = rt*16 + rqb + r;
          stg[lr*128 + coln] = pack_h2(acc[rt][ct][r], m.Sf[lr*132 + coln]);
        }
      }
    }
  }
  __syncthreads();
  {
    uint4* dst = (uint4*)(G_in + (size_t)r0*D);
    const uint4* src = (const uint4*)stg;
    #pragma unroll
    for (int q = 0; q < 4; q++) dst[tid + 256*q] = src[tid + 256*q];
  }
  __syncthreads();
  if (w == 2){
    #pragma unroll
    for (int ct = 0; ct < 8; ct++){
      int coln = ct*16 + cq;
      #pragma unroll
      for (int rt = 0; rt < 2; rt++){
        #pragma unroll
        for (int r = 0; r < 4; r++){
          int lr = rt*16 + rqb + r;
          stg[lr*128 + coln] = pack_h2(acc[rt][ct][r], m.Sf[lr*132 + coln]);
        }
      }
    }
  }
  __syncthreads();
  {
    uint4* dst = (uint4*)(G_out + (size_t)r0*D);
    const uint4* src = (const uint4*)stg;
    #pragma unroll
    for (int q = 0; q < 4; q++) dst[tid + 256*q] = src[tid + 256*q];
  }
  __syncthreads();
  if (w == 0 || w == 3){
    const float* bb = (w == 0) ? b_in : b_out;
    int half = (w == 0) ? 0 : 1;
    #pragma unroll
    for (int ct = 0; ct < 8; ct++){
      int coln = ct*16 + cq;
      float bc = bb[coln];
      #pragma unroll
      for (int rt = 0; rt < 2; rt++){
        #pragma unroll
        for (int r = 0; r < 4; r++){
          int lr = rt*16 + rqb + r;
          stg16[(lr*128 + coln)*2 + half] = f2h(acc[rt][ct][r] + bc);
        }
      }
    }
  }
  __syncthreads();
  {
    uint4* dst = (uint4*)(PownPk + (size_t)r0*D);
    const uint4* src = (const uint4*)stg;
    #pragma unroll
    for (int q = 0; q < 4; q++) dst[tid + 256*q] = src[tid + 256*q];
  }
}

// ---------------------------------------------------------------- per-step kernel B
// blocks [0,Bb): LSTM(i) + seq LN -> so ; then (doNext) seq_in(i+1) staging + pre-GEMM(i+1)
// blocks [Bb, Bb+N/32): edge gather — wave owns 4 consecutive nodes (both dirs + LN),
//   with cross-node prefetch of Pown/own-G rows.
__global__ __launch_bounds__(512) void k_B(
  const unsigned* __restrict__ G_in, const unsigned* __restrict__ G_out,
  const unsigned* __restrict__ PownPk,
  float* __restrict__ to,
  const int* __restrict__ offs_s, const int4* __restrict__ adj_s,
  const int* __restrict__ offs_d, const int4* __restrict__ adj_d,
  const float* __restrict__ WEin, const float* __restrict__ WEout,
  const float* __restrict__ ln_st_g, const float* __restrict__ ln_st_b,
  float* pre_f, float* pre_b,
  const float* __restrict__ Whh_f, const float* __restrict__ Whh_b,
  float* seq_in, float* __restrict__ so,
  const float* __restrict__ otherS, const float* __restrict__ s0s_n,
  const float* __restrict__ Wih_f, const float* __restrict__ Wih_b,
  const float* __restrict__ bsum_f, const float* __restrict__ bsum_b,
  const float* __restrict__ ln_seq_g, const float* __restrict__ ln_seq_b,
  int doNext, int N, int Bb)
{
  __shared__ union {
    struct {
      float h_hist[2][LSEQ][64];
      float hcur[2][64];
      float gsh[2][G4];
      float soL[LSEQ*128];
      float shG[LSEQ*128];
    } sq;
  } u;
  if ((int)blockIdx.x >= Bb){
    int wv = threadIdx.x >> 6, lane = threadIdx.x & 63;
    int n0 = ((blockIdx.x - Bb)*8 + wv)*4;           // 4 consecutive nodes per wave
    const float2* WEi2 = (const float2*)WEin;
    const float2* WEo2 = (const float2*)WEout;
    float2 wi0 = WEi2[lane], wi1 = WEi2[64+lane], wi2 = WEi2[128+lane];
    float2 wo0 = WEo2[lane], wo1 = WEo2[64+lane], wo2 = WEo2[128+lane];
    float2 g2v = ((const float2*)ln_st_g)[lane], be2 = ((const float2*)ln_st_b)[lane];
    const uint2* Gi = (const uint2*)G_in;
    const uint2* Go = (const uint2*)G_out;
    // prefetch first node's own rows
    u32x2 pwN = *((const u32x2*)PownPk + (size_t)n0*64 + lane);
    uint2 gownN = Gi[(size_t)n0*64 + lane];
    #pragma unroll 1
    for (int n = n0; n < n0+4; ++n){
      u32x2 pw = pwN;
      uint2 gown = gownN;
      if (n+1 < n0+4){
        pwN = *((const u32x2*)PownPk + (size_t)(n+1)*64 + lane);
        gownN = Gi[(size_t)(n+1)*64 + lane];
      }
      float2 pp0 = unpack_h2(pw.x), pp1 = unpack_h2(pw.y);
      float2 poI = make_float2(pp0.x, pp1.x);
      float2 poO = make_float2(pp0.y, pp1.y);
      float ax = 0.f, ay = 0.f;
      int j0 = __builtin_amdgcn_readfirstlane(offs_s[n]);
      int j1 = __builtin_amdgcn_readfirstlane(offs_s[n+1]);
      for (int jb = j0; jb < j1; jb += 4){
        int rem = j1 - jb;
        const u32x4* ap = (const u32x4*)adj_s + jb;
        u32x4 a0 = ap[0], a1 = ap[1], a2 = ap[2], a3 = ap[3];
        uint2 g0 = Gi[(size_t)a0.x*64 + lane];
        uint2 g1 = Gi[(size_t)a1.x*64 + lane];
        uint2 g2 = Gi[(size_t)a2.x*64 + lane];
        uint2 g3 = Gi[(size_t)a3.x*64 + lane];
        edge_acc(a0, g0, true,  poI, wi0, wi1, wi2, ax, ay);
        edge_acc(a1, g1, rem>1, poI, wi0, wi1, wi2, ax, ay);
        edge_acc(a2, g2, rem>2, poI, wi0, wi1, wi2, ax, ay);
        edge_acc(a3, g3, rem>3, poI, wi0, wi1, wi2, ax, ay);
      }
      j0 = __builtin_amdgcn_readfirstlane(offs_d[n]);
      j1 = __builtin_amdgcn_readfirstlane(offs_d[n+1]);
      for (int jb = j0; jb < j1; jb += 4){
        int rem = j1 - jb;
        const u32x4* ap = (const u32x4*)adj_d + jb;
        u32x4 a0 = ap[0], a1 = ap[1], a2 = ap[2], a3 = ap[3];
        uint2 g0 = Go[(size_t)a0.x*64 + lane];
        uint2 g1 = Go[(size_t)a1.x*64 + lane];
        uint2 g2 = Go[(size_t)a2.x*64 + lane];
        uint2 g3 = Go[(size_t)a3.x*64 + lane];
        edge_acc(a0, g0, true,  poO, wo0, wo1, wo2, ax, ay);
        edge_acc(a1, g1, rem>1, poO, wo0, wo1, wo2, ax, ay);
        edge_acc(a2, g2, rem>2, poO, wo0, wo1, wo2, ax, ay);
        edge_acc(a3, g3, rem>3, poO, wo0, wo1, wo2, ax, ay);
      }
      float vx = unpack_h2(gown.x).y + ax;
      float vy = unpack_h2(gown.y).y + ay;
      float s = vx+vy, sq = vx*vx + vy*vy;
      #pragma unroll
      for (int o = 32; o; o >>= 1){ s += __shfl_xor(s, o); sq += __shfl_xor(sq, o); }
      float mean = s*(1.f/128.f);
      float inv = rsqrtf(sq*(1.f/128.f) - mean*mean + EPSF);
      float2 o2;
      o2.x = (vx-mean)*inv*g2v.x + be2.x;
      o2.y = (vy-mean)*inv*g2v.y + be2.y;
      ((float2*)to)[(size_t)n*64 + lane] = o2;
    }
  } else {
    int b = blockIdx.x;
    int tid = threadIdx.x;
    int dir = tid >> 8, g = tid & 255;
    const float* Whh = dir ? Whh_b : Whh_f;
    const float* pre = dir ? pre_b : pre_f;
    float w[64];
    #pragma unroll
    for (int q = 0; q < 16; q++){
      float4 t4 = *(const float4*)(Whh + (size_t)g*64 + 4*q);
      w[4*q] = t4.x; w[4*q+1] = t4.y; w[4*q+2] = t4.z; w[4*q+3] = t4.w;
    }
    float c = 0.f;
    for (int t = 0; t < LSEQ; ++t){
      int tt = dir ? (LSEQ-1-t) : t;
      float gate = pre[((size_t)b*LSEQ + tt)*G4 + g];
      if (t > 0){
        #pragma unroll
        for (int q = 0; q < 16; q++){
          float4 h4 = *(const float4*)&u.sq.hcur[dir][4*q];
          gate += w[4*q]*h4.x + w[4*q+1]*h4.y + w[4*q+2]*h4.z + w[4*q+3]*h4.w;
        }
      }
      u.sq.gsh[dir][g] = gate;
      __syncthreads();
      if (g < 64){
        float iv = u.sq.gsh[dir][g], fv = u.sq.gsh[dir][64+g];
        float gv = u.sq.gsh[dir][128+g], ov = u.sq.gsh[dir][192+g];
        c = sigf(fv)*c + sigf(iv)*tanhf(gv);
        float h = sigf(ov)*tanhf(c);
        u.sq.hcur[dir][g] = h;
        u.sq.h_hist[dir][tt][g] = h;
      }
      __syncthreads();
    }
    // residual + LN, wave per row; keep result in soL for next-step pre-GEMM
    int wv = tid >> 6, lane = tid & 63;
    for (int l = wv; l < LSEQ; l += 8){
      float2 sv = ((const float2*)(seq_in + ((size_t)b*LSEQ + l)*128))[lane];
      float hv0, hv1;
      if (lane < 32){ hv0 = u.sq.h_hist[0][l][2*lane];    hv1 = u.sq.h_hist[0][l][2*lane+1]; }
      else          { hv0 = u.sq.h_hist[1][l][2*lane-64]; hv1 = u.sq.h_hist[1][l][2*lane-63]; }
      float vx = sv.x + hv0, vy = sv.y + hv1;
      float s = vx+vy, sq = vx*vx + vy*vy;
      #pragma unroll
      for (int o = 32; o; o >>= 1){ s += __shfl_xor(s, o); sq += __shfl_xor(sq, o); }
      float mean = s*(1.f/128.f);
      float inv = rsqrtf(sq*(1.f/128.f) - mean*mean + EPSF);
      float2 g2 = ((const float2*)ln_seq_g)[lane], b2 = ((const float2*)ln_seq_b)[lane];
      float2 o2;
      o2.x = (vx-mean)*inv*g2.x + b2.x;
      o2.y = (vy-mean)*inv*g2.y + b2.y;
      ((float2*)(so + ((size_t)b*LSEQ + l)*128))[lane] = o2;
      u.sq.soL[l*128 + 2*lane]     = o2.x;
      u.sq.soL[l*128 + 2*lane + 1] = o2.y;
    }
    if (!doNext) return;
    __syncthreads();
    // stage seq_in(i+1) = s0s_n? + soL + otherS -> shG + global seq_in
    {
      const float4* oS4 = (const float4*)(otherS + (size_t)b*LSEQ*128);
      const float4* s04 = s0s_n ? (const float4*)(s0s_n + (size_t)b*LSEQ*128) : nullptr;
      float4* gi4 = (float4*)(seq_in + (size_t)b*LSEQ*128);
      for (int idx = tid; idx < LSEQ*32; idx += 512){
        float4 v = *(const float4*)&u.sq.soL[idx*4];
        float4 o = oS4[idx];
        v.x += o.x; v.y += o.y; v.z += o.z; v.w += o.w;
        if (s04){ float4 s0 = s04[idx]; v.x += s0.x; v.y += s0.y; v.z += s0.z; v.w += s0.w; }
        *(float4*)&u.sq.shG[idx*4] = v;
        gi4[idx] = v;
      }
    }
    __syncthreads();
    // pre-GEMM(i+1): 512 threads, dir-split
    {
      int g2 = tid & 255;
      int dn = tid >> 8;
      const float* wp = (dn ? Wih_b : Wih_f) + (size_t)g2*128;
      float bsv = dn ? bsum_b[g2] : bsum_f[g2];
      float accv[LSEQ];
      #pragma unroll
      for (int l = 0; l < LSEQ; l++) accv[l] = bsv;
      for (int kc = 0; kc < 128; kc += 16){
        float4 wf[4];
        #pragma unroll
        for (int q = 0; q < 4; q++) wf[q] = *(const float4*)(wp + kc + 4*q);
        #pragma unroll
        for (int l = 0; l < LSEQ; l++){
          #pragma unroll
          for (int q = 0; q < 4; q++){
            float4 s4 = *(const float4*)&u.sq.shG[l*128 + kc + 4*q];
            accv[l] += s4.x*wf[q].x + s4.y*wf[q].y + s4.z*wf[q].z + s4.w*wf[q].w;
          }
        }
      }
      float* dst = dn ? pre_b : pre_f;
      for (int l = 0; l < LSEQ; l++)
        dst[((size_t)b*LSEQ + l)*G4 + g2] = accv[l];
    }
  }
}

// ---------------------------------------------------------------- epilogue
__global__ void k_final(float* __restrict__ out, const float* __restrict__ sy,
                        const float* __restrict__ ty, const int* __restrict__ starts,
                        const float* __restrict__ g, const float* __restrict__ b,
                        const float* __restrict__ rm, const float* __restrict__ rv, int Bb){
  int i = blockIdx.x*blockDim.x + threadIdx.x;
  if (i >= Bb*D) return;
  int bb = i >> 7, d = i & 127;
  float feat = sy[((size_t)bb*LSEQ + 10)*D + d] + ty[(size_t)starts[bb]*D + d];
  out[i] = (feat - rm[d])*rsqrtf(rv[d]+EPSF)*g[d] + b[d];
}

// ---------------------------------------------------------------- host
extern "C" void kernel_launch(void* const* d_in, const int* in_sizes, int n_in,
                              void* d_out, int out_size, void* d_ws, size_t ws_size,
                              hipStream_t stream)
{
  const float* x        = (const float*)d_in[0];
  const int*   ei       = (const int*)  d_in[1];
  const float* eattr    = (const float*)d_in[2];
  const int*   batch    = (const int*)  d_in[3];
  const float* hotslice = (const float*)d_in[4];
  const float* nsy      = (const float*)d_in[5];
  const float* nsz      = (const float*)d_in[6];
  const float* nty      = (const float*)d_in[7];
  const float* ntz      = (const float*)d_in[8];
  const float* W_esm    = (const float*)d_in[9];
  const float* b_esm    = (const float*)d_in[10];
  const float* W_node   = (const float*)d_in[11];
  const float* b_node   = (const float*)d_in[12];
  const float* W_seq    = (const float*)d_in[13];
  const float* b_seq    = (const float*)d_in[14];
  const float* ln_seq_g = (const float*)d_in[15];
  const float* ln_seq_b = (const float*)d_in[16];
  const float* ln_st_g  = (const float*)d_in[17];
  const float* ln_st_b  = (const float*)d_in[18];
  const float* W_in     = (const float*)d_in[19];
  const float* b_in     = (const float*)d_in[20];
  const float* W_out    = (const float*)d_in[21];
  const float* b_out    = (const float*)d_in[22];
  const float* Wih_f    = (const float*)d_in[23];
  const float* Whh_f    = (const float*)d_in[24];
  const float* bih_f    = (const float*)d_in[25];
  const float* bhh_f    = (const float*)d_in[26];
  const float* Wih_b    = (const float*)d_in[27];
  const float* Whh_b    = (const float*)d_in[28];
  const float* bih_b    = (const float*)d_in[29];
  const float* bhh_b    = (const float*)d_in[30];
  const float* bn_g     = (const float*)d_in[31];
  const float* bn_b     = (const float*)d_in[32];
  const float* bn_rm    = (const float*)d_in[33];
  const float* bn_rv    = (const float*)d_in[34];

  const int N  = in_sizes[0] / 2561;
  const int E  = in_sizes[1] / 2;
  const int E2 = E / 2;
  const int Bb = in_sizes[4] / (LSEQ*28);
  const int BL = Bb*LSEQ;

  // ---- workspace carve
  char* p = (char*)d_ws;
  auto alloc = [&](size_t bytes)->void*{
    void* r = (void*)p; p += (bytes + 255) & ~(size_t)255; return r;
  };
  float*    seq0      = (float*)alloc((size_t)BL*D*4);
  float*    sy        = (float*)alloc((size_t)BL*D*4);
  float*    sz        = (float*)alloc((size_t)BL*D*4);
  float*    seq_in    = (float*)alloc((size_t)BL*D*4);
  float*    pre_f     = (float*)alloc((size_t)BL*G4*4);
  float*    pre_b     = (float*)alloc((size_t)BL*G4*4);
  float*    struct0   = (float*)alloc((size_t)N*D*4);
  float*    ty        = (float*)alloc((size_t)N*D*4);
  float*    tz        = (float*)alloc((size_t)N*D*4);
  unsigned* G_in      = (unsigned*)alloc((size_t)N*D*4);
  unsigned* G_out     = (unsigned*)alloc((size_t)N*D*4);
  unsigned* PownPk    = (unsigned*)alloc((size_t)N*D*4);
  u16*      PB4h      = (u16*)alloc(65536*2);
  u16*      PB4l      = (u16*)alloc(65536*2);
  u16*      PBnh      = (u16*)alloc(16384*2);
  u16*      PBnl      = (u16*)alloc(16384*2);
  u16*      PBEh      = (u16*)alloc(327680*2);
  u16*      PBEl      = (u16*)alloc(327680*2);
  float*    WEin      = (float*)alloc(384*4);
  float*    WEout     = (float*)alloc(384*4);
  float*    bsum_f    = (float*)alloc(256*4);
  float*    bsum_b    = (float*)alloc(256*4);
  int*      starts    = (int*)alloc((size_t)Bb*4);
  int*      cnt_s     = (int*)alloc((size_t)N*4);
  int*      cnt_d     = (int*)alloc((size_t)N*4);
  int*      offs_s    = (int*)alloc((size_t)(N+1)*4);
  int*      offs_d    = (int*)alloc((size_t)(N+1)*4);
  int*      cur_s     = (int*)alloc((size_t)N*4);
  int*      cur_d     = (int*)alloc((size_t)N*4);
  int*      part      = (int*)alloc(2*((size_t)(N+1023)>>10)*4 + 256);
  int4*     adj_s     = (int4*)alloc((size_t)(E2+8)*16);
  int4*     adj_d     = (int4*)alloc((size_t)(E2+8)*16);
  (void)ws_size; (void)n_in; (void)out_size;

  // ---- init state from noise inputs
  hipMemcpyAsync(sy, nsy, (size_t)BL*D*4, hipMemcpyDeviceToDevice, stream);
  hipMemcpyAsync(sz, nsz, (size_t)BL*D*4, hipMemcpyDeviceToDevice, stream);
  hipMemcpyAsync(ty, nty, (size_t)N*D*4, hipMemcpyDeviceToDevice, stream);
  hipMemcpyAsync(tz, ntz, (size_t)N*D*4, hipMemcpyDeviceToDevice, stream);

  // ---- prologue
  k_misc<<<1, 256, 0, stream>>>(starts, batch, N, Bb, WEin, WEout, W_in, W_out,
                                bsum_f, bsum_b, bih_f, bhh_f, bih_b, bhh_b);
  k_packB<<<1600, 256, 0, stream>>>(PB4h, PB4l, PBnh, PBnl, PBEh, PBEl,
                                    W_in, W_out, W_node, W_esm);
  k_seq0<<<BL, 128, 0, stream>>>(seq0, hotslice, W_seq, b_seq);
  k_esm2<<<N/32, 512, 0, stream>>>(struct0, x, PBEh, PBEl, PBnh, PBnl,
                                   b_esm, W_node, b_node);
  k_zero2<<<(N+255)/256, 256, 0, stream>>>(cnt_s, cnt_d, N);
  k_count<<<(E2+255)/256, 256, 0, stream>>>(cnt_s, cnt_d, ei, E2);
  {
    int nch = (N + 1023) >> 10;
    k_scanp1<<<2*nch, 1024, 0, stream>>>(cnt_s, cnt_d, part, N, nch);
    k_scanp2<<<1, 64, 0, stream>>>(part, nch);
    k_scanp3<<<2*nch, 1024, 0, stream>>>(cnt_s, cnt_d, part, offs_s, offs_d, N, nch);
  }
  k_copy2<<<(N+255)/256, 256, 0, stream>>>(cur_s, offs_s, cur_d, offs_d, N);
  k_fill<<<(E2+255)/256, 256, 0, stream>>>(ei, eattr, E2, cur_s, adj_s, cur_d, adj_d);
  k_pad<<<1, 64, 0, stream>>>(adj_s, adj_d, E2);
  // initial seq_in(0)/pre(0)  (step 0 is inner: s0s = seq0)
  k_seqA<<<Bb, 256, 0, stream>>>(seq0, sy, sz, seq_in, pre_f, pre_b,
                                 Wih_f, Wih_b, bsum_f, bsum_b);

  const int NB = N/32;

  // ---- main loop: 8 outer x (4 inner + 1)
  for (int o = 0; o < 8; ++o){
    for (int it = 0; it < 5; ++it){
      int gi = o*5 + it;
      bool inner = (it < 4);
      const float* s0t = inner ? struct0 : nullptr;
      float* to_ = inner ? tz : ty;
      float* so_ = inner ? sz : sy;
      const float* otherS = inner ? sy : sz;
      int itn = (gi+1) % 5;
      const float* s0s_n = (itn < 4) ? seq0 : nullptr;
      int doNext = (gi < 39) ? 1 : 0;
      k_A<<<NB, 256, 0, stream>>>(s0t, ty, tz, PB4h, PB4l,
                                  G_in, G_out, PownPk, b_in, b_out, N);
      k_B<<<Bb + NB, 512, 0, stream>>>(G_in, G_out, PownPk, to_,
                                       offs_s, adj_s, offs_d, adj_d,
                                       WEin, WEout, ln_st_g, ln_st_b,
                                       pre_f, pre_b, Whh_f, Whh_b,
                                       seq_in, so_, otherS, s0s_n,
                                       Wih_f, Wih_b, bsum_f, bsum_b,
                                       ln_seq_g, ln_seq_b, doNext, N, Bb);
    }
  }

  k_final<<<(Bb*D+255)/256, 256, 0, stream>>>((float*)d_out, sy, ty, starts,
                                              bn_g, bn_b, bn_rm, bn_rv, Bb);
}

// Round 15
// 3553.505 us; speedup vs baseline: 1.2667x; 1.0000x over previous
//
#include <hip/hip_runtime.h>
#include <hip/hip_fp16.h>
#include <math.h>

#define D 128
#define G4 256
#define LSEQ 21
#define EPSF 1e-5f

typedef unsigned short u16;
typedef __attribute__((ext_vector_type(8))) short bf16x8;
typedef __attribute__((ext_vector_type(4))) float f32x4;
typedef __attribute__((ext_vector_type(2))) unsigned u32x2;
typedef __attribute__((ext_vector_type(4))) unsigned u32x4;

#define MFMA16(a,b,c) __builtin_amdgcn_mfma_f32_16x16x32_bf16(a,b,c,0,0,0)

// ---------------------------------------------------------------- helpers
__device__ __forceinline__ float sigf(float x){ return 1.0f/(1.0f+__expf(-x)); }
__device__ __forceinline__ u16 f2bf(float x){
  unsigned u = __float_as_uint(x);
  return (u16)((u + 0x7FFFu + ((u>>16)&1u)) >> 16);
}
__device__ __forceinline__ float bf2f(u16 h){ return __uint_as_float(((unsigned)h)<<16); }
__device__ __forceinline__ unsigned pack_h2(float a, float b){
  __half2 h = __floats2half2_rn(a, b);
  return *(unsigned*)&h;
}
__device__ __forceinline__ float2 unpack_h2(unsigned u){
  __half2 h = *(__half2*)&u;
  return __half22float2(h);
}
__device__ __forceinline__ u16 f2h(float v){ __half h = __float2half(v); return *(u16*)&h; }

__device__ __forceinline__ void edge_acc(u32x4 a, uint2 g, bool valid,
                                         float2 po2, float2 w0, float2 w1, float2 w2,
                                         float& ax, float& ay){
  float e0=__uint_as_float(a.y), e1=__uint_as_float(a.z), e2=__uint_as_float(a.w);
  float2 ps0 = unpack_h2(g.x);   // {P(ch0), S(ch0)}
  float2 ps1 = unpack_h2(g.y);   // {P(ch1), S(ch1)}
  float gx = po2.x + ps0.x + e0*w0.x + e1*w1.x + e2*w2.x;
  float gy = po2.y + ps1.x + e0*w0.y + e1*w1.y + e2*w2.y;
  float mm = valid ? 1.f : 0.f;
  ax = fmaf(ps0.y*mm, sigf(gx), ax);
  ay = fmaf(ps1.y*mm, sigf(gy), ay);
}

// ---------------------------------------------------------------- prologue kernels
__global__ void k_misc(int* __restrict__ starts, const int* __restrict__ batch, int N, int Bb,
                       float* __restrict__ WEin, float* __restrict__ WEout,
                       const float* __restrict__ W_in, const float* __restrict__ W_out,
                       float* __restrict__ bsum_f, float* __restrict__ bsum_b,
                       const float* __restrict__ bih_f, const float* __restrict__ bhh_f,
                       const float* __restrict__ bih_b, const float* __restrict__ bhh_b){
  int tid = threadIdx.x;
  if (tid < Bb){
    int lo = 0, hi = N;
    while (lo < hi){ int m = (lo+hi)>>1; if (batch[m] < tid) lo = m+1; else hi = m; }
    starts[tid] = lo;
  }
  for (int i = tid; i < 384; i += 256){
    int t = i >> 7, j = i & 127;
    WEin [i] = W_in [(size_t)j*259 + 256 + t];
    WEout[i] = W_out[(size_t)j*259 + 256 + t];
  }
  if (tid < 256){
    bsum_f[tid] = bih_f[tid] + bhh_f[tid];
    bsum_b[tid] = bih_b[tid] + bhh_b[tid];
  }
}

// pre-pack MFMA B-fragments (hi/lo bf16), layout [nt][ks][lane][8] contiguous
__global__ void k_packB(u16* __restrict__ PB4h, u16* __restrict__ PB4l,
                        u16* __restrict__ PBnh, u16* __restrict__ PBnl,
                        u16* __restrict__ PBEh, u16* __restrict__ PBEl,
                        const float* __restrict__ W_in, const float* __restrict__ W_out,
                        const float* __restrict__ W_node, const float* __restrict__ W_esm){
  int idx = blockIdx.x*256 + threadIdx.x;
  if (idx < 65536){
    int j = idx&7, l=(idx>>3)&63, q=idx>>9;
    int ks = q&3, nt = q>>2;
    int c = nt*16 + (l&15);
    int k = ks*32 + ((l>>4)<<3) + j;
    float v;
    if (c < 128)      v = W_in [(size_t)c*259 + k];
    else if (c < 256) v = W_in [(size_t)(c-128)*259 + 128 + k];
    else if (c < 384) v = W_out[(size_t)(c-256)*259 + k];
    else              v = W_out[(size_t)(c-384)*259 + 128 + k];
    u16 h = f2bf(v);
    PB4h[idx] = h; PB4l[idx] = f2bf(v - bf2f(h));
  } else if (idx < 65536 + 16384){
    int p = idx - 65536;
    int j = p&7, l=(p>>3)&63, q=p>>9;
    int ks = q&3, nt = q>>2;
    int c = nt*16 + (l&15);
    int k = ks*32 + ((l>>4)<<3) + j;
    float v = W_node[(size_t)c*129 + k];
    u16 h = f2bf(v);
    PBnh[p] = h; PBnl[p] = f2bf(v - bf2f(h));
  } else if (idx < 65536 + 16384 + 327680){
    int p = idx - 81920;
    int j = p&7, l=(p>>3)&63, q=p>>9;
    int ks = q%80, nt = q/80;
    int c = nt*16 + (l&15);
    int k = ks*32 + ((l>>4)<<3) + j;
    float v = W_esm[(size_t)c*2560 + k];
    u16 h = f2bf(v);
    PBEh[p] = h; PBEl[p] = f2bf(v - bf2f(h));
  }
}

__global__ void k_seq0(float* __restrict__ seq0, const float* __restrict__ hot,
                       const float* __restrict__ W_seq, const float* __restrict__ b_seq){
  int row = blockIdx.x, j = threadIdx.x;           // 128 threads
  const float* h = hot + (size_t)row*28;
  const float* w = W_seq + (size_t)j*28;
  float acc = b_seq[j];
  #pragma unroll
  for (int k = 0; k < 28; k++) acc += h[k]*w[k];
  seq0[(size_t)row*D + j] = acc;
}

// fused: esm = x[:,1:] @ W_esm.T + b_esm ; struct0 = [esm, x[:,:1]] @ W_node.T + b_node
// 32 rows/block x 512 threads; depth-3 register prefetch of x chunks
__global__ __launch_bounds__(512) void k_esm2(float* __restrict__ struct0, const float* __restrict__ x,
    const u16* __restrict__ PBEh, const u16* __restrict__ PBEl,
    const u16* __restrict__ PBnh, const u16* __restrict__ PBnl,
    const float* __restrict__ b_esm, const float* __restrict__ W_node,
    const float* __restrict__ b_node){
  __shared__ union {
    struct { u16 xh[32*72], xl[32*72]; } p1;
    struct { u16 Ah[32*136], Al[32*136]; } p2;
  } uu;
  __shared__ float esmF[32*132];
  int tid = threadIdx.x;
  int r0 = blockIdx.x*32;
  int w = tid>>6, l = tid&63;           // 8 waves, wave w owns coltile w
  f32x4 acc[2];
  acc[0] = (f32x4){0.f,0.f,0.f,0.f};
  acc[1] = (f32x4){0.f,0.f,0.f,0.f};

  float xv[4], xw[4];
  int rr = tid >> 5, k2i = tid & 31;    // rows rr, rr+16 ; col pair k2i
  #pragma unroll
  for (int q = 0; q < 2; q++){
    const float* src = x + (size_t)(r0+rr+16*q)*2561 + 1 + k2i*2;
    xv[2*q]   = src[0];
    xv[2*q+1] = src[1];
  }
  #pragma unroll
  for (int q = 0; q < 2; q++){
    const float* src = x + (size_t)(r0+rr+16*q)*2561 + 1 + 64 + k2i*2;
    xw[2*q]   = src[0];
    xw[2*q+1] = src[1];
  }
  for (int kc = 0; kc < 2560; kc += 64){
    __syncthreads();
    unsigned* xh32 = (unsigned*)uu.p1.xh;
    unsigned* xl32 = (unsigned*)uu.p1.xl;
    #pragma unroll
    for (int q = 0; q < 2; q++){
      float v0 = xv[2*q], v1 = xv[2*q+1];
      u16 h0 = f2bf(v0), h1 = f2bf(v1);
      u16 l0 = f2bf(v0 - bf2f(h0)), l1 = f2bf(v1 - bf2f(h1));
      int r = rr + 16*q;
      xh32[r*36 + k2i] = (unsigned)h0 | ((unsigned)h1 << 16);
      xl32[r*36 + k2i] = (unsigned)l0 | ((unsigned)l1 << 16);
    }
    __syncthreads();
    #pragma unroll
    for (int q = 0; q < 4; q++) xv[q] = xw[q];
    if (kc + 128 < 2560){
      #pragma unroll
      for (int q = 0; q < 2; q++){
        const float* src = x + (size_t)(r0+rr+16*q)*2561 + 1 + kc + 128 + k2i*2;
        xw[2*q]   = src[0];
        xw[2*q+1] = src[1];
      }
    }
    #pragma unroll
    for (int ks = 0; ks < 2; ks++){
      bf16x8 ah[2], al[2];
      #pragma unroll
      for (int rt = 0; rt < 2; rt++){
        int row = rt*16 + (l&15);
        int k = ks*32 + ((l>>4)<<3);
        ah[rt] = *(const bf16x8*)&uu.p1.xh[row*72 + k];
        al[rt] = *(const bf16x8*)&uu.p1.xl[row*72 + k];
      }
      int ksg = (kc>>5) + ks;
      bf16x8 bh = *(const bf16x8*)&PBEh[((size_t)(w*80 + ksg)*64 + l)*8];
      bf16x8 bl = *(const bf16x8*)&PBEl[((size_t)(w*80 + ksg)*64 + l)*8];
      #pragma unroll
      for (int rt = 0; rt < 2; rt++){
        acc[rt] = MFMA16(ah[rt], bh, acc[rt]);
        acc[rt] = MFMA16(al[rt], bh, acc[rt]);
        acc[rt] = MFMA16(ah[rt], bl, acc[rt]);
      }
    }
  }
  __syncthreads();
  int cq = l & 15, rqb = (l>>4)*4;
  {
    int coln = w*16 + cq;
    float be = b_esm[coln];
    #pragma unroll
    for (int rt = 0; rt < 2; rt++)
      #pragma unroll
      for (int r = 0; r < 4; r++)
        esmF[(rt*16+rqb+r)*132 + coln] = acc[rt][r] + be;
  }
  __syncthreads();
  {
    unsigned* Ah32 = (unsigned*)uu.p2.Ah;
    unsigned* Al32 = (unsigned*)uu.p2.Al;
    int rr2 = tid >> 6, k2 = tid & 63;   // 8 rows/iter, 64 col-pairs
    #pragma unroll
    for (int q = 0; q < 4; q++){
      int r = rr2 + 8*q;
      float v0 = esmF[r*132 + k2*2];
      float v1 = esmF[r*132 + k2*2 + 1];
      u16 h0 = f2bf(v0), h1 = f2bf(v1);
      u16 l0 = f2bf(v0 - bf2f(h0)), l1 = f2bf(v1 - bf2f(h1));
      Ah32[r*68 + k2] = (unsigned)h0 | ((unsigned)h1 << 16);
      Al32[r*68 + k2] = (unsigned)l0 | ((unsigned)l1 << 16);
    }
  }
  __syncthreads();
  f32x4 acc2[2];
  acc2[0] = (f32x4){0.f,0.f,0.f,0.f};
  acc2[1] = (f32x4){0.f,0.f,0.f,0.f};
  #pragma unroll
  for (int ks = 0; ks < 4; ks++){
    bf16x8 ah[2], al[2];
    #pragma unroll
    for (int rt = 0; rt < 2; rt++){
      int row = rt*16 + (l&15);
      int k = ks*32 + ((l>>4)<<3);
      ah[rt] = *(const bf16x8*)&uu.p2.Ah[row*136 + k];
      al[rt] = *(const bf16x8*)&uu.p2.Al[row*136 + k];
    }
    bf16x8 bh = *(const bf16x8*)&PBnh[((size_t)(w*4 + ks)*64 + l)*8];
    bf16x8 bl = *(const bf16x8*)&PBnl[((size_t)(w*4 + ks)*64 + l)*8];
    #pragma unroll
    for (int rt = 0; rt < 2; rt++){
      acc2[rt] = MFMA16(ah[rt], bh, acc2[rt]);
      acc2[rt] = MFMA16(al[rt], bh, acc2[rt]);
      acc2[rt] = MFMA16(ah[rt], bl, acc2[rt]);
    }
  }
  {
    int col = w*16 + cq;
    float wl = W_node[(size_t)col*129 + 128];
    float bn = b_node[col];
    #pragma unroll
    for (int rt = 0; rt < 2; rt++)
      #pragma unroll
      for (int r = 0; r < 4; r++){
        int row = r0 + rt*16 + rqb + r;
        float x0 = x[(size_t)row*2561];
        struct0[(size_t)row*D + col] = acc2[rt][r] + x0*wl + bn;
      }
  }
}

// ---------------------------------------------------------------- CSR build
__global__ void k_zero2(int* a, int* b, int n){
  int i = blockIdx.x*blockDim.x + threadIdx.x;
  if (i < n){ a[i] = 0; b[i] = 0; }
}
__global__ void k_count(int* cnt_s, int* cnt_d, const int* __restrict__ ei, int E2){
  int e = blockIdx.x*blockDim.x + threadIdx.x;
  if (e < E2){
    atomicAdd(&cnt_s[ei[2*e]], 1);
    atomicAdd(&cnt_d[ei[2*E2 + 2*e]], 1);
  }
}
// parallel 3-phase scan over cnt_s and cnt_d together
__global__ __launch_bounds__(1024) void k_scanp1(const int* __restrict__ cnt_s,
                                                 const int* __restrict__ cnt_d,
                                                 int* __restrict__ part, int n, int nch){
  int arr = blockIdx.x / nch, chunk = blockIdx.x % nch;
  const int* cnt = arr ? cnt_d : cnt_s;
  int i = chunk*1024 + threadIdx.x;
  int v = (i < n) ? cnt[i] : 0;
  __shared__ int ws[16];
  #pragma unroll
  for (int o = 32; o; o >>= 1) v += __shfl_down(v, o);
  if ((threadIdx.x & 63) == 0) ws[threadIdx.x >> 6] = v;
  __syncthreads();
  if (threadIdx.x == 0){
    int t = 0;
    #pragma unroll
    for (int q = 0; q < 16; q++) t += ws[q];
    part[blockIdx.x] = t;
  }
}
__global__ void k_scanp2(int* part, int nch){
  int tid = threadIdx.x;
  if (tid < 2){
    int base = 0;
    for (int i = 0; i < nch; i++){
      int v = part[tid*nch + i];
      part[tid*nch + i] = base;
      base += v;
    }
  }
}
__global__ __launch_bounds__(1024) void k_scanp3(const int* __restrict__ cnt_s,
                                                 const int* __restrict__ cnt_d,
                                                 const int* __restrict__ part,
                                                 int* __restrict__ offs_s, int* __restrict__ offs_d,
                                                 int n, int nch){
  int arr = blockIdx.x / nch, chunk = blockIdx.x % nch;
  const int* cnt = arr ? cnt_d : cnt_s;
  int* offs = arr ? offs_d : offs_s;
  __shared__ int sh[1024];
  int tid = threadIdx.x;
  int i = chunk*1024 + tid;
  int v = (i < n) ? cnt[i] : 0;
  sh[tid] = v;
  __syncthreads();
  for (int off = 1; off < 1024; off <<= 1){
    int t = (tid >= off) ? sh[tid-off] : 0;
    __syncthreads();
    sh[tid] += t;
    __syncthreads();
  }
  int base = part[blockIdx.x];
  if (i < n) offs[i] = base + sh[tid] - v;
  if (i == n-1) offs[n] = base + sh[tid];
}
__global__ void k_copy2(int* cur_s, const int* offs_s, int* cur_d, const int* offs_d, int n){
  int i = blockIdx.x*blockDim.x + threadIdx.x;
  if (i < n){ cur_s[i] = offs_s[i]; cur_d[i] = offs_d[i]; }
}
__global__ void k_fill(const int* __restrict__ ei, const float* __restrict__ eattr, int E2,
                       int* cur_s, int4* __restrict__ adj_s,
                       int* cur_d, int4* __restrict__ adj_d){
  int e = blockIdx.x*blockDim.x + threadIdx.x;
  if (e >= E2) return;
  int s = ei[2*e];
  int d = ei[2*E2 + 2*e];
  const float* ein  = eattr + (size_t)(2*e+1)*3;
  const float* eout = eattr + (size_t)(2*e)*3;
  int ps = atomicAdd(&cur_s[s], 1);
  adj_s[ps] = make_int4(d, __float_as_int(ein[0]),  __float_as_int(ein[1]),  __float_as_int(ein[2]));
  int pd = atomicAdd(&cur_d[d], 1);
  adj_d[pd] = make_int4(s, __float_as_int(eout[0]), __float_as_int(eout[1]), __float_as_int(eout[2]));
}
__global__ void k_pad(int4* __restrict__ adj_s, int4* __restrict__ adj_d, int E2){
  int t = threadIdx.x;
  if (t < 8){
    adj_s[E2+t] = make_int4(0,0,0,0);
    adj_d[E2+t] = make_int4(0,0,0,0);
  }
}

// ---------------------------------------------------------------- initial seq pre-GEMM
__global__ __launch_bounds__(256) void k_seqA(
  const float* __restrict__ s0s, const float* __restrict__ sy, const float* __restrict__ sz,
  float* __restrict__ seq_in, float* __restrict__ pre_f, float* __restrict__ pre_b,
  const float* __restrict__ Wih_f, const float* __restrict__ Wih_b,
  const float* __restrict__ bsum_f, const float* __restrict__ bsum_b)
{
  __shared__ float sh[LSEQ*128];
  int tid = threadIdx.x;
  int b = blockIdx.x;
  for (int idx = tid; idx < LSEQ*128; idx += 256){
    size_t off = (size_t)b*LSEQ*128 + idx;
    float v = sy[off] + sz[off];
    if (s0s) v += s0s[off];
    sh[idx] = v;
    seq_in[off] = v;
  }
  __syncthreads();
  int g = tid;  // 0..255
  float accf[LSEQ], accb[LSEQ];
  float bf = bsum_f[g], bb = bsum_b[g];
  #pragma unroll
  for (int l = 0; l < LSEQ; l++){ accf[l] = bf; accb[l] = bb; }
  const float* wfp = Wih_f + (size_t)g*128;
  const float* wbp = Wih_b + (size_t)g*128;
  for (int kc = 0; kc < 128; kc += 16){
    float4 wf[4], wb[4];
    #pragma unroll
    for (int q = 0; q < 4; q++){
      wf[q] = *(const float4*)(wfp + kc + 4*q);
      wb[q] = *(const float4*)(wbp + kc + 4*q);
    }
    #pragma unroll
    for (int l = 0; l < LSEQ; l++){
      #pragma unroll
      for (int q = 0; q < 4; q++){
        float4 s4 = *(const float4*)&sh[l*128 + kc + 4*q];
        accf[l] += s4.x*wf[q].x + s4.y*wf[q].y + s4.z*wf[q].z + s4.w*wf[q].w;
        accb[l] += s4.x*wb[q].x + s4.y*wb[q].y + s4.z*wb[q].z + s4.w*wb[q].w;
      }
    }
  }
  for (int l = 0; l < LSEQ; l++){
    pre_f[((size_t)b*LSEQ + l)*G4 + g] = accf[l];
    pre_b[((size_t)b*LSEQ + l)*G4 + g] = accb[l];
  }
}

// ---------------------------------------------------------------- per-step kernel A (struct only)
__global__ __launch_bounds__(256) void k_A(
  const float* __restrict__ s0t, const float* __restrict__ ty, const float* __restrict__ tz,
  const u16* __restrict__ PB4h, const u16* __restrict__ PB4l,
  unsigned* __restrict__ G_in, unsigned* __restrict__ G_out,
  unsigned* __restrict__ PownPk,
  const float* __restrict__ b_in, const float* __restrict__ b_out, int N)
{
  __shared__ struct { u16 Ah[32*136], Al[32*136]; float Sf[32*132]; } m;
  int tid = threadIdx.x;
  int r0 = blockIdx.x*32;
  const float4* ty4 = (const float4*)(ty + (size_t)r0*D);
  const float4* tz4 = (const float4*)(tz + (size_t)r0*D);
  const float4* s04 = s0t ? (const float4*)(s0t + (size_t)r0*D) : nullptr;
  #pragma unroll
  for (int q = 0; q < 4; q++){
    int i = tid + 256*q;          // float4 index, 0..1023
    int r = i >> 5, k4 = i & 31;
    float4 v = ty4[i];
    float4 z = tz4[i];
    v.x += z.x; v.y += z.y; v.z += z.z; v.w += z.w;
    if (s04){ float4 s = s04[i]; v.x += s.x; v.y += s.y; v.z += s.z; v.w += s.w; }
    u16 h0 = f2bf(v.x), h1 = f2bf(v.y), h2 = f2bf(v.z), h3 = f2bf(v.w);
    *(ushort4*)&m.Ah[r*136 + k4*4] = make_ushort4(h0,h1,h2,h3);
    *(ushort4*)&m.Al[r*136 + k4*4] = make_ushort4(
        f2bf(v.x - bf2f(h0)), f2bf(v.y - bf2f(h1)),
        f2bf(v.z - bf2f(h2)), f2bf(v.w - bf2f(h3)));
    *(float4*)&m.Sf[r*132 + k4*4] = v;
  }
  __syncthreads();
  int w = tid >> 6, l = tid & 63;
  f32x4 acc[2][8];
  #pragma unroll
  for (int a=0;a<2;a++)
    #pragma unroll
    for (int b=0;b<8;b++) acc[a][b] = (f32x4){0.f,0.f,0.f,0.f};
  #pragma unroll
  for (int ks = 0; ks < 4; ks++){
    bf16x8 ah[2], al[2];
    #pragma unroll
    for (int rt = 0; rt < 2; rt++){
      int row = rt*16 + (l&15);
      int k = ks*32 + ((l>>4)<<3);
      ah[rt] = *(const bf16x8*)&m.Ah[row*136 + k];
      al[rt] = *(const bf16x8*)&m.Al[row*136 + k];
    }
    #pragma unroll
    for (int ct = 0; ct < 8; ct++){
      int nt = w*8 + ct;
      bf16x8 bh = *(const bf16x8*)&PB4h[((size_t)(nt*4 + ks)*64 + l)*8];
      bf16x8 bl = *(const bf16x8*)&PB4l[((size_t)(nt*4 + ks)*64 + l)*8];
      #pragma unroll
      for (int rt = 0; rt < 2; rt++){
        acc[rt][ct] = MFMA16(ah[rt], bh, acc[rt][ct]);
        acc[rt][ct] = MFMA16(al[rt], bh, acc[rt][ct]);
        acc[rt][ct] = MFMA16(ah[rt], bl, acc[rt][ct]);
      }
    }
  }
  // ---- coalesced table epilogue via LDS staging (reuses Ah/Al region) ----
  __syncthreads();                      // MFMA done reading Ah/Al
  unsigned* stg = (unsigned*)m.Ah;      // 32*128 u32 = 16KB (fits in Ah+Al)
  u16* stg16 = (u16*)m.Ah;
  int cq = l & 15, rqb = (l>>4)*4;
  if (w == 1){
    #pragma unroll
    for (int ct = 0; ct < 8; ct++){
      int coln = ct*16 + cq;
      #pragma unroll
      for (int rt = 0; rt < 2; rt++){
        #pragma unroll
        for (int r = 0; r < 4; r++){
          int lr = rt*16 + rqb + r;
          stg[lr*128 + coln] = pack_h2(acc[rt][ct][r], m.Sf[lr*132 + coln]);
        }
      }
    }
  }
  __syncthreads();
  {
    uint4* dst = (uint4*)(G_in + (size_t)r0*D);
    const uint4* src = (const uint4*)stg;
    #pragma unroll
    for (int q = 0; q < 4; q++) dst[tid + 256*q] = src[tid + 256*q];
  }
  __syncthreads();
  if (w == 2){
    #pragma unroll
    for (int ct = 0; ct < 8; ct++){
      int coln = ct*16 + cq;
      #pragma unroll
      for (int rt = 0; rt < 2; rt++){
        #pragma unroll
        for (int r = 0; r < 4; r++){
          int lr = rt*16 + rqb + r;
          stg[lr*128 + coln] = pack_h2(acc[rt][ct][r], m.Sf[lr*132 + coln]);
        }
      }
    }
  }
  __syncthreads();
  {
    uint4* dst = (uint4*)(G_out + (size_t)r0*D);
    const uint4* src = (const uint4*)stg;
    #pragma unroll
    for (int q = 0; q < 4; q++) dst[tid + 256*q] = src[tid + 256*q];
  }
  __syncthreads();
  if (w == 0 || w == 3){
    const float* bb = (w == 0) ? b_in : b_out;
    int half = (w == 0) ? 0 : 1;
    #pragma unroll
    for (int ct = 0; ct < 8; ct++){
      int coln = ct*16 + cq;
      float bc = bb[coln];
      #pragma unroll
      for (int rt = 0; rt < 2; rt++){
        #pragma unroll
        for (int r = 0; r < 4; r++){
          int lr = rt*16 + rqb + r;
          stg16[(lr*128 + coln)*2 + half] = f2h(acc[rt][ct][r] + bc);
        }
      }
    }
  }
  __syncthreads();
  {
    uint4* dst = (uint4*)(PownPk + (size_t)r0*D);
    const uint4* src = (const uint4*)stg;
    #pragma unroll
    for (int q = 0; q < 4; q++) dst[tid + 256*q] = src[tid + 256*q];
  }
}

// ---------------------------------------------------------------- per-step kernel B
// blocks [0,Bb): LSTM(i) + seq LN -> so ; then (doNext) seq_in(i+1) staging + pre-GEMM(i+1)
// blocks [Bb, Bb+N/32): edge gather — wave owns 4 consecutive nodes (both dirs + LN),
//   with cross-node prefetch of Pown/own-G rows.
__global__ __launch_bounds__(512) void k_B(
  const unsigned* __restrict__ G_in, const unsigned* __restrict__ G_out,
  const unsigned* __restrict__ PownPk,
  float* __restrict__ to,
  const int* __restrict__ offs_s, const int4* __restrict__ adj_s,
  const int* __restrict__ offs_d, const int4* __restrict__ adj_d,
  const float* __restrict__ WEin, const float* __restrict__ WEout,
  const float* __restrict__ ln_st_g, const float* __restrict__ ln_st_b,
  float* pre_f, float* pre_b,
  const float* __restrict__ Whh_f, const float* __restrict__ Whh_b,
  float* seq_in, float* __restrict__ so,
  const float* __restrict__ otherS, const float* __restrict__ s0s_n,
  const float* __restrict__ Wih_f, const float* __restrict__ Wih_b,
  const float* __restrict__ bsum_f, const float* __restrict__ bsum_b,
  const float* __restrict__ ln_seq_g, const float* __restrict__ ln_seq_b,
  int doNext, int N, int Bb)
{
  __shared__ union {
    struct {
      float h_hist[2][LSEQ][64];
      float hcur[2][64];
      float gsh[2][G4];
      float soL[LSEQ*128];
      float shG[LSEQ*128];
    } sq;
  } u;
  if ((int)blockIdx.x >= Bb){
    int wv = threadIdx.x >> 6, lane = threadIdx.x & 63;
    int n0 = ((blockIdx.x - Bb)*8 + wv)*4;           // 4 consecutive nodes per wave
    const float2* WEi2 = (const float2*)WEin;
    const float2* WEo2 = (const float2*)WEout;
    float2 wi0 = WEi2[lane], wi1 = WEi2[64+lane], wi2 = WEi2[128+lane];
    float2 wo0 = WEo2[lane], wo1 = WEo2[64+lane], wo2 = WEo2[128+lane];
    float2 g2v = ((const float2*)ln_st_g)[lane], be2 = ((const float2*)ln_st_b)[lane];
    const uint2* Gi = (const uint2*)G_in;
    const uint2* Go = (const uint2*)G_out;
    // prefetch first node's own rows
    u32x2 pwN = *((const u32x2*)PownPk + (size_t)n0*64 + lane);
    uint2 gownN = Gi[(size_t)n0*64 + lane];
    #pragma unroll 1
    for (int n = n0; n < n0+4; ++n){
      u32x2 pw = pwN;
      uint2 gown = gownN;
      if (n+1 < n0+4){
        pwN = *((const u32x2*)PownPk + (size_t)(n+1)*64 + lane);
        gownN = Gi[(size_t)(n+1)*64 + lane];
      }
      float2 pp0 = unpack_h2(pw.x), pp1 = unpack_h2(pw.y);
      float2 poI = make_float2(pp0.x, pp1.x);
      float2 poO = make_float2(pp0.y, pp1.y);
      float ax = 0.f, ay = 0.f;
      int j0 = __builtin_amdgcn_readfirstlane(offs_s[n]);
      int j1 = __builtin_amdgcn_readfirstlane(offs_s[n+1]);
      for (int jb = j0; jb < j1; jb += 4){
        int rem = j1 - jb;
        const u32x4* ap = (const u32x4*)adj_s + jb;
        u32x4 a0 = ap[0], a1 = ap[1], a2 = ap[2], a3 = ap[3];
        uint2 g0 = Gi[(size_t)a0.x*64 + lane];
        uint2 g1 = Gi[(size_t)a1.x*64 + lane];
        uint2 g2 = Gi[(size_t)a2.x*64 + lane];
        uint2 g3 = Gi[(size_t)a3.x*64 + lane];
        edge_acc(a0, g0, true,  poI, wi0, wi1, wi2, ax, ay);
        edge_acc(a1, g1, rem>1, poI, wi0, wi1, wi2, ax, ay);
        edge_acc(a2, g2, rem>2, poI, wi0, wi1, wi2, ax, ay);
        edge_acc(a3, g3, rem>3, poI, wi0, wi1, wi2, ax, ay);
      }
      j0 = __builtin_amdgcn_readfirstlane(offs_d[n]);
      j1 = __builtin_amdgcn_readfirstlane(offs_d[n+1]);
      for (int jb = j0; jb < j1; jb += 4){
        int rem = j1 - jb;
        const u32x4* ap = (const u32x4*)adj_d + jb;
        u32x4 a0 = ap[0], a1 = ap[1], a2 = ap[2], a3 = ap[3];
        uint2 g0 = Go[(size_t)a0.x*64 + lane];
        uint2 g1 = Go[(size_t)a1.x*64 + lane];
        uint2 g2 = Go[(size_t)a2.x*64 + lane];
        uint2 g3 = Go[(size_t)a3.x*64 + lane];
        edge_acc(a0, g0, true,  poO, wo0, wo1, wo2, ax, ay);
        edge_acc(a1, g1, rem>1, poO, wo0, wo1, wo2, ax, ay);
        edge_acc(a2, g2, rem>2, poO, wo0, wo1, wo2, ax, ay);
        edge_acc(a3, g3, rem>3, poO, wo0, wo1, wo2, ax, ay);
      }
      float vx = unpack_h2(gown.x).y + ax;
      float vy = unpack_h2(gown.y).y + ay;
      float s = vx+vy, sq = vx*vx + vy*vy;
      #pragma unroll
      for (int o = 32; o; o >>= 1){ s += __shfl_xor(s, o); sq += __shfl_xor(sq, o); }
      float mean = s*(1.f/128.f);
      float inv = rsqrtf(sq*(1.f/128.f) - mean*mean + EPSF);
      float2 o2;
      o2.x = (vx-mean)*inv*g2v.x + be2.x;
      o2.y = (vy-mean)*inv*g2v.y + be2.y;
      ((float2*)to)[(size_t)n*64 + lane] = o2;
    }
  } else {
    int b = blockIdx.x;
    int tid = threadIdx.x;
    int dir = tid >> 8, g = tid & 255;
    const float* Whh = dir ? Whh_b : Whh_f;
    const float* pre = dir ? pre_b : pre_f;
    float w[64];
    #pragma unroll
    for (int q = 0; q < 16; q++){
      float4 t4 = *(const float4*)(Whh + (size_t)g*64 + 4*q);
      w[4*q] = t4.x; w[4*q+1] = t4.y; w[4*q+2] = t4.z; w[4*q+3] = t4.w;
    }
    float c = 0.f;
    for (int t = 0; t < LSEQ; ++t){
      int tt = dir ? (LSEQ-1-t) : t;
      float gate = pre[((size_t)b*LSEQ + tt)*G4 + g];
      if (t > 0){
        #pragma unroll
        for (int q = 0; q < 16; q++){
          float4 h4 = *(const float4*)&u.sq.hcur[dir][4*q];
          gate += w[4*q]*h4.x + w[4*q+1]*h4.y + w[4*q+2]*h4.z + w[4*q+3]*h4.w;
        }
      }
      u.sq.gsh[dir][g] = gate;
      __syncthreads();
      if (g < 64){
        float iv = u.sq.gsh[dir][g], fv = u.sq.gsh[dir][64+g];
        float gv = u.sq.gsh[dir][128+g], ov = u.sq.gsh[dir][192+g];
        c = sigf(fv)*c + sigf(iv)*tanhf(gv);
        float h = sigf(ov)*tanhf(c);
        u.sq.hcur[dir][g] = h;
        u.sq.h_hist[dir][tt][g] = h;
      }
      __syncthreads();
    }
    // residual + LN, wave per row; keep result in soL for next-step pre-GEMM
    int wv = tid >> 6, lane = tid & 63;
    for (int l = wv; l < LSEQ; l += 8){
      float2 sv = ((const float2*)(seq_in + ((size_t)b*LSEQ + l)*128))[lane];
      float hv0, hv1;
      if (lane < 32){ hv0 = u.sq.h_hist[0][l][2*lane];    hv1 = u.sq.h_hist[0][l][2*lane+1]; }
      else          { hv0 = u.sq.h_hist[1][l][2*lane-64]; hv1 = u.sq.h_hist[1][l][2*lane-63]; }
      float vx = sv.x + hv0, vy = sv.y + hv1;
      float s = vx+vy, sq = vx*vx + vy*vy;
      #pragma unroll
      for (int o = 32; o; o >>= 1){ s += __shfl_xor(s, o); sq += __shfl_xor(sq, o); }
      float mean = s*(1.f/128.f);
      float inv = rsqrtf(sq*(1.f/128.f) - mean*mean + EPSF);
      float2 g2 = ((const float2*)ln_seq_g)[lane], b2 = ((const float2*)ln_seq_b)[lane];
      float2 o2;
      o2.x = (vx-mean)*inv*g2.x + b2.x;
      o2.y = (vy-mean)*inv*g2.y + b2.y;
      ((float2*)(so + ((size_t)b*LSEQ + l)*128))[lane] = o2;
      u.sq.soL[l*128 + 2*lane]     = o2.x;
      u.sq.soL[l*128 + 2*lane + 1] = o2.y;
    }
    if (!doNext) return;
    __syncthreads();
    // stage seq_in(i+1) = s0s_n? + soL + otherS -> shG + global seq_in
    {
      const float4* oS4 = (const float4*)(otherS + (size_t)b*LSEQ*128);
      const float4* s04 = s0s_n ? (const float4*)(s0s_n + (size_t)b*LSEQ*128) : nullptr;
      float4* gi4 = (float4*)(seq_in + (size_t)b*LSEQ*128);
      for (int idx = tid; idx < LSEQ*32; idx += 512){
        float4 v = *(const float4*)&u.sq.soL[idx*4];
        float4 o = oS4[idx];
        v.x += o.x; v.y += o.y; v.z += o.z; v.w += o.w;
        if (s04){ float4 s0 = s04[idx]; v.x += s0.x; v.y += s0.y; v.z += s0.z; v.w += s0.w; }
        *(float4*)&u.sq.shG[idx*4] = v;
        gi4[idx] = v;
      }
    }
    __syncthreads();
    // pre-GEMM(i+1): 512 threads, dir-split
    {
      int g2 = tid & 255;
      int dn = tid >> 8;
      const float* wp = (dn ? Wih_b : Wih_f) + (size_t)g2*128;
      float bsv = dn ? bsum_b[g2] : bsum_f[g2];
      float accv[LSEQ];
      #pragma unroll
      for (int l = 0; l < LSEQ; l++) accv[l] = bsv;
      for (int kc = 0; kc < 128; kc += 16){
        float4 wf[4];
        #pragma unroll
        for (int q = 0; q < 4; q++) wf[q] = *(const float4*)(wp + kc + 4*q);
        #pragma unroll
        for (int l = 0; l < LSEQ; l++){
          #pragma unroll
          for (int q = 0; q < 4; q++){
            float4 s4 = *(const float4*)&u.sq.shG[l*128 + kc + 4*q];
            accv[l] += s4.x*wf[q].x + s4.y*wf[q].y + s4.z*wf[q].z + s4.w*wf[q].w;
          }
        }
      }
      float* dst = dn ? pre_b : pre_f;
      for (int l = 0; l < LSEQ; l++)
        dst[((size_t)b*LSEQ + l)*G4 + g2] = accv[l];
    }
  }
}

// ---------------------------------------------------------------- epilogue
__global__ void k_final(float* __restrict__ out, const float* __restrict__ sy,
                        const float* __restrict__ ty, const int* __restrict__ starts,
                        const float* __restrict__ g, const float* __restrict__ b,
                        const float* __restrict__ rm, const float* __restrict__ rv, int Bb){
  int i = blockIdx.x*blockDim.x + threadIdx.x;
  if (i >= Bb*D) return;
  int bb = i >> 7, d = i & 127;
  float feat = sy[((size_t)bb*LSEQ + 10)*D + d] + ty[(size_t)starts[bb]*D + d];
  out[i] = (feat - rm[d])*rsqrtf(rv[d]+EPSF)*g[d] + b[d];
}

// ---------------------------------------------------------------- host
extern "C" void kernel_launch(void* const* d_in, const int* in_sizes, int n_in,
                              void* d_out, int out_size, void* d_ws, size_t ws_size,
                              hipStream_t stream)
{
  const float* x        = (const float*)d_in[0];
  const int*   ei       = (const int*)  d_in[1];
  const float* eattr    = (const float*)d_in[2];
  const int*   batch    = (const int*)  d_in[3];
  const float* hotslice = (const float*)d_in[4];
  const float* nsy      = (const float*)d_in[5];
  const float* nsz      = (const float*)d_in[6];
  const float* nty      = (const float*)d_in[7];
  const float* ntz      = (const float*)d_in[8];
  const float* W_esm    = (const float*)d_in[9];
  const float* b_esm    = (const float*)d_in[10];
  const float* W_node   = (const float*)d_in[11];
  const float* b_node   = (const float*)d_in[12];
  const float* W_seq    = (const float*)d_in[13];
  const float* b_seq    = (const float*)d_in[14];
  const float* ln_seq_g = (const float*)d_in[15];
  const float* ln_seq_b = (const float*)d_in[16];
  const float* ln_st_g  = (const float*)d_in[17];
  const float* ln_st_b  = (const float*)d_in[18];
  const float* W_in     = (const float*)d_in[19];
  const float* b_in     = (const float*)d_in[20];
  const float* W_out    = (const float*)d_in[21];
  const float* b_out    = (const float*)d_in[22];
  const float* Wih_f    = (const float*)d_in[23];
  const float* Whh_f    = (const float*)d_in[24];
  const float* bih_f    = (const float*)d_in[25];
  const float* bhh_f    = (const float*)d_in[26];
  const float* Wih_b    = (const float*)d_in[27];
  const float* Whh_b    = (const float*)d_in[28];
  const float* bih_b    = (const float*)d_in[29];
  const float* bhh_b    = (const float*)d_in[30];
  const float* bn_g     = (const float*)d_in[31];
  const float* bn_b     = (const float*)d_in[32];
  const float* bn_rm    = (const float*)d_in[33];
  const float* bn_rv    = (const float*)d_in[34];

  const int N  = in_sizes[0] / 2561;
  const int E  = in_sizes[1] / 2;
  const int E2 = E / 2;
  const int Bb = in_sizes[4] / (LSEQ*28);
  const int BL = Bb*LSEQ;

  // ---- workspace carve
  char* p = (char*)d_ws;
  auto alloc = [&](size_t bytes)->void*{
    void* r = (void*)p; p += (bytes + 255) & ~(size_t)255; return r;
  };
  float*    seq0      = (float*)alloc((size_t)BL*D*4);
  float*    sy        = (float*)alloc((size_t)BL*D*4);
  float*    sz        = (float*)alloc((size_t)BL*D*4);
  float*    seq_in    = (float*)alloc((size_t)BL*D*4);
  float*    pre_f     = (float*)alloc((size_t)BL*G4*4);
  float*    pre_b     = (float*)alloc((size_t)BL*G4*4);
  float*    struct0   = (float*)alloc((size_t)N*D*4);
  float*    ty        = (float*)alloc((size_t)N*D*4);
  float*    tz        = (float*)alloc((size_t)N*D*4);
  unsigned* G_in      = (unsigned*)alloc((size_t)N*D*4);
  unsigned* G_out     = (unsigned*)alloc((size_t)N*D*4);
  unsigned* PownPk    = (unsigned*)alloc((size_t)N*D*4);
  u16*      PB4h      = (u16*)alloc(65536*2);
  u16*      PB4l      = (u16*)alloc(65536*2);
  u16*      PBnh      = (u16*)alloc(16384*2);
  u16*      PBnl      = (u16*)alloc(16384*2);
  u16*      PBEh      = (u16*)alloc(327680*2);
  u16*      PBEl      = (u16*)alloc(327680*2);
  float*    WEin      = (float*)alloc(384*4);
  float*    WEout     = (float*)alloc(384*4);
  float*    bsum_f    = (float*)alloc(256*4);
  float*    bsum_b    = (float*)alloc(256*4);
  int*      starts    = (int*)alloc((size_t)Bb*4);
  int*      cnt_s     = (int*)alloc((size_t)N*4);
  int*      cnt_d     = (int*)alloc((size_t)N*4);
  int*      offs_s    = (int*)alloc((size_t)(N+1)*4);
  int*      offs_d    = (int*)alloc((size_t)(N+1)*4);
  int*      cur_s     = (int*)alloc((size_t)N*4);
  int*      cur_d     = (int*)alloc((size_t)N*4);
  int*      part      = (int*)alloc(2*((size_t)(N+1023)>>10)*4 + 256);
  int4*     adj_s     = (int4*)alloc((size_t)(E2+8)*16);
  int4*     adj_d     = (int4*)alloc((size_t)(E2+8)*16);
  (void)ws_size; (void)n_in; (void)out_size;

  // ---- init state from noise inputs
  hipMemcpyAsync(sy, nsy, (size_t)BL*D*4, hipMemcpyDeviceToDevice, stream);
  hipMemcpyAsync(sz, nsz, (size_t)BL*D*4, hipMemcpyDeviceToDevice, stream);
  hipMemcpyAsync(ty, nty, (size_t)N*D*4, hipMemcpyDeviceToDevice, stream);
  hipMemcpyAsync(tz, ntz, (size_t)N*D*4, hipMemcpyDeviceToDevice, stream);

  // ---- prologue
  k_misc<<<1, 256, 0, stream>>>(starts, batch, N, Bb, WEin, WEout, W_in, W_out,
                                bsum_f, bsum_b, bih_f, bhh_f, bih_b, bhh_b);
  k_packB<<<1600, 256, 0, stream>>>(PB4h, PB4l, PBnh, PBnl, PBEh, PBEl,
                                    W_in, W_out, W_node, W_esm);
  k_seq0<<<BL, 128, 0, stream>>>(seq0, hotslice, W_seq, b_seq);
  k_esm2<<<N/32, 512, 0, stream>>>(struct0, x, PBEh, PBEl, PBnh, PBnl,
                                   b_esm, W_node, b_node);
  k_zero2<<<(N+255)/256, 256, 0, stream>>>(cnt_s, cnt_d, N);
  k_count<<<(E2+255)/256, 256, 0, stream>>>(cnt_s, cnt_d, ei, E2);
  {
    int nch = (N + 1023) >> 10;
    k_scanp1<<<2*nch, 1024, 0, stream>>>(cnt_s, cnt_d, part, N, nch);
    k_scanp2<<<1, 64, 0, stream>>>(part, nch);
    k_scanp3<<<2*nch, 1024, 0, stream>>>(cnt_s, cnt_d, part, offs_s, offs_d, N, nch);
  }
  k_copy2<<<(N+255)/256, 256, 0, stream>>>(cur_s, offs_s, cur_d, offs_d, N);
  k_fill<<<(E2+255)/256, 256, 0, stream>>>(ei, eattr, E2, cur_s, adj_s, cur_d, adj_d);
  k_pad<<<1, 64, 0, stream>>>(adj_s, adj_d, E2);
  // initial seq_in(0)/pre(0)  (step 0 is inner: s0s = seq0)
  k_seqA<<<Bb, 256, 0, stream>>>(seq0, sy, sz, seq_in, pre_f, pre_b,
                                 Wih_f, Wih_b, bsum_f, bsum_b);

  const int NB = N/32;

  // ---- main loop: 8 outer x (4 inner + 1)
  for (int o = 0; o < 8; ++o){
    for (int it = 0; it < 5; ++it){
      int gi = o*5 + it;
      bool inner = (it < 4);
      const float* s0t = inner ? struct0 : nullptr;
      float* to_ = inner ? tz : ty;
      float* so_ = inner ? sz : sy;
      const float* otherS = inner ? sy : sz;
      int itn = (gi+1) % 5;
      const float* s0s_n = (itn < 4) ? seq0 : nullptr;
      int doNext = (gi < 39) ? 1 : 0;
      k_A<<<NB, 256, 0, stream>>>(s0t, ty, tz, PB4h, PB4l,
                                  G_in, G_out, PownPk, b_in, b_out, N);
      k_B<<<Bb + NB, 512, 0, stream>>>(G_in, G_out, PownPk, to_,
                                       offs_s, adj_s, offs_d, adj_d,
                                       WEin, WEout, ln_st_g, ln_st_b,
                                       pre_f, pre_b, Whh_f, Whh_b,
                                       seq_in, so_, otherS, s0s_n,
                                       Wih_f, Wih_b, bsum_f, bsum_b,
                                       ln_seq_g, ln_seq_b, doNext, N, Bb);
    }
  }

  k_final<<<(Bb*D+255)/256, 256, 0, stream>>>((float*)d_out, sy, ty, starts,
                                              bn_g, bn_b, bn_rm, bn_rv, Bb);
}